// Round 7
// baseline (1938.038 us; speedup 1.0000x reference)
//
#include <hip/hip_runtime.h>
#include <math.h>

#define HEADS 4
#define CPH 256
#define DHID 1024
#define NEG_SLOPE 0.2f
#define FLT_BIG 3.402823466e38f
#define PCHUNK 128

typedef unsigned short u16;
typedef __bf16 bf16x8 __attribute__((ext_vector_type(8)));
typedef float f32x4 __attribute__((ext_vector_type(4)));
typedef float f32x16 __attribute__((ext_vector_type(16)));

__device__ __forceinline__ float lrelu(float x){ return x > 0.f ? x : NEG_SLOPE * x; }
__device__ __forceinline__ float eluf(float x){ return x > 0.f ? x : expf(x) - 1.f; }

__device__ __forceinline__ u16 f2bf(float f){
    unsigned u = __float_as_uint(f);
    u += 0x7fffu + ((u >> 16) & 1u);
    return (u16)(u >> 16);
}
__device__ __forceinline__ float bf2f(u16 h){ return __uint_as_float(((unsigned)h) << 16); }
__device__ __forceinline__ float4 bf4_to_f4(ushort4 u){
    return make_float4(bf2f(u.x), bf2f(u.y), bf2f(u.z), bf2f(u.w));
}

__device__ __forceinline__ void gload_lds16(const void* g, void* l){
    __builtin_amdgcn_global_load_lds((const __attribute__((address_space(1))) unsigned int*)g,
                                     (__attribute__((address_space(3))) unsigned int*)l, 16, 0, 0);
}

__device__ __forceinline__ void atomicMaxF(float* addr, float v){
    if (v >= 0.f) atomicMax((int*)addr, __float_as_int(v));
    else          atomicMin((unsigned int*)addr, __float_as_uint(v));
}

// ---------------- CSR build + pooling bounds ----------------
__global__ void k_init(int* cnt, int* fill, int* lo, int* hi, int N, int G){
    int i = blockIdx.x * blockDim.x + threadIdx.x;
    if (i < N){ cnt[i] = 0; fill[i] = 0; }
    if (i < G){ lo[i] = 0x7fffffff; hi[i] = 0; }
}

__global__ void k_count(const int* __restrict__ dst, int* __restrict__ cnt, int E){
    int e = blockIdx.x * blockDim.x + threadIdx.x;
    if (e < E) atomicAdd(&cnt[dst[e]], 1);
}

__global__ __launch_bounds__(1024) void k_scan(const int* __restrict__ cnt, int* __restrict__ rowptr,
                                               int N, int E){
    __shared__ int tot[1024];
    int tid = threadIdx.x;
    int items = (N + 1023) >> 10;
    int base = tid * items;
    int sum = 0;
    for (int i = 0; i < items; ++i){ int idx = base + i; if (idx < N) sum += cnt[idx]; }
    tot[tid] = sum;
    __syncthreads();
    for (int off = 1; off < 1024; off <<= 1){
        int t = (tid >= off) ? tot[tid - off] : 0;
        __syncthreads();
        tot[tid] += t;
        __syncthreads();
    }
    int run = tot[tid] - sum;
    for (int i = 0; i < items; ++i){
        int idx = base + i;
        if (idx < N){ rowptr[idx] = run; run += cnt[idx]; }
    }
    if (tid == 0) rowptr[N] = E;
}

__global__ void k_scatter(const int* __restrict__ src, const int* __restrict__ dst,
                          const int* __restrict__ rowptr, int* __restrict__ fill,
                          int* __restrict__ col, int E){
    int e = blockIdx.x * blockDim.x + threadIdx.x;
    if (e < E){
        int d = dst[e];
        int pos = rowptr[d] + atomicAdd(&fill[d], 1);
        col[pos] = src[e];
    }
}

__global__ void k_bounds(const int* __restrict__ batch, int* lo, int* hi, int N){
    int i = blockIdx.x * blockDim.x + threadIdx.x;
    if (i < N){
        int b = batch[i];
        atomicMin(&lo[b], i);
        atomicMax(&hi[b], i + 1);
    }
}

// ---------------- split kernels ----------------
__global__ void k_split(const float* __restrict__ X, u16* __restrict__ hi, u16* __restrict__ lo, long L4){
    long i = (long)blockIdx.x * blockDim.x + threadIdx.x;
    if (i < L4){
        float4 v = ((const float4*)X)[i];
        ushort4 h, l;
        h.x = f2bf(v.x); l.x = f2bf(v.x - bf2f(h.x));
        h.y = f2bf(v.y); l.y = f2bf(v.y - bf2f(h.y));
        h.z = f2bf(v.z); l.z = f2bf(v.z - bf2f(h.z));
        h.w = f2bf(v.w); l.w = f2bf(v.w - bf2f(h.w));
        ((ushort4*)hi)[i] = h;
        ((ushort4*)lo)[i] = l;
    }
}

// LDS-tiled transpose split: W (K x Nn, row-major) -> hiT/loT (Nn x K, row-major).
__global__ __launch_bounds__(256) void k_splitT(const float* __restrict__ W, u16* __restrict__ hiT,
                                                u16* __restrict__ loT, int K, int Nn){
    __shared__ float t[32][33];
    int n0 = blockIdx.x * 32;
    int k0 = blockIdx.y * 32;
    int tx = threadIdx.x & 31, ty = threadIdx.x >> 5;   // 8 rows per pass
    for (int r = ty; r < 32; r += 8){
        int k = k0 + r, n = n0 + tx;
        t[r][tx] = (k < K && n < Nn) ? W[(size_t)k * Nn + n] : 0.f;
    }
    __syncthreads();
    for (int r = ty; r < 32; r += 8){
        int n = n0 + r, k = k0 + tx;
        if (n < Nn && k < K){
            float v = t[tx][r];
            u16 h = f2bf(v);
            hiT[(size_t)n * K + k] = h;
            loT[(size_t)n * K + k] = f2bf(v - bf2f(h));
        }
    }
}

// ---------------- split-bf16 MFMA GEMM (32x32x16), 256x256 tile, tile-level pipeline ----------------
// T2: 16B-chunk XOR swizzle (pre-swizzled global source, linear LDS dest, swizzled ds_read).
// T3+T4 "minimum 2-phase" (catalog-verified m230/m248): stage ALL planes of tile t+1 at the top
// of tile t; ONE vmcnt(0)+barrier per K-tile (loads get a full tile ~5000 cyc to land, so the
// drain is nearly free); NO intra-tile barriers — rounds 4-6 showed per-phase barriers lockstep
// the CU into alternating {LDS-burst, MFMA-burst} (util 42% == serial sum of the two pipes).
// The compiler hoists ds_reads early and interleaves with MFMAs via counted lgkm waits (r109).
// 3-pass sub-order (hh, hl, lh) staggers fragment lifetimes to bound VGPR pressure.
__global__ __launch_bounds__(512, 2) void k_gemm_mfma(
    const u16* __restrict__ Ahi, const u16* __restrict__ Alo,
    const u16* __restrict__ BThi, const u16* __restrict__ BTlo,
    u16* __restrict__ Cbf, int M, int K, int Nn, int nwg)
{
    __shared__ __align__(16) u16 As[2][2][256][32];   // [dbuf][hi/lo][row][k] chunk-swizzled
    __shared__ __align__(16) u16 Bs[2][2][256][32];
    int tid = threadIdx.x;
    int w = tid >> 6, lane = tid & 63;

    // bijective XCD swizzle (m204)
    int orig = blockIdx.x;
    int q = nwg >> 3, r8 = nwg & 7;
    int xcd = orig & 7, loc = orig >> 3;
    int wg = (xcd < r8 ? xcd * (q + 1) : r8 * (q + 1) + (xcd - r8) * q) + loc;
    int by = wg >> 2, bx = wg & 3;
    int row0 = by * 256, col0 = bx * 256;

    // staging map: thread -> (rows tid>>2 and +128, 16B chunk tid&3), source chunk XOR-swizzled
    int srow = tid >> 2;
    int schunk = tid & 3;
    int ssw = (schunk ^ ((srow >> 1) & 3)) * 8;   // ((srow+128)>>1)&3 == ((srow>>1)&3)
    int ra0 = row0 + srow;        if (ra0 >= M) ra0 = M - 1;
    int ra1 = row0 + srow + 128;  if (ra1 >= M) ra1 = M - 1;
    int rb0 = col0 + srow;
    int rb1 = col0 + srow + 128;

    auto stageA = [&](int buf, int plane, const u16* __restrict__ P, int k0){
        gload_lds16(P + (size_t)ra0 * K + k0 + ssw, &As[buf][plane][srow      ][schunk * 8]);
        gload_lds16(P + (size_t)ra1 * K + k0 + ssw, &As[buf][plane][srow + 128][schunk * 8]);
    };
    auto stageB = [&](int buf, int plane, const u16* __restrict__ P, int k0){
        gload_lds16(P + (size_t)rb0 * K + k0 + ssw, &Bs[buf][plane][srow      ][schunk * 8]);
        gload_lds16(P + (size_t)rb1 * K + k0 + ssw, &Bs[buf][plane][srow + 128][schunk * 8]);
    };

    // wave tile: 2M x 4N waves, per-wave 128x64 output
    int wr = w >> 2, wc = w & 3;
    int wm = wr * 128, wn = wc * 64;
    int l31 = lane & 31;
    int hi  = lane >> 5;

    // fragment LDS chunk offsets: rows are base|l31 (base mult of 32) -> (row>>1)&3 == (l31>>1)&3
    int sfr = (l31 >> 1) & 3;
    int c0 = ((0 | hi) ^ sfr) * 8;   // kk=0
    int c1 = ((2 | hi) ^ sfr) * 8;   // kk=1

    f32x16 acc[4][2];
#pragma unroll
    for (int i = 0; i < 4; ++i)
#pragma unroll
        for (int j = 0; j < 2; ++j)
#pragma unroll
            for (int e = 0; e < 16; ++e) acc[i][j][e] = 0.f;

    // prologue: stage K-tile 0 into buf 0
    stageA(0, 0, Ahi, 0);
    stageB(0, 0, BThi, 0);
    stageB(0, 1, BTlo, 0);
    stageA(0, 1, Alo, 0);

    int nt = K >> 5;
    int cur = 0;
    for (int t = 0; t < nt; ++t){
        int nxt = cur ^ 1;
        int kn = (t + 1) << 5;
        bool pf = (t + 1 < nt);

        // tile gate: stage(t) loads were issued a full tile ago -> vmcnt(0) is cheap.
        asm volatile("s_waitcnt vmcnt(0)" ::: "memory");
        __builtin_amdgcn_s_barrier();
        asm volatile("" ::: "memory");

        // stage ALL planes of tile t+1 (8 loads in flight across the whole tile body)
        if (pf){
            stageA(nxt, 0, Ahi, kn);
            stageB(nxt, 0, BThi, kn);
            stageB(nxt, 1, BTlo, kn);
            stageA(nxt, 1, Alo, kn);
        }

        // ---- pass 1: hh ----
        bf16x8 ah[4][2], bh[2][2];
#pragma unroll
        for (int i = 0; i < 4; ++i){
            ah[i][0] = *(const bf16x8*)&As[cur][0][wm + i * 32 + l31][c0];
            ah[i][1] = *(const bf16x8*)&As[cur][0][wm + i * 32 + l31][c1];
        }
#pragma unroll
        for (int j = 0; j < 2; ++j){
            bh[j][0] = *(const bf16x8*)&Bs[cur][0][wn + j * 32 + l31][c0];
            bh[j][1] = *(const bf16x8*)&Bs[cur][0][wn + j * 32 + l31][c1];
        }
#pragma unroll
        for (int i = 0; i < 4; ++i)
#pragma unroll
            for (int j = 0; j < 2; ++j){
                acc[i][j] = __builtin_amdgcn_mfma_f32_32x32x16_bf16(ah[i][0], bh[j][0], acc[i][j], 0, 0, 0);
                acc[i][j] = __builtin_amdgcn_mfma_f32_32x32x16_bf16(ah[i][1], bh[j][1], acc[i][j], 0, 0, 0);
            }

        // ---- pass 2: hl ----
        bf16x8 bl[2][2];
#pragma unroll
        for (int j = 0; j < 2; ++j){
            bl[j][0] = *(const bf16x8*)&Bs[cur][1][wn + j * 32 + l31][c0];
            bl[j][1] = *(const bf16x8*)&Bs[cur][1][wn + j * 32 + l31][c1];
        }
#pragma unroll
        for (int i = 0; i < 4; ++i)
#pragma unroll
            for (int j = 0; j < 2; ++j){
                acc[i][j] = __builtin_amdgcn_mfma_f32_32x32x16_bf16(ah[i][0], bl[j][0], acc[i][j], 0, 0, 0);
                acc[i][j] = __builtin_amdgcn_mfma_f32_32x32x16_bf16(ah[i][1], bl[j][1], acc[i][j], 0, 0, 0);
            }

        // ---- pass 3: lh ----
        bf16x8 al[4][2];
#pragma unroll
        for (int i = 0; i < 4; ++i){
            al[i][0] = *(const bf16x8*)&As[cur][1][wm + i * 32 + l31][c0];
            al[i][1] = *(const bf16x8*)&As[cur][1][wm + i * 32 + l31][c1];
        }
#pragma unroll
        for (int i = 0; i < 4; ++i)
#pragma unroll
            for (int j = 0; j < 2; ++j){
                acc[i][j] = __builtin_amdgcn_mfma_f32_32x32x16_bf16(al[i][0], bh[j][0], acc[i][j], 0, 0, 0);
                acc[i][j] = __builtin_amdgcn_mfma_f32_32x32x16_bf16(al[i][1], bh[j][1], acc[i][j], 0, 0, 0);
            }

        cur = nxt;
    }

    // C/D layout (32x32, HW-verified): col = lane&31, row = (reg&3) + 8*(reg>>2) + 4*(lane>>5)
#pragma unroll
    for (int fi = 0; fi < 4; ++fi){
#pragma unroll
        for (int fj = 0; fj < 2; ++fj){
            int colc = col0 + wn + fj * 32 + l31;
#pragma unroll
            for (int e = 0; e < 16; ++e){
                int row = row0 + wm + fi * 32 + (e & 3) + 8 * (e >> 2) + 4 * hi;
                if (row < M) Cbf[(size_t)row * Nn + colc] = f2bf(acc[fi][fj][e]);
            }
        }
    }
}

// ---------------- per-node attention score dots (bf16 h) ----------------
__global__ __launch_bounds__(256) void k_esd(const u16* __restrict__ h, const float* __restrict__ asrc,
                                             const float* __restrict__ adst,
                                             float* __restrict__ es, float* __restrict__ ed){
    int n = blockIdx.x;
    int tid = threadIdx.x;
    int w = tid >> 6, lane = tid & 63;
    float4 hv = bf4_to_f4(*(const ushort4*)(h + (size_t)n * DHID + w * CPH + lane * 4));
    float4 av = *(const float4*)(asrc + w * CPH + lane * 4);
    float4 dv = *(const float4*)(adst + w * CPH + lane * 4);
    float s = hv.x * av.x + hv.y * av.y + hv.z * av.z + hv.w * av.w;
    float d = hv.x * dv.x + hv.y * dv.y + hv.z * dv.z + hv.w * dv.w;
    for (int off = 32; off > 0; off >>= 1){
        s += __shfl_down(s, off);
        d += __shfl_down(d, off);
    }
    if (lane == 0){ es[n * HEADS + w] = s; ed[n * HEADS + w] = d; }
}

// ---------------- wave-per-node segment softmax + aggregation + bias + elu + split write ----------------
__global__ __launch_bounds__(256) void k_agg(const u16* __restrict__ hsrc, const float* __restrict__ es,
                                             const float* __restrict__ ed, const int* __restrict__ rowptr,
                                             const int* __restrict__ col, const float* __restrict__ bias,
                                             u16* __restrict__ outhi, u16* __restrict__ outlo,
                                             int writeLo, int N){
    int n = blockIdx.x * 4 + (threadIdx.x >> 6);
    if (n >= N) return;
    int lane = threadIdx.x & 63;
    int rp0 = rowptr[n];
    int deg = rowptr[n + 1] - rp0;
    int total = deg + 1;                         // + implicit self-loop
    float4 edv = *(const float4*)(ed + (size_t)n * HEADS);

    // pass 1: per-head max over incoming edges
    float4 mx = make_float4(-FLT_BIG, -FLT_BIG, -FLT_BIG, -FLT_BIG);
    for (int i = lane; i < total; i += 64){
        int s = (i < deg) ? col[rp0 + i] : n;
        float4 ev = *(const float4*)(es + (size_t)s * HEADS);
        mx.x = fmaxf(mx.x, lrelu(ev.x + edv.x));
        mx.y = fmaxf(mx.y, lrelu(ev.y + edv.y));
        mx.z = fmaxf(mx.z, lrelu(ev.z + edv.z));
        mx.w = fmaxf(mx.w, lrelu(ev.w + edv.w));
    }
#pragma unroll
    for (int off = 1; off < 64; off <<= 1){
        mx.x = fmaxf(mx.x, __shfl_xor(mx.x, off));
        mx.y = fmaxf(mx.y, __shfl_xor(mx.y, off));
        mx.z = fmaxf(mx.z, __shfl_xor(mx.z, off));
        mx.w = fmaxf(mx.w, __shfl_xor(mx.w, off));
    }

    // pass 2: per-head sum of exp(e - m)
    float4 sm = make_float4(0.f, 0.f, 0.f, 0.f);
    for (int i = lane; i < total; i += 64){
        int s = (i < deg) ? col[rp0 + i] : n;
        float4 ev = *(const float4*)(es + (size_t)s * HEADS);
        sm.x += expf(lrelu(ev.x + edv.x) - mx.x);
        sm.y += expf(lrelu(ev.y + edv.y) - mx.y);
        sm.z += expf(lrelu(ev.z + edv.z) - mx.z);
        sm.w += expf(lrelu(ev.w + edv.w) - mx.w);
    }
#pragma unroll
    for (int off = 1; off < 64; off <<= 1){
        sm.x += __shfl_xor(sm.x, off);
        sm.y += __shfl_xor(sm.y, off);
        sm.z += __shfl_xor(sm.z, off);
        sm.w += __shfl_xor(sm.w, off);
    }
    float4 inv = make_float4(1.f / (sm.x + 1e-16f), 1.f / (sm.y + 1e-16f),
                             1.f / (sm.z + 1e-16f), 1.f / (sm.w + 1e-16f));

    // pass 3: weighted aggregation — wave reads the full 2KB row per edge
    float4 a0 = make_float4(0.f,0.f,0.f,0.f), a1 = a0, a2 = a0, a3 = a0;
    int c4 = lane * 4;
    for (int i = 0; i < total; ++i){
        int s = (i < deg) ? col[rp0 + i] : n;           // wave-uniform
        float4 ev = *(const float4*)(es + (size_t)s * HEADS);
        const u16* rowp = hsrc + (size_t)s * DHID;
        ushort4 r0 = *(const ushort4*)(rowp + 0 * CPH + c4);
        ushort4 r1 = *(const ushort4*)(rowp + 1 * CPH + c4);
        ushort4 r2 = *(const ushort4*)(rowp + 2 * CPH + c4);
        ushort4 r3 = *(const ushort4*)(rowp + 3 * CPH + c4);
        float alx = expf(lrelu(ev.x + edv.x) - mx.x) * inv.x;
        float aly = expf(lrelu(ev.y + edv.y) - mx.y) * inv.y;
        float alz = expf(lrelu(ev.z + edv.z) - mx.z) * inv.z;
        float alw = expf(lrelu(ev.w + edv.w) - mx.w) * inv.w;
        float4 f0 = bf4_to_f4(r0), f1 = bf4_to_f4(r1), f2 = bf4_to_f4(r2), f3 = bf4_to_f4(r3);
        a0.x = fmaf(alx, f0.x, a0.x); a0.y = fmaf(alx, f0.y, a0.y);
        a0.z = fmaf(alx, f0.z, a0.z); a0.w = fmaf(alx, f0.w, a0.w);
        a1.x = fmaf(aly, f1.x, a1.x); a1.y = fmaf(aly, f1.y, a1.y);
        a1.z = fmaf(aly, f1.z, a1.z); a1.w = fmaf(aly, f1.w, a1.w);
        a2.x = fmaf(alz, f2.x, a2.x); a2.y = fmaf(alz, f2.y, a2.y);
        a2.z = fmaf(alz, f2.z, a2.z); a2.w = fmaf(alz, f2.w, a2.w);
        a3.x = fmaf(alw, f3.x, a3.x); a3.y = fmaf(alw, f3.y, a3.y);
        a3.z = fmaf(alw, f3.z, a3.z); a3.w = fmaf(alw, f3.w, a3.w);
    }

    // epilogue: +bias, elu, bf16 hi(/lo) store per head
#pragma unroll
    for (int h = 0; h < 4; ++h){
        float4 a = (h == 0) ? a0 : (h == 1) ? a1 : (h == 2) ? a2 : a3;
        int cidx = h * CPH + c4;
        float4 bv = *(const float4*)(bias + cidx);
        float ox = eluf(a.x + bv.x);
        float oy = eluf(a.y + bv.y);
        float oz = eluf(a.z + bv.z);
        float ow = eluf(a.w + bv.w);
        ushort4 h4;
        h4.x = f2bf(ox); h4.y = f2bf(oy); h4.z = f2bf(oz); h4.w = f2bf(ow);
        *(ushort4*)(outhi + (size_t)n * DHID + cidx) = h4;
        if (writeLo){
            ushort4 l4;
            l4.x = f2bf(ox - bf2f(h4.x));
            l4.y = f2bf(oy - bf2f(h4.y));
            l4.z = f2bf(oz - bf2f(h4.z));
            l4.w = f2bf(ow - bf2f(h4.w));
            *(ushort4*)(outlo + (size_t)n * DHID + cidx) = l4;
        }
    }
}

// ---------------- two-stage per-graph mean/max pooling (bf16 input) ----------------
__global__ __launch_bounds__(256) void k_pool_init(float* __restrict__ gsum, float* __restrict__ gmax, int L){
    int i = blockIdx.x * blockDim.x + threadIdx.x;
    if (i < L){ gsum[i] = 0.f; gmax[i] = -FLT_BIG; }
}

__global__ __launch_bounds__(256) void k_pool_partial(const u16* __restrict__ hf,
                                                      const int* __restrict__ batch,
                                                      float* __restrict__ gsum, float* __restrict__ gmax,
                                                      int N){
    int c = blockIdx.y * 256 + threadIdx.x;
    int i0 = blockIdx.x * PCHUNK;
    int i1 = i0 + PCHUNK; if (i1 > N) i1 = N;
    int curg = batch[i0];
    float s = 0.f, m = -FLT_BIG;
    for (int i = i0; i < i1; ++i){
        int g = batch[i];
        if (g != curg){
            atomicAdd(&gsum[(size_t)curg * DHID + c], s);
            atomicMaxF(&gmax[(size_t)curg * DHID + c], m);
            s = 0.f; m = -FLT_BIG; curg = g;
        }
        float v = bf2f(hf[(size_t)i * DHID + c]);
        s += v;
        m = fmaxf(m, v);
    }
    atomicAdd(&gsum[(size_t)curg * DHID + c], s);
    atomicMaxF(&gmax[(size_t)curg * DHID + c], m);
}

__global__ __launch_bounds__(256) void k_pool_final(const float* __restrict__ gsum,
                                                    const float* __restrict__ gmax,
                                                    const int* __restrict__ lo, const int* __restrict__ hi,
                                                    float* __restrict__ gfeat){
    int g = blockIdx.x;
    int c = threadIdx.x * 4;
    int l = lo[g], h2 = hi[g];
    int cnt = (h2 > l) ? (h2 - l) : 0;
    float invc = 1.f / (float)((cnt > 1) ? cnt : 1);
    float4 s = *(const float4*)(gsum + (size_t)g * DHID + c);
    float4 m = *(const float4*)(gmax + (size_t)g * DHID + c);
    float4 mean = make_float4(s.x * invc, s.y * invc, s.z * invc, s.w * invc);
    if (cnt == 0) m = make_float4(0.f, 0.f, 0.f, 0.f);
    *(float4*)(gfeat + (size_t)g * 2048 + c)        = mean;
    *(float4*)(gfeat + (size_t)g * 2048 + 1024 + c) = m;
}

// ---------------- small FC ----------------
__global__ __launch_bounds__(256) void k_fc(const float* __restrict__ X, const float* __restrict__ W,
                                            const float* __restrict__ b, float* __restrict__ Y,
                                            int K, int Nc, int relu){
    __shared__ float xr[2048];
    int r = blockIdx.y;
    int tid = threadIdx.x;
    for (int i = tid; i < K; i += 256) xr[i] = X[(size_t)r * K + i];
    __syncthreads();
    int c = blockIdx.x * 256 + tid;
    if (c >= Nc) return;
    float acc = b[c];
    for (int k = 0; k < K; ++k) acc += xr[k] * W[(size_t)k * Nc + c];
    if (relu) acc = fmaxf(acc, 0.f);
    Y[(size_t)r * Nc + c] = acc;
}

// ---------------- launch ----------------
extern "C" void kernel_launch(void* const* d_in, const int* in_sizes, int n_in,
                              void* d_out, int out_size, void* d_ws, size_t ws_size,
                              hipStream_t stream) {
    const float* x      = (const float*)d_in[0];
    const int*   ei     = (const int*)  d_in[1];
    const int*   batch  = (const int*)  d_in[2];
    const float* W1     = (const float*)d_in[3];
    const float* asrc1  = (const float*)d_in[4];
    const float* adst1  = (const float*)d_in[5];
    const float* b1     = (const float*)d_in[6];
    const float* W2     = (const float*)d_in[7];
    const float* asrc2  = (const float*)d_in[8];
    const float* adst2  = (const float*)d_in[9];
    const float* b2     = (const float*)d_in[10];
    const float* Wc1    = (const float*)d_in[11];
    const float* bc1    = (const float*)d_in[12];
    const float* Wc2    = (const float*)d_in[13];
    const float* bc2    = (const float*)d_in[14];
    const float* Wc3    = (const float*)d_in[15];
    const float* bc3    = (const float*)d_in[16];

    const int N = in_sizes[2];
    const int E = in_sizes[1] / 2;
    const int G = out_size / 5;
    const int DIN = in_sizes[0] / N;

    const int* srcI = ei;
    const int* dstI = ei + E;

    char* p = (char*)d_ws;
    auto alloc = [&](size_t bytes) -> void* {
        void* q = (void*)p;
        p += (bytes + 255) & ~(size_t)255;
        return q;
    };
    u16*   R1     = (u16*)alloc((size_t)N * DHID * 2 * 2);   // activations hi+lo
    u16*   R2     = (u16*)alloc((size_t)N * DHID * 2);       // bf16 h plane
    float* es     = (float*)alloc((size_t)N * HEADS * 4);
    float* ed     = (float*)alloc((size_t)N * HEADS * 4);
    float* gfeat  = (float*)alloc((size_t)G * 2048 * 4);
    float* gsum   = (float*)alloc((size_t)G * DHID * 4);
    float* gmax   = (float*)alloc((size_t)G * DHID * 4);
    float* z1     = (float*)alloc((size_t)G * 512 * 4);
    float* z2     = (float*)alloc((size_t)G * 256 * 4);
    int*   cnt    = (int*)  alloc((size_t)N * 4);
    int*   fill   = (int*)  alloc((size_t)N * 4);
    int*   rowptr = (int*)  alloc((size_t)(N + 1) * 4);
    int*   col    = (int*)  alloc((size_t)E * 4);
    int*   lo     = (int*)  alloc((size_t)G * 4);
    int*   hi     = (int*)  alloc((size_t)G * 4);
    u16*   w1th   = (u16*)  alloc((size_t)DIN * DHID * 2);
    u16*   w1tl   = (u16*)  alloc((size_t)DIN * DHID * 2);
    u16*   w2th   = (u16*)  alloc((size_t)DHID * DHID * 2);
    u16*   w2tl   = (u16*)  alloc((size_t)DHID * DHID * 2);
    float* logits = (float*)d_out;

    int nb = (N + 255) / 256;
    int ebp = (E + 255) / 256;
    int aggb = (N + 3) / 4;

    // CSR + pooling bounds
    k_init   <<<nb,  256, 0, stream>>>(cnt, fill, lo, hi, N, G);
    k_count  <<<ebp, 256, 0, stream>>>(dstI, cnt, E);
    k_scan   <<<1,  1024, 0, stream>>>(cnt, rowptr, N, E);
    k_scatter<<<ebp, 256, 0, stream>>>(srcI, dstI, rowptr, fill, col, E);
    k_bounds <<<nb,  256, 0, stream>>>(batch, lo, hi, N);

    // weight splits (with LDS-tiled transpose)
    k_splitT<<<dim3((DHID + 31) / 32, (DIN + 31) / 32),  256, 0, stream>>>(W1, w1th, w1tl, DIN, DHID);
    k_splitT<<<dim3((DHID + 31) / 32, (DHID + 31) / 32), 256, 0, stream>>>(W2, w2th, w2tl, DHID, DHID);

    int Rt = (N + 255) / 256;
    int nwg = Rt * 4;                 // 4 col-tiles of 256 over DHID=1024

    // ---- GAT layer 1 ----
    u16* a1h = R1;
    u16* a1l = R1 + (size_t)N * DIN;
    long L41 = (long)N * DIN / 4;
    k_split<<<(unsigned)((L41 + 255) / 256), 256, 0, stream>>>(x, a1h, a1l, L41);
    u16* h1 = R2;
    k_gemm_mfma<<<nwg, 512, 0, stream>>>(a1h, a1l, w1th, w1tl, h1, N, DIN, DHID, nwg);
    k_esd<<<N, 256, 0, stream>>>(h1, asrc1, adst1, es, ed);
    u16* o1h = R1;
    u16* o1l = R1 + (size_t)N * DHID;
    k_agg<<<aggb, 256, 0, stream>>>(h1, es, ed, rowptr, col, b1, o1h, o1l, 1, N);

    // ---- GAT layer 2 ----
    u16* h2 = R2;
    k_gemm_mfma<<<nwg, 512, 0, stream>>>(o1h, o1l, w2th, w2tl, h2, N, DHID, DHID, nwg);
    k_esd<<<N, 256, 0, stream>>>(h2, asrc2, adst2, es, ed);
    u16* o2h = R1;
    k_agg<<<aggb, 256, 0, stream>>>(h2, es, ed, rowptr, col, b2, o2h, (u16*)0, 0, N);

    // ---- pooling + classifier ----
    k_pool_init<<<(G * DHID + 255) / 256, 256, 0, stream>>>(gsum, gmax, G * DHID);
    dim3 poolGrd((N + PCHUNK - 1) / PCHUNK, DHID / 256);
    k_pool_partial<<<poolGrd, 256, 0, stream>>>(o2h, batch, gsum, gmax, N);
    k_pool_final<<<G, 256, 0, stream>>>(gsum, gmax, lo, hi, gfeat);

    k_fc<<<dim3(2, G), 256, 0, stream>>>(gfeat, Wc1, bc1, z1, 2048, 512, 1);
    k_fc<<<dim3(1, G), 256, 0, stream>>>(z1,    Wc2, bc2, z2, 512,  256, 1);
    k_fc<<<dim3(1, G), 256, 0, stream>>>(z2,    Wc3, bc3, logits, 256, 5, 0);
}

// Round 8
// 1874.711 us; speedup vs baseline: 1.0338x; 1.0338x over previous
//
#include <hip/hip_runtime.h>
#include <math.h>

#define HEADS 4
#define CPH 256
#define DHID 1024
#define NEG_SLOPE 0.2f
#define FLT_BIG 3.402823466e38f
#define PCHUNK 128

typedef unsigned short u16;
typedef __bf16 bf16x8 __attribute__((ext_vector_type(8)));
typedef float f32x4 __attribute__((ext_vector_type(4)));

__device__ __forceinline__ float lrelu(float x){ return x > 0.f ? x : NEG_SLOPE * x; }
__device__ __forceinline__ float eluf(float x){ return x > 0.f ? x : expf(x) - 1.f; }

__device__ __forceinline__ u16 f2bf(float f){
    unsigned u = __float_as_uint(f);
    u += 0x7fffu + ((u >> 16) & 1u);
    return (u16)(u >> 16);
}
__device__ __forceinline__ float bf2f(u16 h){ return __uint_as_float(((unsigned)h) << 16); }
__device__ __forceinline__ float4 bf4_to_f4(ushort4 u){
    return make_float4(bf2f(u.x), bf2f(u.y), bf2f(u.z), bf2f(u.w));
}

__device__ __forceinline__ void gload_lds16(const void* g, void* l){
    __builtin_amdgcn_global_load_lds((const __attribute__((address_space(1))) unsigned int*)g,
                                     (__attribute__((address_space(3))) unsigned int*)l, 16, 0, 0);
}

__device__ __forceinline__ void atomicMaxF(float* addr, float v){
    if (v >= 0.f) atomicMax((int*)addr, __float_as_int(v));
    else          atomicMin((unsigned int*)addr, __float_as_uint(v));
}

// ---------------- CSR build + pooling bounds ----------------
__global__ void k_init(int* cnt, int* fill, int* lo, int* hi, int N, int G){
    int i = blockIdx.x * blockDim.x + threadIdx.x;
    if (i < N){ cnt[i] = 0; fill[i] = 0; }
    if (i < G){ lo[i] = 0x7fffffff; hi[i] = 0; }
}

__global__ void k_count(const int* __restrict__ dst, int* __restrict__ cnt, int E){
    int e = blockIdx.x * blockDim.x + threadIdx.x;
    if (e < E) atomicAdd(&cnt[dst[e]], 1);
}

__global__ __launch_bounds__(1024) void k_scan(const int* __restrict__ cnt, int* __restrict__ rowptr,
                                               int N, int E){
    __shared__ int tot[1024];
    int tid = threadIdx.x;
    int items = (N + 1023) >> 10;
    int base = tid * items;
    int sum = 0;
    for (int i = 0; i < items; ++i){ int idx = base + i; if (idx < N) sum += cnt[idx]; }
    tot[tid] = sum;
    __syncthreads();
    for (int off = 1; off < 1024; off <<= 1){
        int t = (tid >= off) ? tot[tid - off] : 0;
        __syncthreads();
        tot[tid] += t;
        __syncthreads();
    }
    int run = tot[tid] - sum;
    for (int i = 0; i < items; ++i){
        int idx = base + i;
        if (idx < N){ rowptr[idx] = run; run += cnt[idx]; }
    }
    if (tid == 0) rowptr[N] = E;
}

__global__ void k_scatter(const int* __restrict__ src, const int* __restrict__ dst,
                          const int* __restrict__ rowptr, int* __restrict__ fill,
                          int* __restrict__ col, int E){
    int e = blockIdx.x * blockDim.x + threadIdx.x;
    if (e < E){
        int d = dst[e];
        int pos = rowptr[d] + atomicAdd(&fill[d], 1);
        col[pos] = src[e];
    }
}

__global__ void k_bounds(const int* __restrict__ batch, int* lo, int* hi, int N){
    int i = blockIdx.x * blockDim.x + threadIdx.x;
    if (i < N){
        int b = batch[i];
        atomicMin(&lo[b], i);
        atomicMax(&hi[b], i + 1);
    }
}

// ---------------- split kernels ----------------
__global__ void k_split(const float* __restrict__ X, u16* __restrict__ hi, u16* __restrict__ lo, long L4){
    long i = (long)blockIdx.x * blockDim.x + threadIdx.x;
    if (i < L4){
        float4 v = ((const float4*)X)[i];
        ushort4 h, l;
        h.x = f2bf(v.x); l.x = f2bf(v.x - bf2f(h.x));
        h.y = f2bf(v.y); l.y = f2bf(v.y - bf2f(h.y));
        h.z = f2bf(v.z); l.z = f2bf(v.z - bf2f(h.z));
        h.w = f2bf(v.w); l.w = f2bf(v.w - bf2f(h.w));
        ((ushort4*)hi)[i] = h;
        ((ushort4*)lo)[i] = l;
    }
}

// LDS-tiled transpose split: W (K x Nn, row-major) -> hiT/loT (Nn x K, row-major).
__global__ __launch_bounds__(256) void k_splitT(const float* __restrict__ W, u16* __restrict__ hiT,
                                                u16* __restrict__ loT, int K, int Nn){
    __shared__ float t[32][33];
    int n0 = blockIdx.x * 32;
    int k0 = blockIdx.y * 32;
    int tx = threadIdx.x & 31, ty = threadIdx.x >> 5;   // 8 rows per pass
    for (int r = ty; r < 32; r += 8){
        int k = k0 + r, n = n0 + tx;
        t[r][tx] = (k < K && n < Nn) ? W[(size_t)k * Nn + n] : 0.f;
    }
    __syncthreads();
    for (int r = ty; r < 32; r += 8){
        int n = n0 + r, k = k0 + tx;
        if (n < Nn && k < K){
            float v = t[tx][r];
            u16 h = f2bf(v);
            hiT[(size_t)n * K + k] = h;
            loT[(size_t)n * K + k] = f2bf(v - bf2f(h));
        }
    }
}

// ---------------- split-bf16 MFMA GEMM (16x16x32), 128x128 tile — round-0 verified best ----------------
// Reverted verbatim to the session-best kernel (316 us @ K=1024, MfmaUtil 46, ~3 blocks/CU;
// every 256^2 8-wave scheduled variant measured slower: 341/368/382). Added rowbase/Rd so each
// GEMM is launched as TWO half-M dispatches: same total work, and any non-GEMM kernel >~160 us
// now surfaces in the rocprof top-5 (instrumentation for the dominant ~1.3 ms non-GEMM side).
__global__ __launch_bounds__(256) void k_gemm_mfma(
    const u16* __restrict__ Ahi, const u16* __restrict__ Alo,
    const u16* __restrict__ BThi, const u16* __restrict__ BTlo,
    u16* __restrict__ Cbf, int M, int K, int Nn, int Rchunk, int rowbase, int Rd)
{
    __shared__ __align__(16) u16 As[2][128][32];
    __shared__ __align__(16) u16 Bs[2][128][32];
    int tid = threadIdx.x;
    int w = tid >> 6, lane = tid & 63;

    int by = blockIdx.x * Rchunk + (blockIdx.y >> 3);   // gridDim.x==8 (XCD swizzle)
    int bx = blockIdx.y & 7;
    if (by >= Rd) return;
    int row0 = (rowbase + by) * 128, col0 = bx * 128;

    int srow = tid >> 2;
    int skoff = (tid & 3) * 8;

    int wm = (w >> 1) * 64, wn = (w & 1) * 64;
    int fr = lane & 15;
    int fq = lane >> 4;

    f32x4 acc[4][4];
#pragma unroll
    for (int i = 0; i < 4; ++i)
#pragma unroll
        for (int j = 0; j < 4; ++j){ acc[i][j].x = 0.f; acc[i][j].y = 0.f; acc[i][j].z = 0.f; acc[i][j].w = 0.f; }

    int ra0 = row0 + srow;      if (ra0 >= M) ra0 = M - 1;
    int ra1 = row0 + srow + 64; if (ra1 >= M) ra1 = M - 1;
    int rb0 = col0 + srow;
    int rb1 = col0 + srow + 64;

    for (int k0 = 0; k0 < K; k0 += 32){
        size_t ga0 = (size_t)ra0 * K + k0 + skoff;
        size_t ga1 = (size_t)ra1 * K + k0 + skoff;
        size_t gb0 = (size_t)rb0 * K + k0 + skoff;
        size_t gb1 = (size_t)rb1 * K + k0 + skoff;
        gload_lds16(Ahi  + ga0, &As[0][srow     ][skoff]);
        gload_lds16(Ahi  + ga1, &As[0][srow + 64][skoff]);
        gload_lds16(Alo  + ga0, &As[1][srow     ][skoff]);
        gload_lds16(Alo  + ga1, &As[1][srow + 64][skoff]);
        gload_lds16(BThi + gb0, &Bs[0][srow     ][skoff]);
        gload_lds16(BThi + gb1, &Bs[0][srow + 64][skoff]);
        gload_lds16(BTlo + gb0, &Bs[1][srow     ][skoff]);
        gload_lds16(BTlo + gb1, &Bs[1][srow + 64][skoff]);
        __syncthreads();

        bf16x8 ah[4], al[4], bh[4], bl[4];
#pragma unroll
        for (int i = 0; i < 4; ++i){
            ah[i] = *(const bf16x8*)&As[0][wm + i * 16 + fr][fq * 8];
            al[i] = *(const bf16x8*)&As[1][wm + i * 16 + fr][fq * 8];
            bh[i] = *(const bf16x8*)&Bs[0][wn + i * 16 + fr][fq * 8];
            bl[i] = *(const bf16x8*)&Bs[1][wn + i * 16 + fr][fq * 8];
        }
#pragma unroll
        for (int i = 0; i < 4; ++i)
#pragma unroll
            for (int j = 0; j < 4; ++j){
                acc[i][j] = __builtin_amdgcn_mfma_f32_16x16x32_bf16(ah[i], bh[j], acc[i][j], 0, 0, 0);
                acc[i][j] = __builtin_amdgcn_mfma_f32_16x16x32_bf16(ah[i], bl[j], acc[i][j], 0, 0, 0);
                acc[i][j] = __builtin_amdgcn_mfma_f32_16x16x32_bf16(al[i], bh[j], acc[i][j], 0, 0, 0);
            }
        __syncthreads();
    }

#pragma unroll
    for (int i = 0; i < 4; ++i){
#pragma unroll
        for (int j = 0; j < 4; ++j){
            int colc = col0 + wn + j * 16 + fr;
#pragma unroll
            for (int r = 0; r < 4; ++r){
                int row = row0 + wm + i * 16 + fq * 4 + r;
                if (row < M) Cbf[(size_t)row * Nn + colc] = f2bf(acc[i][j][r]);
            }
        }
    }
}

// ---------------- per-node attention score dots (bf16 h) ----------------
__global__ __launch_bounds__(256) void k_esd(const u16* __restrict__ h, const float* __restrict__ asrc,
                                             const float* __restrict__ adst,
                                             float* __restrict__ es, float* __restrict__ ed){
    int n = blockIdx.x;
    int tid = threadIdx.x;
    int w = tid >> 6, lane = tid & 63;
    float4 hv = bf4_to_f4(*(const ushort4*)(h + (size_t)n * DHID + w * CPH + lane * 4));
    float4 av = *(const float4*)(asrc + w * CPH + lane * 4);
    float4 dv = *(const float4*)(adst + w * CPH + lane * 4);
    float s = hv.x * av.x + hv.y * av.y + hv.z * av.z + hv.w * av.w;
    float d = hv.x * dv.x + hv.y * dv.y + hv.z * dv.z + hv.w * dv.w;
    for (int off = 32; off > 0; off >>= 1){
        s += __shfl_down(s, off);
        d += __shfl_down(d, off);
    }
    if (lane == 0){ es[n * HEADS + w] = s; ed[n * HEADS + w] = d; }
}

// ---------------- wave-per-node segment softmax + aggregation + bias + elu + split write ----------------
// Fast path (total <= 64, i.e. essentially all nodes at avg degree 4): each lane owns one
// incoming edge; scores computed ONCE per edge in-lane, max/sum via shuffle butterflies,
// alpha broadcast in the gather loop via __shfl — removes 2 of 3 es-passes and 8 of 12
// expf per edge. Fallback: original 3-pass loop for total > 64.
__global__ __launch_bounds__(256) void k_agg(const u16* __restrict__ hsrc, const float* __restrict__ es,
                                             const float* __restrict__ ed, const int* __restrict__ rowptr,
                                             const int* __restrict__ col, const float* __restrict__ bias,
                                             u16* __restrict__ outhi, u16* __restrict__ outlo,
                                             int writeLo, int N){
    int n = blockIdx.x * 4 + (threadIdx.x >> 6);
    if (n >= N) return;
    int lane = threadIdx.x & 63;
    int rp0 = rowptr[n];
    int deg = rowptr[n + 1] - rp0;
    int total = deg + 1;                         // + implicit self-loop
    float4 edv = *(const float4*)(ed + (size_t)n * HEADS);

    float4 a0 = make_float4(0.f,0.f,0.f,0.f), a1 = a0, a2 = a0, a3 = a0;
    int c4 = lane * 4;

    if (total <= 64){
        // per-lane edge score (lane i owns edge i)
        int sl = (lane < deg) ? col[rp0 + lane] : n;
        float4 ev = *(const float4*)(es + (size_t)sl * HEADS);
        bool valid = (lane < total);
        float ex = valid ? lrelu(ev.x + edv.x) : -FLT_BIG;
        float ey = valid ? lrelu(ev.y + edv.y) : -FLT_BIG;
        float ez = valid ? lrelu(ev.z + edv.z) : -FLT_BIG;
        float ew = valid ? lrelu(ev.w + edv.w) : -FLT_BIG;
        float mxx = ex, mxy = ey, mxz = ez, mxw = ew;
#pragma unroll
        for (int off = 1; off < 64; off <<= 1){
            mxx = fmaxf(mxx, __shfl_xor(mxx, off));
            mxy = fmaxf(mxy, __shfl_xor(mxy, off));
            mxz = fmaxf(mxz, __shfl_xor(mxz, off));
            mxw = fmaxf(mxw, __shfl_xor(mxw, off));
        }
        float px = valid ? expf(ex - mxx) : 0.f;
        float py = valid ? expf(ey - mxy) : 0.f;
        float pz = valid ? expf(ez - mxz) : 0.f;
        float pw = valid ? expf(ew - mxw) : 0.f;
        float sx = px, sy = py, sz = pz, sw = pw;
#pragma unroll
        for (int off = 1; off < 64; off <<= 1){
            sx += __shfl_xor(sx, off);
            sy += __shfl_xor(sy, off);
            sz += __shfl_xor(sz, off);
            sw += __shfl_xor(sw, off);
        }
        float alx_l = px / (sx + 1e-16f);
        float aly_l = py / (sy + 1e-16f);
        float alz_l = pz / (sz + 1e-16f);
        float alw_l = pw / (sw + 1e-16f);

        for (int i = 0; i < total; ++i){
            int s = (i < deg) ? col[rp0 + i] : n;       // wave-uniform
            float alx = __shfl(alx_l, i);
            float aly = __shfl(aly_l, i);
            float alz = __shfl(alz_l, i);
            float alw = __shfl(alw_l, i);
            const u16* rowp = hsrc + (size_t)s * DHID;
            ushort4 r0 = *(const ushort4*)(rowp + 0 * CPH + c4);
            ushort4 r1 = *(const ushort4*)(rowp + 1 * CPH + c4);
            ushort4 r2 = *(const ushort4*)(rowp + 2 * CPH + c4);
            ushort4 r3 = *(const ushort4*)(rowp + 3 * CPH + c4);
            float4 f0 = bf4_to_f4(r0), f1 = bf4_to_f4(r1), f2 = bf4_to_f4(r2), f3 = bf4_to_f4(r3);
            a0.x = fmaf(alx, f0.x, a0.x); a0.y = fmaf(alx, f0.y, a0.y);
            a0.z = fmaf(alx, f0.z, a0.z); a0.w = fmaf(alx, f0.w, a0.w);
            a1.x = fmaf(aly, f1.x, a1.x); a1.y = fmaf(aly, f1.y, a1.y);
            a1.z = fmaf(aly, f1.z, a1.z); a1.w = fmaf(aly, f1.w, a1.w);
            a2.x = fmaf(alz, f2.x, a2.x); a2.y = fmaf(alz, f2.y, a2.y);
            a2.z = fmaf(alz, f2.z, a2.z); a2.w = fmaf(alz, f2.w, a2.w);
            a3.x = fmaf(alw, f3.x, a3.x); a3.y = fmaf(alw, f3.y, a3.y);
            a3.z = fmaf(alw, f3.z, a3.z); a3.w = fmaf(alw, f3.w, a3.w);
        }
    } else {
        // fallback: original 3-pass
        float4 mx = make_float4(-FLT_BIG, -FLT_BIG, -FLT_BIG, -FLT_BIG);
        for (int i = lane; i < total; i += 64){
            int s = (i < deg) ? col[rp0 + i] : n;
            float4 ev = *(const float4*)(es + (size_t)s * HEADS);
            mx.x = fmaxf(mx.x, lrelu(ev.x + edv.x));
            mx.y = fmaxf(mx.y, lrelu(ev.y + edv.y));
            mx.z = fmaxf(mx.z, lrelu(ev.z + edv.z));
            mx.w = fmaxf(mx.w, lrelu(ev.w + edv.w));
        }
#pragma unroll
        for (int off = 1; off < 64; off <<= 1){
            mx.x = fmaxf(mx.x, __shfl_xor(mx.x, off));
            mx.y = fmaxf(mx.y, __shfl_xor(mx.y, off));
            mx.z = fmaxf(mx.z, __shfl_xor(mx.z, off));
            mx.w = fmaxf(mx.w, __shfl_xor(mx.w, off));
        }
        float4 sm = make_float4(0.f, 0.f, 0.f, 0.f);
        for (int i = lane; i < total; i += 64){
            int s = (i < deg) ? col[rp0 + i] : n;
            float4 ev = *(const float4*)(es + (size_t)s * HEADS);
            sm.x += expf(lrelu(ev.x + edv.x) - mx.x);
            sm.y += expf(lrelu(ev.y + edv.y) - mx.y);
            sm.z += expf(lrelu(ev.z + edv.z) - mx.z);
            sm.w += expf(lrelu(ev.w + edv.w) - mx.w);
        }
#pragma unroll
        for (int off = 1; off < 64; off <<= 1){
            sm.x += __shfl_xor(sm.x, off);
            sm.y += __shfl_xor(sm.y, off);
            sm.z += __shfl_xor(sm.z, off);
            sm.w += __shfl_xor(sm.w, off);
        }
        float4 inv = make_float4(1.f / (sm.x + 1e-16f), 1.f / (sm.y + 1e-16f),
                                 1.f / (sm.z + 1e-16f), 1.f / (sm.w + 1e-16f));
        for (int i = 0; i < total; ++i){
            int s = (i < deg) ? col[rp0 + i] : n;
            float4 ev = *(const float4*)(es + (size_t)s * HEADS);
            const u16* rowp = hsrc + (size_t)s * DHID;
            ushort4 r0 = *(const ushort4*)(rowp + 0 * CPH + c4);
            ushort4 r1 = *(const ushort4*)(rowp + 1 * CPH + c4);
            ushort4 r2 = *(const ushort4*)(rowp + 2 * CPH + c4);
            ushort4 r3 = *(const ushort4*)(rowp + 3 * CPH + c4);
            float alx = expf(lrelu(ev.x + edv.x) - mx.x) * inv.x;
            float aly = expf(lrelu(ev.y + edv.y) - mx.y) * inv.y;
            float alz = expf(lrelu(ev.z + edv.z) - mx.z) * inv.z;
            float alw = expf(lrelu(ev.w + edv.w) - mx.w) * inv.w;
            float4 f0 = bf4_to_f4(r0), f1 = bf4_to_f4(r1), f2 = bf4_to_f4(r2), f3 = bf4_to_f4(r3);
            a0.x = fmaf(alx, f0.x, a0.x); a0.y = fmaf(alx, f0.y, a0.y);
            a0.z = fmaf(alx, f0.z, a0.z); a0.w = fmaf(alx, f0.w, a0.w);
            a1.x = fmaf(aly, f1.x, a1.x); a1.y = fmaf(aly, f1.y, a1.y);
            a1.z = fmaf(aly, f1.z, a1.z); a1.w = fmaf(aly, f1.w, a1.w);
            a2.x = fmaf(alz, f2.x, a2.x); a2.y = fmaf(alz, f2.y, a2.y);
            a2.z = fmaf(alz, f2.z, a2.z); a2.w = fmaf(alz, f2.w, a2.w);
            a3.x = fmaf(alw, f3.x, a3.x); a3.y = fmaf(alw, f3.y, a3.y);
            a3.z = fmaf(alw, f3.z, a3.z); a3.w = fmaf(alw, f3.w, a3.w);
        }
    }

    // epilogue: +bias, elu, bf16 hi(/lo) store per head
#pragma unroll
    for (int h = 0; h < 4; ++h){
        float4 a = (h == 0) ? a0 : (h == 1) ? a1 : (h == 2) ? a2 : a3;
        int cidx = h * CPH + c4;
        float4 bv = *(const float4*)(bias + cidx);
        float ox = eluf(a.x + bv.x);
        float oy = eluf(a.y + bv.y);
        float oz = eluf(a.z + bv.z);
        float ow = eluf(a.w + bv.w);
        ushort4 h4;
        h4.x = f2bf(ox); h4.y = f2bf(oy); h4.z = f2bf(oz); h4.w = f2bf(ow);
        *(ushort4*)(outhi + (size_t)n * DHID + cidx) = h4;
        if (writeLo){
            ushort4 l4;
            l4.x = f2bf(ox - bf2f(h4.x));
            l4.y = f2bf(oy - bf2f(h4.y));
            l4.z = f2bf(oz - bf2f(h4.z));
            l4.w = f2bf(ow - bf2f(h4.w));
            *(ushort4*)(outlo + (size_t)n * DHID + cidx) = l4;
        }
    }
}

// ---------------- two-stage per-graph mean/max pooling (bf16 input) ----------------
__global__ __launch_bounds__(256) void k_pool_init(float* __restrict__ gsum, float* __restrict__ gmax, int L){
    int i = blockIdx.x * blockDim.x + threadIdx.x;
    if (i < L){ gsum[i] = 0.f; gmax[i] = -FLT_BIG; }
}

__global__ __launch_bounds__(256) void k_pool_partial(const u16* __restrict__ hf,
                                                      const int* __restrict__ batch,
                                                      float* __restrict__ gsum, float* __restrict__ gmax,
                                                      int N){
    int c = blockIdx.y * 256 + threadIdx.x;
    int i0 = blockIdx.x * PCHUNK;
    int i1 = i0 + PCHUNK; if (i1 > N) i1 = N;
    int curg = batch[i0];
    float s = 0.f, m = -FLT_BIG;
    for (int i = i0; i < i1; ++i){
        int g = batch[i];
        if (g != curg){
            atomicAdd(&gsum[(size_t)curg * DHID + c], s);
            atomicMaxF(&gmax[(size_t)curg * DHID + c], m);
            s = 0.f; m = -FLT_BIG; curg = g;
        }
        float v = bf2f(hf[(size_t)i * DHID + c]);
        s += v;
        m = fmaxf(m, v);
    }
    atomicAdd(&gsum[(size_t)curg * DHID + c], s);
    atomicMaxF(&gmax[(size_t)curg * DHID + c], m);
}

__global__ __launch_bounds__(256) void k_pool_final(const float* __restrict__ gsum,
                                                    const float* __restrict__ gmax,
                                                    const int* __restrict__ lo, const int* __restrict__ hi,
                                                    float* __restrict__ gfeat){
    int g = blockIdx.x;
    int c = threadIdx.x * 4;
    int l = lo[g], h2 = hi[g];
    int cnt = (h2 > l) ? (h2 - l) : 0;
    float invc = 1.f / (float)((cnt > 1) ? cnt : 1);
    float4 s = *(const float4*)(gsum + (size_t)g * DHID + c);
    float4 m = *(const float4*)(gmax + (size_t)g * DHID + c);
    float4 mean = make_float4(s.x * invc, s.y * invc, s.z * invc, s.w * invc);
    if (cnt == 0) m = make_float4(0.f, 0.f, 0.f, 0.f);
    *(float4*)(gfeat + (size_t)g * 2048 + c)        = mean;
    *(float4*)(gfeat + (size_t)g * 2048 + 1024 + c) = m;
}

// ---------------- small FC ----------------
__global__ __launch_bounds__(256) void k_fc(const float* __restrict__ X, const float* __restrict__ W,
                                            const float* __restrict__ b, float* __restrict__ Y,
                                            int K, int Nc, int relu){
    __shared__ float xr[2048];
    int r = blockIdx.y;
    int tid = threadIdx.x;
    for (int i = tid; i < K; i += 256) xr[i] = X[(size_t)r * K + i];
    __syncthreads();
    int c = blockIdx.x * 256 + tid;
    if (c >= Nc) return;
    float acc = b[c];
    for (int k = 0; k < K; ++k) acc += xr[k] * W[(size_t)k * Nc + c];
    if (relu) acc = fmaxf(acc, 0.f);
    Y[(size_t)r * Nc + c] = acc;
}

// ---------------- launch ----------------
extern "C" void kernel_launch(void* const* d_in, const int* in_sizes, int n_in,
                              void* d_out, int out_size, void* d_ws, size_t ws_size,
                              hipStream_t stream) {
    const float* x      = (const float*)d_in[0];
    const int*   ei     = (const int*)  d_in[1];
    const int*   batch  = (const int*)  d_in[2];
    const float* W1     = (const float*)d_in[3];
    const float* asrc1  = (const float*)d_in[4];
    const float* adst1  = (const float*)d_in[5];
    const float* b1     = (const float*)d_in[6];
    const float* W2     = (const float*)d_in[7];
    const float* asrc2  = (const float*)d_in[8];
    const float* adst2  = (const float*)d_in[9];
    const float* b2     = (const float*)d_in[10];
    const float* Wc1    = (const float*)d_in[11];
    const float* bc1    = (const float*)d_in[12];
    const float* Wc2    = (const float*)d_in[13];
    const float* bc2    = (const float*)d_in[14];
    const float* Wc3    = (const float*)d_in[15];
    const float* bc3    = (const float*)d_in[16];

    const int N = in_sizes[2];
    const int E = in_sizes[1] / 2;
    const int G = out_size / 5;
    const int DIN = in_sizes[0] / N;

    const int* srcI = ei;
    const int* dstI = ei + E;

    char* p = (char*)d_ws;
    auto alloc = [&](size_t bytes) -> void* {
        void* q = (void*)p;
        p += (bytes + 255) & ~(size_t)255;
        return q;
    };
    u16*   R1     = (u16*)alloc((size_t)N * DHID * 2 * 2);   // activations hi+lo
    u16*   R2     = (u16*)alloc((size_t)N * DHID * 2);       // bf16 h plane
    float* es     = (float*)alloc((size_t)N * HEADS * 4);
    float* ed     = (float*)alloc((size_t)N * HEADS * 4);
    float* gfeat  = (float*)alloc((size_t)G * 2048 * 4);
    float* gsum   = (float*)alloc((size_t)G * DHID * 4);
    float* gmax   = (float*)alloc((size_t)G * DHID * 4);
    float* z1     = (float*)alloc((size_t)G * 512 * 4);
    float* z2     = (float*)alloc((size_t)G * 256 * 4);
    int*   cnt    = (int*)  alloc((size_t)N * 4);
    int*   fill   = (int*)  alloc((size_t)N * 4);
    int*   rowptr = (int*)  alloc((size_t)(N + 1) * 4);
    int*   col    = (int*)  alloc((size_t)E * 4);
    int*   lo     = (int*)  alloc((size_t)G * 4);
    int*   hi     = (int*)  alloc((size_t)G * 4);
    u16*   w1th   = (u16*)  alloc((size_t)DIN * DHID * 2);
    u16*   w1tl   = (u16*)  alloc((size_t)DIN * DHID * 2);
    u16*   w2th   = (u16*)  alloc((size_t)DHID * DHID * 2);
    u16*   w2tl   = (u16*)  alloc((size_t)DHID * DHID * 2);
    float* logits = (float*)d_out;

    int nb = (N + 255) / 256;
    int ebp = (E + 255) / 256;
    int aggb = (N + 3) / 4;

    // CSR + pooling bounds
    k_init   <<<nb,  256, 0, stream>>>(cnt, fill, lo, hi, N, G);
    k_count  <<<ebp, 256, 0, stream>>>(dstI, cnt, E);
    k_scan   <<<1,  1024, 0, stream>>>(cnt, rowptr, N, E);
    k_scatter<<<ebp, 256, 0, stream>>>(srcI, dstI, rowptr, fill, col, E);
    k_bounds <<<nb,  256, 0, stream>>>(batch, lo, hi, N);

    // weight splits (with LDS-tiled transpose)
    k_splitT<<<dim3((DHID + 31) / 32, (DIN + 31) / 32),  256, 0, stream>>>(W1, w1th, w1tl, DIN, DHID);
    k_splitT<<<dim3((DHID + 31) / 32, (DHID + 31) / 32), 256, 0, stream>>>(W2, w2th, w2tl, DHID, DHID);

    // GEMM launched as two half-M dispatches (instrumentation + identical total work)
    int R = (N + 127) / 128;
    int Rh = (R + 1) / 2;         // first-half row-tiles
    int Rl = R - Rh;              // second-half row-tiles
    int Rchunk_h = (Rh + 7) / 8;
    int Rchunk_l = (Rl + 7) / 8;
    dim3 grdH(8, 8 * Rchunk_h);
    dim3 grdL(8, 8 * Rchunk_l);

    // ---- GAT layer 1 ----
    u16* a1h = R1;
    u16* a1l = R1 + (size_t)N * DIN;
    long L41 = (long)N * DIN / 4;
    k_split<<<(unsigned)((L41 + 255) / 256), 256, 0, stream>>>(x, a1h, a1l, L41);
    u16* h1 = R2;
    k_gemm_mfma<<<grdH, 256, 0, stream>>>(a1h, a1l, w1th, w1tl, h1, N, DIN, DHID, Rchunk_h, 0,  Rh);
    k_gemm_mfma<<<grdL, 256, 0, stream>>>(a1h, a1l, w1th, w1tl, h1, N, DIN, DHID, Rchunk_l, Rh, Rl);
    k_esd<<<N, 256, 0, stream>>>(h1, asrc1, adst1, es, ed);
    u16* o1h = R1;
    u16* o1l = R1 + (size_t)N * DHID;
    k_agg<<<aggb, 256, 0, stream>>>(h1, es, ed, rowptr, col, b1, o1h, o1l, 1, N);

    // ---- GAT layer 2 ----
    u16* h2 = R2;
    k_gemm_mfma<<<grdH, 256, 0, stream>>>(o1h, o1l, w2th, w2tl, h2, N, DHID, DHID, Rchunk_h, 0,  Rh);
    k_gemm_mfma<<<grdL, 256, 0, stream>>>(o1h, o1l, w2th, w2tl, h2, N, DHID, DHID, Rchunk_l, Rh, Rl);
    k_esd<<<N, 256, 0, stream>>>(h2, asrc2, adst2, es, ed);
    u16* o2h = R1;
    k_agg<<<aggb, 256, 0, stream>>>(h2, es, ed, rowptr, col, b2, o2h, (u16*)0, 0, N);

    // ---- pooling + classifier ----
    k_pool_init<<<(G * DHID + 255) / 256, 256, 0, stream>>>(gsum, gmax, G * DHID);
    dim3 poolGrd((N + PCHUNK - 1) / PCHUNK, DHID / 256);
    k_pool_partial<<<poolGrd, 256, 0, stream>>>(o2h, batch, gsum, gmax, N);
    k_pool_final<<<G, 256, 0, stream>>>(gsum, gmax, lo, hi, gfeat);

    k_fc<<<dim3(2, G), 256, 0, stream>>>(gfeat, Wc1, bc1, z1, 2048, 512, 1);
    k_fc<<<dim3(1, G), 256, 0, stream>>>(z1,    Wc2, bc2, z2, 512,  256, 1);
    k_fc<<<dim3(1, G), 256, 0, stream>>>(z2,    Wc3, bc3, logits, 256, 5, 0);
}

// Round 9
// 1621.775 us; speedup vs baseline: 1.1950x; 1.1560x over previous
//
#include <hip/hip_runtime.h>
#include <math.h>

#define HEADS 4
#define CPH 256
#define DHID 1024
#define NEG_SLOPE 0.2f
#define FLT_BIG 3.402823466e38f
#define PCHUNK 128

typedef unsigned short u16;
typedef __bf16 bf16x8 __attribute__((ext_vector_type(8)));
typedef float f32x4 __attribute__((ext_vector_type(4)));

__device__ __forceinline__ float lrelu(float x){ return x > 0.f ? x : NEG_SLOPE * x; }
__device__ __forceinline__ float eluf(float x){ return x > 0.f ? x : expf(x) - 1.f; }

__device__ __forceinline__ u16 f2bf(float f){
    unsigned u = __float_as_uint(f);
    u += 0x7fffu + ((u >> 16) & 1u);
    return (u16)(u >> 16);
}
__device__ __forceinline__ float bf2f(u16 h){ return __uint_as_float(((unsigned)h) << 16); }
__device__ __forceinline__ float4 bf4_to_f4(ushort4 u){
    return make_float4(bf2f(u.x), bf2f(u.y), bf2f(u.z), bf2f(u.w));
}

__device__ __forceinline__ void gload_lds16(const void* g, void* l){
    __builtin_amdgcn_global_load_lds((const __attribute__((address_space(1))) unsigned int*)g,
                                     (__attribute__((address_space(3))) unsigned int*)l, 16, 0, 0);
}

__device__ __forceinline__ void atomicMaxF(float* addr, float v){
    if (v >= 0.f) atomicMax((int*)addr, __float_as_int(v));
    else          atomicMin((unsigned int*)addr, __float_as_uint(v));
}

// ---------------- CSR build + pooling bounds ----------------
__global__ void k_init(int* cnt, int* fill, int* lo, int* hi, int N, int G){
    int i = blockIdx.x * blockDim.x + threadIdx.x;
    if (i < N){ cnt[i] = 0; fill[i] = 0; }
    if (i < G){ lo[i] = 0x7fffffff; hi[i] = 0; }
}

__global__ void k_count(const int* __restrict__ dst, int* __restrict__ cnt, int E){
    int e = blockIdx.x * blockDim.x + threadIdx.x;
    if (e < E) atomicAdd(&cnt[dst[e]], 1);
}

__global__ __launch_bounds__(1024) void k_scan(const int* __restrict__ cnt, int* __restrict__ rowptr,
                                               int N, int E){
    __shared__ int tot[1024];
    int tid = threadIdx.x;
    int items = (N + 1023) >> 10;
    int base = tid * items;
    int sum = 0;
    for (int i = 0; i < items; ++i){ int idx = base + i; if (idx < N) sum += cnt[idx]; }
    tot[tid] = sum;
    __syncthreads();
    for (int off = 1; off < 1024; off <<= 1){
        int t = (tid >= off) ? tot[tid - off] : 0;
        __syncthreads();
        tot[tid] += t;
        __syncthreads();
    }
    int run = tot[tid] - sum;
    for (int i = 0; i < items; ++i){
        int idx = base + i;
        if (idx < N){ rowptr[idx] = run; run += cnt[idx]; }
    }
    if (tid == 0) rowptr[N] = E;
}

__global__ void k_scatter(const int* __restrict__ src, const int* __restrict__ dst,
                          const int* __restrict__ rowptr, int* __restrict__ fill,
                          int* __restrict__ col, int E){
    int e = blockIdx.x * blockDim.x + threadIdx.x;
    if (e < E){
        int d = dst[e];
        int pos = rowptr[d] + atomicAdd(&fill[d], 1);
        col[pos] = src[e];
    }
}

// batch is SORTED (reference: jnp.sort; k_pool_partial already relies on it).
// Per-graph [lo,hi) = run boundaries — zero atomics. Old version: 100k device atomics
// onto 64 addresses with 64-way same-address lane conflicts = 288 us (round-8 top-5).
__global__ void k_bounds(const int* __restrict__ batch, int* lo, int* hi, int N){
    int i = blockIdx.x * blockDim.x + threadIdx.x;
    if (i < N){
        int b = batch[i];
        if (i == 0     || batch[i - 1] != b) lo[b] = i;
        if (i == N - 1 || batch[i + 1] != b) hi[b] = i + 1;
    }
}

// ---------------- split kernels ----------------
__global__ void k_split(const float* __restrict__ X, u16* __restrict__ hi, u16* __restrict__ lo, long L4){
    long i = (long)blockIdx.x * blockDim.x + threadIdx.x;
    if (i < L4){
        float4 v = ((const float4*)X)[i];
        ushort4 h, l;
        h.x = f2bf(v.x); l.x = f2bf(v.x - bf2f(h.x));
        h.y = f2bf(v.y); l.y = f2bf(v.y - bf2f(h.y));
        h.z = f2bf(v.z); l.z = f2bf(v.z - bf2f(h.z));
        h.w = f2bf(v.w); l.w = f2bf(v.w - bf2f(h.w));
        ((ushort4*)hi)[i] = h;
        ((ushort4*)lo)[i] = l;
    }
}

// LDS-tiled transpose split: W (K x Nn, row-major) -> hiT/loT (Nn x K, row-major).
__global__ __launch_bounds__(256) void k_splitT(const float* __restrict__ W, u16* __restrict__ hiT,
                                                u16* __restrict__ loT, int K, int Nn){
    __shared__ float t[32][33];
    int n0 = blockIdx.x * 32;
    int k0 = blockIdx.y * 32;
    int tx = threadIdx.x & 31, ty = threadIdx.x >> 5;   // 8 rows per pass
    for (int r = ty; r < 32; r += 8){
        int k = k0 + r, n = n0 + tx;
        t[r][tx] = (k < K && n < Nn) ? W[(size_t)k * Nn + n] : 0.f;
    }
    __syncthreads();
    for (int r = ty; r < 32; r += 8){
        int n = n0 + r, k = k0 + tx;
        if (n < Nn && k < K){
            float v = t[tx][r];
            u16 h = f2bf(v);
            hiT[(size_t)n * K + k] = h;
            loT[(size_t)n * K + k] = f2bf(v - bf2f(h));
        }
    }
}

// ---------------- split-bf16 MFMA GEMM (16x16x32), 128x128 tile — round-0 verified best ----------------
// Launched as two half-M dispatches: same total work; keeps non-GEMM kernels visible in top-5.
__global__ __launch_bounds__(256) void k_gemm_mfma(
    const u16* __restrict__ Ahi, const u16* __restrict__ Alo,
    const u16* __restrict__ BThi, const u16* __restrict__ BTlo,
    u16* __restrict__ Cbf, int M, int K, int Nn, int Rchunk, int rowbase, int Rd)
{
    __shared__ __align__(16) u16 As[2][128][32];
    __shared__ __align__(16) u16 Bs[2][128][32];
    int tid = threadIdx.x;
    int w = tid >> 6, lane = tid & 63;

    int by = blockIdx.x * Rchunk + (blockIdx.y >> 3);   // gridDim.x==8 (XCD swizzle)
    int bx = blockIdx.y & 7;
    if (by >= Rd) return;
    int row0 = (rowbase + by) * 128, col0 = bx * 128;

    int srow = tid >> 2;
    int skoff = (tid & 3) * 8;

    int wm = (w >> 1) * 64, wn = (w & 1) * 64;
    int fr = lane & 15;
    int fq = lane >> 4;

    f32x4 acc[4][4];
#pragma unroll
    for (int i = 0; i < 4; ++i)
#pragma unroll
        for (int j = 0; j < 4; ++j){ acc[i][j].x = 0.f; acc[i][j].y = 0.f; acc[i][j].z = 0.f; acc[i][j].w = 0.f; }

    int ra0 = row0 + srow;      if (ra0 >= M) ra0 = M - 1;
    int ra1 = row0 + srow + 64; if (ra1 >= M) ra1 = M - 1;
    int rb0 = col0 + srow;
    int rb1 = col0 + srow + 64;

    for (int k0 = 0; k0 < K; k0 += 32){
        size_t ga0 = (size_t)ra0 * K + k0 + skoff;
        size_t ga1 = (size_t)ra1 * K + k0 + skoff;
        size_t gb0 = (size_t)rb0 * K + k0 + skoff;
        size_t gb1 = (size_t)rb1 * K + k0 + skoff;
        gload_lds16(Ahi  + ga0, &As[0][srow     ][skoff]);
        gload_lds16(Ahi  + ga1, &As[0][srow + 64][skoff]);
        gload_lds16(Alo  + ga0, &As[1][srow     ][skoff]);
        gload_lds16(Alo  + ga1, &As[1][srow + 64][skoff]);
        gload_lds16(BThi + gb0, &Bs[0][srow     ][skoff]);
        gload_lds16(BThi + gb1, &Bs[0][srow + 64][skoff]);
        gload_lds16(BTlo + gb0, &Bs[1][srow     ][skoff]);
        gload_lds16(BTlo + gb1, &Bs[1][srow + 64][skoff]);
        __syncthreads();

        bf16x8 ah[4], al[4], bh[4], bl[4];
#pragma unroll
        for (int i = 0; i < 4; ++i){
            ah[i] = *(const bf16x8*)&As[0][wm + i * 16 + fr][fq * 8];
            al[i] = *(const bf16x8*)&As[1][wm + i * 16 + fr][fq * 8];
            bh[i] = *(const bf16x8*)&Bs[0][wn + i * 16 + fr][fq * 8];
            bl[i] = *(const bf16x8*)&Bs[1][wn + i * 16 + fr][fq * 8];
        }
#pragma unroll
        for (int i = 0; i < 4; ++i)
#pragma unroll
            for (int j = 0; j < 4; ++j){
                acc[i][j] = __builtin_amdgcn_mfma_f32_16x16x32_bf16(ah[i], bh[j], acc[i][j], 0, 0, 0);
                acc[i][j] = __builtin_amdgcn_mfma_f32_16x16x32_bf16(ah[i], bl[j], acc[i][j], 0, 0, 0);
                acc[i][j] = __builtin_amdgcn_mfma_f32_16x16x32_bf16(al[i], bh[j], acc[i][j], 0, 0, 0);
            }
        __syncthreads();
    }

#pragma unroll
    for (int i = 0; i < 4; ++i){
#pragma unroll
        for (int j = 0; j < 4; ++j){
            int colc = col0 + wn + j * 16 + fr;
#pragma unroll
            for (int r = 0; r < 4; ++r){
                int row = row0 + wm + i * 16 + fq * 4 + r;
                if (row < M) Cbf[(size_t)row * Nn + colc] = f2bf(acc[i][j][r]);
            }
        }
    }
}

// ---------------- per-node attention score dots (bf16 h) ----------------
__global__ __launch_bounds__(256) void k_esd(const u16* __restrict__ h, const float* __restrict__ asrc,
                                             const float* __restrict__ adst,
                                             float* __restrict__ es, float* __restrict__ ed){
    int n = blockIdx.x;
    int tid = threadIdx.x;
    int w = tid >> 6, lane = tid & 63;
    float4 hv = bf4_to_f4(*(const ushort4*)(h + (size_t)n * DHID + w * CPH + lane * 4));
    float4 av = *(const float4*)(asrc + w * CPH + lane * 4);
    float4 dv = *(const float4*)(adst + w * CPH + lane * 4);
    float s = hv.x * av.x + hv.y * av.y + hv.z * av.z + hv.w * av.w;
    float d = hv.x * dv.x + hv.y * dv.y + hv.z * dv.z + hv.w * dv.w;
    for (int off = 32; off > 0; off >>= 1){
        s += __shfl_down(s, off);
        d += __shfl_down(d, off);
    }
    if (lane == 0){ es[n * HEADS + w] = s; ed[n * HEADS + w] = d; }
}

// ---------------- wave-per-node segment softmax + aggregation + bias + elu + split write ----------------
__global__ __launch_bounds__(256) void k_agg(const u16* __restrict__ hsrc, const float* __restrict__ es,
                                             const float* __restrict__ ed, const int* __restrict__ rowptr,
                                             const int* __restrict__ col, const float* __restrict__ bias,
                                             u16* __restrict__ outhi, u16* __restrict__ outlo,
                                             int writeLo, int N){
    int n = blockIdx.x * 4 + (threadIdx.x >> 6);
    if (n >= N) return;
    int lane = threadIdx.x & 63;
    int rp0 = rowptr[n];
    int deg = rowptr[n + 1] - rp0;
    int total = deg + 1;                         // + implicit self-loop
    float4 edv = *(const float4*)(ed + (size_t)n * HEADS);

    float4 a0 = make_float4(0.f,0.f,0.f,0.f), a1 = a0, a2 = a0, a3 = a0;
    int c4 = lane * 4;

    if (total <= 64){
        // per-lane edge score (lane i owns edge i)
        int sl = (lane < deg) ? col[rp0 + lane] : n;
        float4 ev = *(const float4*)(es + (size_t)sl * HEADS);
        bool valid = (lane < total);
        float ex = valid ? lrelu(ev.x + edv.x) : -FLT_BIG;
        float ey = valid ? lrelu(ev.y + edv.y) : -FLT_BIG;
        float ez = valid ? lrelu(ev.z + edv.z) : -FLT_BIG;
        float ew = valid ? lrelu(ev.w + edv.w) : -FLT_BIG;
        float mxx = ex, mxy = ey, mxz = ez, mxw = ew;
#pragma unroll
        for (int off = 1; off < 64; off <<= 1){
            mxx = fmaxf(mxx, __shfl_xor(mxx, off));
            mxy = fmaxf(mxy, __shfl_xor(mxy, off));
            mxz = fmaxf(mxz, __shfl_xor(mxz, off));
            mxw = fmaxf(mxw, __shfl_xor(mxw, off));
        }
        float px = valid ? expf(ex - mxx) : 0.f;
        float py = valid ? expf(ey - mxy) : 0.f;
        float pz = valid ? expf(ez - mxz) : 0.f;
        float pw = valid ? expf(ew - mxw) : 0.f;
        float sx = px, sy = py, sz = pz, sw = pw;
#pragma unroll
        for (int off = 1; off < 64; off <<= 1){
            sx += __shfl_xor(sx, off);
            sy += __shfl_xor(sy, off);
            sz += __shfl_xor(sz, off);
            sw += __shfl_xor(sw, off);
        }
        float alx_l = px / (sx + 1e-16f);
        float aly_l = py / (sy + 1e-16f);
        float alz_l = pz / (sz + 1e-16f);
        float alw_l = pw / (sw + 1e-16f);

        for (int i = 0; i < total; ++i){
            int s = (i < deg) ? col[rp0 + i] : n;       // wave-uniform
            float alx = __shfl(alx_l, i);
            float aly = __shfl(aly_l, i);
            float alz = __shfl(alz_l, i);
            float alw = __shfl(alw_l, i);
            const u16* rowp = hsrc + (size_t)s * DHID;
            ushort4 r0 = *(const ushort4*)(rowp + 0 * CPH + c4);
            ushort4 r1 = *(const ushort4*)(rowp + 1 * CPH + c4);
            ushort4 r2 = *(const ushort4*)(rowp + 2 * CPH + c4);
            ushort4 r3 = *(const ushort4*)(rowp + 3 * CPH + c4);
            float4 f0 = bf4_to_f4(r0), f1 = bf4_to_f4(r1), f2 = bf4_to_f4(r2), f3 = bf4_to_f4(r3);
            a0.x = fmaf(alx, f0.x, a0.x); a0.y = fmaf(alx, f0.y, a0.y);
            a0.z = fmaf(alx, f0.z, a0.z); a0.w = fmaf(alx, f0.w, a0.w);
            a1.x = fmaf(aly, f1.x, a1.x); a1.y = fmaf(aly, f1.y, a1.y);
            a1.z = fmaf(aly, f1.z, a1.z); a1.w = fmaf(aly, f1.w, a1.w);
            a2.x = fmaf(alz, f2.x, a2.x); a2.y = fmaf(alz, f2.y, a2.y);
            a2.z = fmaf(alz, f2.z, a2.z); a2.w = fmaf(alz, f2.w, a2.w);
            a3.x = fmaf(alw, f3.x, a3.x); a3.y = fmaf(alw, f3.y, a3.y);
            a3.z = fmaf(alw, f3.z, a3.z); a3.w = fmaf(alw, f3.w, a3.w);
        }
    } else {
        // fallback: original 3-pass
        float4 mx = make_float4(-FLT_BIG, -FLT_BIG, -FLT_BIG, -FLT_BIG);
        for (int i = lane; i < total; i += 64){
            int s = (i < deg) ? col[rp0 + i] : n;
            float4 ev = *(const float4*)(es + (size_t)s * HEADS);
            mx.x = fmaxf(mx.x, lrelu(ev.x + edv.x));
            mx.y = fmaxf(mx.y, lrelu(ev.y + edv.y));
            mx.z = fmaxf(mx.z, lrelu(ev.z + edv.z));
            mx.w = fmaxf(mx.w, lrelu(ev.w + edv.w));
        }
#pragma unroll
        for (int off = 1; off < 64; off <<= 1){
            mx.x = fmaxf(mx.x, __shfl_xor(mx.x, off));
            mx.y = fmaxf(mx.y, __shfl_xor(mx.y, off));
            mx.z = fmaxf(mx.z, __shfl_xor(mx.z, off));
            mx.w = fmaxf(mx.w, __shfl_xor(mx.w, off));
        }
        float4 sm = make_float4(0.f, 0.f, 0.f, 0.f);
        for (int i = lane; i < total; i += 64){
            int s = (i < deg) ? col[rp0 + i] : n;
            float4 ev = *(const float4*)(es + (size_t)s * HEADS);
            sm.x += expf(lrelu(ev.x + edv.x) - mx.x);
            sm.y += expf(lrelu(ev.y + edv.y) - mx.y);
            sm.z += expf(lrelu(ev.z + edv.z) - mx.z);
            sm.w += expf(lrelu(ev.w + edv.w) - mx.w);
        }
#pragma unroll
        for (int off = 1; off < 64; off <<= 1){
            sm.x += __shfl_xor(sm.x, off);
            sm.y += __shfl_xor(sm.y, off);
            sm.z += __shfl_xor(sm.z, off);
            sm.w += __shfl_xor(sm.w, off);
        }
        float4 inv = make_float4(1.f / (sm.x + 1e-16f), 1.f / (sm.y + 1e-16f),
                                 1.f / (sm.z + 1e-16f), 1.f / (sm.w + 1e-16f));
        for (int i = 0; i < total; ++i){
            int s = (i < deg) ? col[rp0 + i] : n;
            float4 ev = *(const float4*)(es + (size_t)s * HEADS);
            const u16* rowp = hsrc + (size_t)s * DHID;
            ushort4 r0 = *(const ushort4*)(rowp + 0 * CPH + c4);
            ushort4 r1 = *(const ushort4*)(rowp + 1 * CPH + c4);
            ushort4 r2 = *(const ushort4*)(rowp + 2 * CPH + c4);
            ushort4 r3 = *(const ushort4*)(rowp + 3 * CPH + c4);
            float alx = expf(lrelu(ev.x + edv.x) - mx.x) * inv.x;
            float aly = expf(lrelu(ev.y + edv.y) - mx.y) * inv.y;
            float alz = expf(lrelu(ev.z + edv.z) - mx.z) * inv.z;
            float alw = expf(lrelu(ev.w + edv.w) - mx.w) * inv.w;
            float4 f0 = bf4_to_f4(r0), f1 = bf4_to_f4(r1), f2 = bf4_to_f4(r2), f3 = bf4_to_f4(r3);
            a0.x = fmaf(alx, f0.x, a0.x); a0.y = fmaf(alx, f0.y, a0.y);
            a0.z = fmaf(alx, f0.z, a0.z); a0.w = fmaf(alx, f0.w, a0.w);
            a1.x = fmaf(aly, f1.x, a1.x); a1.y = fmaf(aly, f1.y, a1.y);
            a1.z = fmaf(aly, f1.z, a1.z); a1.w = fmaf(aly, f1.w, a1.w);
            a2.x = fmaf(alz, f2.x, a2.x); a2.y = fmaf(alz, f2.y, a2.y);
            a2.z = fmaf(alz, f2.z, a2.z); a2.w = fmaf(alz, f2.w, a2.w);
            a3.x = fmaf(alw, f3.x, a3.x); a3.y = fmaf(alw, f3.y, a3.y);
            a3.z = fmaf(alw, f3.z, a3.z); a3.w = fmaf(alw, f3.w, a3.w);
        }
    }

    // epilogue: +bias, elu, bf16 hi(/lo) store per head
#pragma unroll
    for (int h = 0; h < 4; ++h){
        float4 a = (h == 0) ? a0 : (h == 1) ? a1 : (h == 2) ? a2 : a3;
        int cidx = h * CPH + c4;
        float4 bv = *(const float4*)(bias + cidx);
        float ox = eluf(a.x + bv.x);
        float oy = eluf(a.y + bv.y);
        float oz = eluf(a.z + bv.z);
        float ow = eluf(a.w + bv.w);
        ushort4 h4;
        h4.x = f2bf(ox); h4.y = f2bf(oy); h4.z = f2bf(oz); h4.w = f2bf(ow);
        *(ushort4*)(outhi + (size_t)n * DHID + cidx) = h4;
        if (writeLo){
            ushort4 l4;
            l4.x = f2bf(ox - bf2f(h4.x));
            l4.y = f2bf(oy - bf2f(h4.y));
            l4.z = f2bf(oz - bf2f(h4.z));
            l4.w = f2bf(ow - bf2f(h4.w));
            *(ushort4*)(outlo + (size_t)n * DHID + cidx) = l4;
        }
    }
}

// ---------------- two-stage per-graph mean/max pooling (bf16 input) ----------------
__global__ __launch_bounds__(256) void k_pool_init(float* __restrict__ gsum, float* __restrict__ gmax, int L){
    int i = blockIdx.x * blockDim.x + threadIdx.x;
    if (i < L){ gsum[i] = 0.f; gmax[i] = -FLT_BIG; }
}

__global__ __launch_bounds__(256) void k_pool_partial(const u16* __restrict__ hf,
                                                      const int* __restrict__ batch,
                                                      float* __restrict__ gsum, float* __restrict__ gmax,
                                                      int N){
    int c = blockIdx.y * 256 + threadIdx.x;
    int i0 = blockIdx.x * PCHUNK;
    int i1 = i0 + PCHUNK; if (i1 > N) i1 = N;
    int curg = batch[i0];
    float s = 0.f, m = -FLT_BIG;
    for (int i = i0; i < i1; ++i){
        int g = batch[i];
        if (g != curg){
            atomicAdd(&gsum[(size_t)curg * DHID + c], s);
            atomicMaxF(&gmax[(size_t)curg * DHID + c], m);
            s = 0.f; m = -FLT_BIG; curg = g;
        }
        float v = bf2f(hf[(size_t)i * DHID + c]);
        s += v;
        m = fmaxf(m, v);
    }
    atomicAdd(&gsum[(size_t)curg * DHID + c], s);
    atomicMaxF(&gmax[(size_t)curg * DHID + c], m);
}

__global__ __launch_bounds__(256) void k_pool_final(const float* __restrict__ gsum,
                                                    const float* __restrict__ gmax,
                                                    const int* __restrict__ lo, const int* __restrict__ hi,
                                                    float* __restrict__ gfeat){
    int g = blockIdx.x;
    int c = threadIdx.x * 4;
    int l = lo[g], h2 = hi[g];
    int cnt = (h2 > l) ? (h2 - l) : 0;
    float invc = 1.f / (float)((cnt > 1) ? cnt : 1);
    float4 s = *(const float4*)(gsum + (size_t)g * DHID + c);
    float4 m = *(const float4*)(gmax + (size_t)g * DHID + c);
    float4 mean = make_float4(s.x * invc, s.y * invc, s.z * invc, s.w * invc);
    if (cnt == 0) m = make_float4(0.f, 0.f, 0.f, 0.f);
    *(float4*)(gfeat + (size_t)g * 2048 + c)        = mean;
    *(float4*)(gfeat + (size_t)g * 2048 + 1024 + c) = m;
}

// ---------------- small FC ----------------
__global__ __launch_bounds__(256) void k_fc(const float* __restrict__ X, const float* __restrict__ W,
                                            const float* __restrict__ b, float* __restrict__ Y,
                                            int K, int Nc, int relu){
    __shared__ float xr[2048];
    int r = blockIdx.y;
    int tid = threadIdx.x;
    for (int i = tid; i < K; i += 256) xr[i] = X[(size_t)r * K + i];
    __syncthreads();
    int c = blockIdx.x * 256 + tid;
    if (c >= Nc) return;
    float acc = b[c];
    for (int k = 0; k < K; ++k) acc += xr[k] * W[(size_t)k * Nc + c];
    if (relu) acc = fmaxf(acc, 0.f);
    Y[(size_t)r * Nc + c] = acc;
}

// ---------------- launch ----------------
extern "C" void kernel_launch(void* const* d_in, const int* in_sizes, int n_in,
                              void* d_out, int out_size, void* d_ws, size_t ws_size,
                              hipStream_t stream) {
    const float* x      = (const float*)d_in[0];
    const int*   ei     = (const int*)  d_in[1];
    const int*   batch  = (const int*)  d_in[2];
    const float* W1     = (const float*)d_in[3];
    const float* asrc1  = (const float*)d_in[4];
    const float* adst1  = (const float*)d_in[5];
    const float* b1     = (const float*)d_in[6];
    const float* W2     = (const float*)d_in[7];
    const float* asrc2  = (const float*)d_in[8];
    const float* adst2  = (const float*)d_in[9];
    const float* b2     = (const float*)d_in[10];
    const float* Wc1    = (const float*)d_in[11];
    const float* bc1    = (const float*)d_in[12];
    const float* Wc2    = (const float*)d_in[13];
    const float* bc2    = (const float*)d_in[14];
    const float* Wc3    = (const float*)d_in[15];
    const float* bc3    = (const float*)d_in[16];

    const int N = in_sizes[2];
    const int E = in_sizes[1] / 2;
    const int G = out_size / 5;
    const int DIN = in_sizes[0] / N;

    const int* srcI = ei;
    const int* dstI = ei + E;

    char* p = (char*)d_ws;
    auto alloc = [&](size_t bytes) -> void* {
        void* q = (void*)p;
        p += (bytes + 255) & ~(size_t)255;
        return q;
    };
    u16*   R1     = (u16*)alloc((size_t)N * DHID * 2 * 2);   // activations hi+lo
    u16*   R2     = (u16*)alloc((size_t)N * DHID * 2);       // bf16 h plane
    float* es     = (float*)alloc((size_t)N * HEADS * 4);
    float* ed     = (float*)alloc((size_t)N * HEADS * 4);
    float* gfeat  = (float*)alloc((size_t)G * 2048 * 4);
    float* gsum   = (float*)alloc((size_t)G * DHID * 4);
    float* gmax   = (float*)alloc((size_t)G * DHID * 4);
    float* z1     = (float*)alloc((size_t)G * 512 * 4);
    float* z2     = (float*)alloc((size_t)G * 256 * 4);
    int*   cnt    = (int*)  alloc((size_t)N * 4);
    int*   fill   = (int*)  alloc((size_t)N * 4);
    int*   rowptr = (int*)  alloc((size_t)(N + 1) * 4);
    int*   col    = (int*)  alloc((size_t)E * 4);
    int*   lo     = (int*)  alloc((size_t)G * 4);
    int*   hi     = (int*)  alloc((size_t)G * 4);
    u16*   w1th   = (u16*)  alloc((size_t)DIN * DHID * 2);
    u16*   w1tl   = (u16*)  alloc((size_t)DIN * DHID * 2);
    u16*   w2th   = (u16*)  alloc((size_t)DHID * DHID * 2);
    u16*   w2tl   = (u16*)  alloc((size_t)DHID * DHID * 2);
    float* logits = (float*)d_out;

    int nb = (N + 255) / 256;
    int ebp = (E + 255) / 256;
    int aggb = (N + 3) / 4;

    // CSR + pooling bounds
    k_init   <<<nb,  256, 0, stream>>>(cnt, fill, lo, hi, N, G);
    k_count  <<<ebp, 256, 0, stream>>>(dstI, cnt, E);
    k_scan   <<<1,  1024, 0, stream>>>(cnt, rowptr, N, E);
    k_scatter<<<ebp, 256, 0, stream>>>(srcI, dstI, rowptr, fill, col, E);
    k_bounds <<<nb,  256, 0, stream>>>(batch, lo, hi, N);

    // weight splits (with LDS-tiled transpose)
    k_splitT<<<dim3((DHID + 31) / 32, (DIN + 31) / 32),  256, 0, stream>>>(W1, w1th, w1tl, DIN, DHID);
    k_splitT<<<dim3((DHID + 31) / 32, (DHID + 31) / 32), 256, 0, stream>>>(W2, w2th, w2tl, DHID, DHID);

    // GEMM launched as two half-M dispatches (instrumentation + identical total work)
    int R = (N + 127) / 128;
    int Rh = (R + 1) / 2;         // first-half row-tiles
    int Rl = R - Rh;              // second-half row-tiles
    int Rchunk_h = (Rh + 7) / 8;
    int Rchunk_l = (Rl + 7) / 8;
    dim3 grdH(8, 8 * Rchunk_h);
    dim3 grdL(8, 8 * Rchunk_l);

    // ---- GAT layer 1 ----
    u16* a1h = R1;
    u16* a1l = R1 + (size_t)N * DIN;
    long L41 = (long)N * DIN / 4;
    k_split<<<(unsigned)((L41 + 255) / 256), 256, 0, stream>>>(x, a1h, a1l, L41);
    u16* h1 = R2;
    k_gemm_mfma<<<grdH, 256, 0, stream>>>(a1h, a1l, w1th, w1tl, h1, N, DIN, DHID, Rchunk_h, 0,  Rh);
    k_gemm_mfma<<<grdL, 256, 0, stream>>>(a1h, a1l, w1th, w1tl, h1, N, DIN, DHID, Rchunk_l, Rh, Rl);
    k_esd<<<N, 256, 0, stream>>>(h1, asrc1, adst1, es, ed);
    u16* o1h = R1;
    u16* o1l = R1 + (size_t)N * DHID;
    k_agg<<<aggb, 256, 0, stream>>>(h1, es, ed, rowptr, col, b1, o1h, o1l, 1, N);

    // ---- GAT layer 2 ----
    u16* h2 = R2;
    k_gemm_mfma<<<grdH, 256, 0, stream>>>(o1h, o1l, w2th, w2tl, h2, N, DHID, DHID, Rchunk_h, 0,  Rh);
    k_gemm_mfma<<<grdL, 256, 0, stream>>>(o1h, o1l, w2th, w2tl, h2, N, DHID, DHID, Rchunk_l, Rh, Rl);
    k_esd<<<N, 256, 0, stream>>>(h2, asrc2, adst2, es, ed);
    u16* o2h = R1;
    k_agg<<<aggb, 256, 0, stream>>>(h2, es, ed, rowptr, col, b2, o2h, (u16*)0, 0, N);

    // ---- pooling + classifier ----
    k_pool_init<<<(G * DHID + 255) / 256, 256, 0, stream>>>(gsum, gmax, G * DHID);
    dim3 poolGrd((N + PCHUNK - 1) / PCHUNK, DHID / 256);
    k_pool_partial<<<poolGrd, 256, 0, stream>>>(o2h, batch, gsum, gmax, N);
    k_pool_final<<<G, 256, 0, stream>>>(gsum, gmax, lo, hi, gfeat);

    k_fc<<<dim3(2, G), 256, 0, stream>>>(gfeat, Wc1, bc1, z1, 2048, 512, 1);
    k_fc<<<dim3(1, G), 256, 0, stream>>>(z1,    Wc2, bc2, z2, 512,  256, 1);
    k_fc<<<dim3(1, G), 256, 0, stream>>>(z2,    Wc3, bc3, logits, 256, 5, 0);
}

// Round 10
// 1387.522 us; speedup vs baseline: 1.3968x; 1.1688x over previous
//
#include <hip/hip_runtime.h>
#include <math.h>

#define HEADS 4
#define CPH 256
#define DHID 1024
#define NEG_SLOPE 0.2f
#define FLT_BIG 3.402823466e38f
#define PCHUNK 128

typedef unsigned short u16;
typedef __bf16 bf16x8 __attribute__((ext_vector_type(8)));
typedef float f32x4 __attribute__((ext_vector_type(4)));

__device__ __forceinline__ float lrelu(float x){ return x > 0.f ? x : NEG_SLOPE * x; }
__device__ __forceinline__ float eluf(float x){ return x > 0.f ? x : expf(x) - 1.f; }

__device__ __forceinline__ u16 f2bf(float f){
    unsigned u = __float_as_uint(f);
    u += 0x7fffu + ((u >> 16) & 1u);
    return (u16)(u >> 16);
}
__device__ __forceinline__ float bf2f(u16 h){ return __uint_as_float(((unsigned)h) << 16); }
__device__ __forceinline__ float4 bf4_to_f4(ushort4 u){
    return make_float4(bf2f(u.x), bf2f(u.y), bf2f(u.z), bf2f(u.w));
}

__device__ __forceinline__ void gload_lds16(const void* g, void* l){
    __builtin_amdgcn_global_load_lds((const __attribute__((address_space(1))) unsigned int*)g,
                                     (__attribute__((address_space(3))) unsigned int*)l, 16, 0, 0);
}

__device__ __forceinline__ void atomicMaxF(float* addr, float v){
    if (v >= 0.f) atomicMax((int*)addr, __float_as_int(v));
    else          atomicMin((unsigned int*)addr, __float_as_uint(v));
}

// ---------------- CSR build + pooling bounds ----------------
__global__ void k_init(int* cnt, int* fill, int* lo, int* hi, int N, int G){
    int i = blockIdx.x * blockDim.x + threadIdx.x;
    if (i < N){ cnt[i] = 0; fill[i] = 0; }
    if (i < G){ lo[i] = 0x7fffffff; hi[i] = 0; }
}

__global__ void k_count(const int* __restrict__ dst, int* __restrict__ cnt, int E){
    int e = blockIdx.x * blockDim.x + threadIdx.x;
    if (e < E) atomicAdd(&cnt[dst[e]], 1);
}

__global__ __launch_bounds__(1024) void k_scan(const int* __restrict__ cnt, int* __restrict__ rowptr,
                                               int N, int E){
    __shared__ int tot[1024];
    int tid = threadIdx.x;
    int items = (N + 1023) >> 10;
    int base = tid * items;
    int sum = 0;
    for (int i = 0; i < items; ++i){ int idx = base + i; if (idx < N) sum += cnt[idx]; }
    tot[tid] = sum;
    __syncthreads();
    for (int off = 1; off < 1024; off <<= 1){
        int t = (tid >= off) ? tot[tid - off] : 0;
        __syncthreads();
        tot[tid] += t;
        __syncthreads();
    }
    int run = tot[tid] - sum;
    for (int i = 0; i < items; ++i){
        int idx = base + i;
        if (idx < N){ rowptr[idx] = run; run += cnt[idx]; }
    }
    if (tid == 0) rowptr[N] = E;
}

__global__ void k_scatter(const int* __restrict__ src, const int* __restrict__ dst,
                          const int* __restrict__ rowptr, int* __restrict__ fill,
                          int* __restrict__ col, int E){
    int e = blockIdx.x * blockDim.x + threadIdx.x;
    if (e < E){
        int d = dst[e];
        int pos = rowptr[d] + atomicAdd(&fill[d], 1);
        col[pos] = src[e];
    }
}

// batch is SORTED — per-graph [lo,hi) = run boundaries, zero atomics (was 288 us of
// 64-way same-address atomic serialization; now ~5 us).
__global__ void k_bounds(const int* __restrict__ batch, int* lo, int* hi, int N){
    int i = blockIdx.x * blockDim.x + threadIdx.x;
    if (i < N){
        int b = batch[i];
        if (i == 0     || batch[i - 1] != b) lo[b] = i;
        if (i == N - 1 || batch[i + 1] != b) hi[b] = i + 1;
    }
}

// ---------------- split kernels ----------------
__global__ void k_split(const float* __restrict__ X, u16* __restrict__ hi, u16* __restrict__ lo, long L4){
    long i = (long)blockIdx.x * blockDim.x + threadIdx.x;
    if (i < L4){
        float4 v = ((const float4*)X)[i];
        ushort4 h, l;
        h.x = f2bf(v.x); l.x = f2bf(v.x - bf2f(h.x));
        h.y = f2bf(v.y); l.y = f2bf(v.y - bf2f(h.y));
        h.z = f2bf(v.z); l.z = f2bf(v.z - bf2f(h.z));
        h.w = f2bf(v.w); l.w = f2bf(v.w - bf2f(h.w));
        ((ushort4*)hi)[i] = h;
        ((ushort4*)lo)[i] = l;
    }
}

// LDS-tiled transpose split: W (K x Nn, row-major) -> hiT/loT (Nn x K, row-major).
__global__ __launch_bounds__(256) void k_splitT(const float* __restrict__ W, u16* __restrict__ hiT,
                                                u16* __restrict__ loT, int K, int Nn){
    __shared__ float t[32][33];
    int n0 = blockIdx.x * 32;
    int k0 = blockIdx.y * 32;
    int tx = threadIdx.x & 31, ty = threadIdx.x >> 5;   // 8 rows per pass
    for (int r = ty; r < 32; r += 8){
        int k = k0 + r, n = n0 + tx;
        t[r][tx] = (k < K && n < Nn) ? W[(size_t)k * Nn + n] : 0.f;
    }
    __syncthreads();
    for (int r = ty; r < 32; r += 8){
        int n = n0 + r, k = k0 + tx;
        if (n < Nn && k < K){
            float v = t[tx][r];
            u16 h = f2bf(v);
            hiT[(size_t)n * K + k] = h;
            loT[(size_t)n * K + k] = f2bf(v - bf2f(h));
        }
    }
}

// ---------------- split-bf16 MFMA GEMM (16x16x32), 128x128 tile — round-0 verified best ----------------
// Launched as two half-M dispatches: same total work; keeps non-GEMM kernels visible in top-5.
__global__ __launch_bounds__(256) void k_gemm_mfma(
    const u16* __restrict__ Ahi, const u16* __restrict__ Alo,
    const u16* __restrict__ BThi, const u16* __restrict__ BTlo,
    u16* __restrict__ Cbf, int M, int K, int Nn, int Rchunk, int rowbase, int Rd)
{
    __shared__ __align__(16) u16 As[2][128][32];
    __shared__ __align__(16) u16 Bs[2][128][32];
    int tid = threadIdx.x;
    int w = tid >> 6, lane = tid & 63;

    int by = blockIdx.x * Rchunk + (blockIdx.y >> 3);   // gridDim.x==8 (XCD swizzle)
    int bx = blockIdx.y & 7;
    if (by >= Rd) return;
    int row0 = (rowbase + by) * 128, col0 = bx * 128;

    int srow = tid >> 2;
    int skoff = (tid & 3) * 8;

    int wm = (w >> 1) * 64, wn = (w & 1) * 64;
    int fr = lane & 15;
    int fq = lane >> 4;

    f32x4 acc[4][4];
#pragma unroll
    for (int i = 0; i < 4; ++i)
#pragma unroll
        for (int j = 0; j < 4; ++j){ acc[i][j].x = 0.f; acc[i][j].y = 0.f; acc[i][j].z = 0.f; acc[i][j].w = 0.f; }

    int ra0 = row0 + srow;      if (ra0 >= M) ra0 = M - 1;
    int ra1 = row0 + srow + 64; if (ra1 >= M) ra1 = M - 1;
    int rb0 = col0 + srow;
    int rb1 = col0 + srow + 64;

    for (int k0 = 0; k0 < K; k0 += 32){
        size_t ga0 = (size_t)ra0 * K + k0 + skoff;
        size_t ga1 = (size_t)ra1 * K + k0 + skoff;
        size_t gb0 = (size_t)rb0 * K + k0 + skoff;
        size_t gb1 = (size_t)rb1 * K + k0 + skoff;
        gload_lds16(Ahi  + ga0, &As[0][srow     ][skoff]);
        gload_lds16(Ahi  + ga1, &As[0][srow + 64][skoff]);
        gload_lds16(Alo  + ga0, &As[1][srow     ][skoff]);
        gload_lds16(Alo  + ga1, &As[1][srow + 64][skoff]);
        gload_lds16(BThi + gb0, &Bs[0][srow     ][skoff]);
        gload_lds16(BThi + gb1, &Bs[0][srow + 64][skoff]);
        gload_lds16(BTlo + gb0, &Bs[1][srow     ][skoff]);
        gload_lds16(BTlo + gb1, &Bs[1][srow + 64][skoff]);
        __syncthreads();

        bf16x8 ah[4], al[4], bh[4], bl[4];
#pragma unroll
        for (int i = 0; i < 4; ++i){
            ah[i] = *(const bf16x8*)&As[0][wm + i * 16 + fr][fq * 8];
            al[i] = *(const bf16x8*)&As[1][wm + i * 16 + fr][fq * 8];
            bh[i] = *(const bf16x8*)&Bs[0][wn + i * 16 + fr][fq * 8];
            bl[i] = *(const bf16x8*)&Bs[1][wn + i * 16 + fr][fq * 8];
        }
#pragma unroll
        for (int i = 0; i < 4; ++i)
#pragma unroll
            for (int j = 0; j < 4; ++j){
                acc[i][j] = __builtin_amdgcn_mfma_f32_16x16x32_bf16(ah[i], bh[j], acc[i][j], 0, 0, 0);
                acc[i][j] = __builtin_amdgcn_mfma_f32_16x16x32_bf16(ah[i], bl[j], acc[i][j], 0, 0, 0);
                acc[i][j] = __builtin_amdgcn_mfma_f32_16x16x32_bf16(al[i], bh[j], acc[i][j], 0, 0, 0);
            }
        __syncthreads();
    }

#pragma unroll
    for (int i = 0; i < 4; ++i){
#pragma unroll
        for (int j = 0; j < 4; ++j){
            int colc = col0 + wn + j * 16 + fr;
#pragma unroll
            for (int r = 0; r < 4; ++r){
                int row = row0 + wm + i * 16 + fq * 4 + r;
                if (row < M) Cbf[(size_t)row * Nn + colc] = f2bf(acc[i][j][r]);
            }
        }
    }
}

// ---------------- per-node attention score dots (bf16 h) ----------------
__global__ __launch_bounds__(256) void k_esd(const u16* __restrict__ h, const float* __restrict__ asrc,
                                             const float* __restrict__ adst,
                                             float* __restrict__ es, float* __restrict__ ed){
    int n = blockIdx.x;
    int tid = threadIdx.x;
    int w = tid >> 6, lane = tid & 63;
    float4 hv = bf4_to_f4(*(const ushort4*)(h + (size_t)n * DHID + w * CPH + lane * 4));
    float4 av = *(const float4*)(asrc + w * CPH + lane * 4);
    float4 dv = *(const float4*)(adst + w * CPH + lane * 4);
    float s = hv.x * av.x + hv.y * av.y + hv.z * av.z + hv.w * av.w;
    float d = hv.x * dv.x + hv.y * dv.y + hv.z * dv.z + hv.w * dv.w;
    for (int off = 32; off > 0; off >>= 1){
        s += __shfl_down(s, off);
        d += __shfl_down(d, off);
    }
    if (lane == 0){ es[n * HEADS + w] = s; ed[n * HEADS + w] = d; }
}

// ---------------- wave-per-node segment softmax + aggregation + bias + elu + split write ----------------
__global__ __launch_bounds__(256) void k_agg(const u16* __restrict__ hsrc, const float* __restrict__ es,
                                             const float* __restrict__ ed, const int* __restrict__ rowptr,
                                             const int* __restrict__ col, const float* __restrict__ bias,
                                             u16* __restrict__ outhi, u16* __restrict__ outlo,
                                             int writeLo, int N){
    int n = blockIdx.x * 4 + (threadIdx.x >> 6);
    if (n >= N) return;
    int lane = threadIdx.x & 63;
    int rp0 = rowptr[n];
    int deg = rowptr[n + 1] - rp0;
    int total = deg + 1;                         // + implicit self-loop
    float4 edv = *(const float4*)(ed + (size_t)n * HEADS);

    float4 a0 = make_float4(0.f,0.f,0.f,0.f), a1 = a0, a2 = a0, a3 = a0;
    int c4 = lane * 4;

    if (total <= 64){
        // per-lane edge score (lane i owns edge i)
        int sl = (lane < deg) ? col[rp0 + lane] : n;
        float4 ev = *(const float4*)(es + (size_t)sl * HEADS);
        bool valid = (lane < total);
        float ex = valid ? lrelu(ev.x + edv.x) : -FLT_BIG;
        float ey = valid ? lrelu(ev.y + edv.y) : -FLT_BIG;
        float ez = valid ? lrelu(ev.z + edv.z) : -FLT_BIG;
        float ew = valid ? lrelu(ev.w + edv.w) : -FLT_BIG;
        float mxx = ex, mxy = ey, mxz = ez, mxw = ew;
#pragma unroll
        for (int off = 1; off < 64; off <<= 1){
            mxx = fmaxf(mxx, __shfl_xor(mxx, off));
            mxy = fmaxf(mxy, __shfl_xor(mxy, off));
            mxz = fmaxf(mxz, __shfl_xor(mxz, off));
            mxw = fmaxf(mxw, __shfl_xor(mxw, off));
        }
        float px = valid ? expf(ex - mxx) : 0.f;
        float py = valid ? expf(ey - mxy) : 0.f;
        float pz = valid ? expf(ez - mxz) : 0.f;
        float pw = valid ? expf(ew - mxw) : 0.f;
        float sx = px, sy = py, sz = pz, sw = pw;
#pragma unroll
        for (int off = 1; off < 64; off <<= 1){
            sx += __shfl_xor(sx, off);
            sy += __shfl_xor(sy, off);
            sz += __shfl_xor(sz, off);
            sw += __shfl_xor(sw, off);
        }
        float alx_l = px / (sx + 1e-16f);
        float aly_l = py / (sy + 1e-16f);
        float alz_l = pz / (sz + 1e-16f);
        float alw_l = pw / (sw + 1e-16f);

        for (int i = 0; i < total; ++i){
            int s = (i < deg) ? col[rp0 + i] : n;       // wave-uniform
            float alx = __shfl(alx_l, i);
            float aly = __shfl(aly_l, i);
            float alz = __shfl(alz_l, i);
            float alw = __shfl(alw_l, i);
            const u16* rowp = hsrc + (size_t)s * DHID;
            ushort4 r0 = *(const ushort4*)(rowp + 0 * CPH + c4);
            ushort4 r1 = *(const ushort4*)(rowp + 1 * CPH + c4);
            ushort4 r2 = *(const ushort4*)(rowp + 2 * CPH + c4);
            ushort4 r3 = *(const ushort4*)(rowp + 3 * CPH + c4);
            float4 f0 = bf4_to_f4(r0), f1 = bf4_to_f4(r1), f2 = bf4_to_f4(r2), f3 = bf4_to_f4(r3);
            a0.x = fmaf(alx, f0.x, a0.x); a0.y = fmaf(alx, f0.y, a0.y);
            a0.z = fmaf(alx, f0.z, a0.z); a0.w = fmaf(alx, f0.w, a0.w);
            a1.x = fmaf(aly, f1.x, a1.x); a1.y = fmaf(aly, f1.y, a1.y);
            a1.z = fmaf(aly, f1.z, a1.z); a1.w = fmaf(aly, f1.w, a1.w);
            a2.x = fmaf(alz, f2.x, a2.x); a2.y = fmaf(alz, f2.y, a2.y);
            a2.z = fmaf(alz, f2.z, a2.z); a2.w = fmaf(alz, f2.w, a2.w);
            a3.x = fmaf(alw, f3.x, a3.x); a3.y = fmaf(alw, f3.y, a3.y);
            a3.z = fmaf(alw, f3.z, a3.z); a3.w = fmaf(alw, f3.w, a3.w);
        }
    } else {
        // fallback: original 3-pass
        float4 mx = make_float4(-FLT_BIG, -FLT_BIG, -FLT_BIG, -FLT_BIG);
        for (int i = lane; i < total; i += 64){
            int s = (i < deg) ? col[rp0 + i] : n;
            float4 ev = *(const float4*)(es + (size_t)s * HEADS);
            mx.x = fmaxf(mx.x, lrelu(ev.x + edv.x));
            mx.y = fmaxf(mx.y, lrelu(ev.y + edv.y));
            mx.z = fmaxf(mx.z, lrelu(ev.z + edv.z));
            mx.w = fmaxf(mx.w, lrelu(ev.w + edv.w));
        }
#pragma unroll
        for (int off = 1; off < 64; off <<= 1){
            mx.x = fmaxf(mx.x, __shfl_xor(mx.x, off));
            mx.y = fmaxf(mx.y, __shfl_xor(mx.y, off));
            mx.z = fmaxf(mx.z, __shfl_xor(mx.z, off));
            mx.w = fmaxf(mx.w, __shfl_xor(mx.w, off));
        }
        float4 sm = make_float4(0.f, 0.f, 0.f, 0.f);
        for (int i = lane; i < total; i += 64){
            int s = (i < deg) ? col[rp0 + i] : n;
            float4 ev = *(const float4*)(es + (size_t)s * HEADS);
            sm.x += expf(lrelu(ev.x + edv.x) - mx.x);
            sm.y += expf(lrelu(ev.y + edv.y) - mx.y);
            sm.z += expf(lrelu(ev.z + edv.z) - mx.z);
            sm.w += expf(lrelu(ev.w + edv.w) - mx.w);
        }
#pragma unroll
        for (int off = 1; off < 64; off <<= 1){
            sm.x += __shfl_xor(sm.x, off);
            sm.y += __shfl_xor(sm.y, off);
            sm.z += __shfl_xor(sm.z, off);
            sm.w += __shfl_xor(sm.w, off);
        }
        float4 inv = make_float4(1.f / (sm.x + 1e-16f), 1.f / (sm.y + 1e-16f),
                                 1.f / (sm.z + 1e-16f), 1.f / (sm.w + 1e-16f));
        for (int i = 0; i < total; ++i){
            int s = (i < deg) ? col[rp0 + i] : n;
            float4 ev = *(const float4*)(es + (size_t)s * HEADS);
            const u16* rowp = hsrc + (size_t)s * DHID;
            ushort4 r0 = *(const ushort4*)(rowp + 0 * CPH + c4);
            ushort4 r1 = *(const ushort4*)(rowp + 1 * CPH + c4);
            ushort4 r2 = *(const ushort4*)(rowp + 2 * CPH + c4);
            ushort4 r3 = *(const ushort4*)(rowp + 3 * CPH + c4);
            float alx = expf(lrelu(ev.x + edv.x) - mx.x) * inv.x;
            float aly = expf(lrelu(ev.y + edv.y) - mx.y) * inv.y;
            float alz = expf(lrelu(ev.z + edv.z) - mx.z) * inv.z;
            float alw = expf(lrelu(ev.w + edv.w) - mx.w) * inv.w;
            float4 f0 = bf4_to_f4(r0), f1 = bf4_to_f4(r1), f2 = bf4_to_f4(r2), f3 = bf4_to_f4(r3);
            a0.x = fmaf(alx, f0.x, a0.x); a0.y = fmaf(alx, f0.y, a0.y);
            a0.z = fmaf(alx, f0.z, a0.z); a0.w = fmaf(alx, f0.w, a0.w);
            a1.x = fmaf(aly, f1.x, a1.x); a1.y = fmaf(aly, f1.y, a1.y);
            a1.z = fmaf(aly, f1.z, a1.z); a1.w = fmaf(aly, f1.w, a1.w);
            a2.x = fmaf(alz, f2.x, a2.x); a2.y = fmaf(alz, f2.y, a2.y);
            a2.z = fmaf(alz, f2.z, a2.z); a2.w = fmaf(alz, f2.w, a2.w);
            a3.x = fmaf(alw, f3.x, a3.x); a3.y = fmaf(alw, f3.y, a3.y);
            a3.z = fmaf(alw, f3.z, a3.z); a3.w = fmaf(alw, f3.w, a3.w);
        }
    }

    // epilogue: +bias, elu, bf16 hi(/lo) store per head
#pragma unroll
    for (int h = 0; h < 4; ++h){
        float4 a = (h == 0) ? a0 : (h == 1) ? a1 : (h == 2) ? a2 : a3;
        int cidx = h * CPH + c4;
        float4 bv = *(const float4*)(bias + cidx);
        float ox = eluf(a.x + bv.x);
        float oy = eluf(a.y + bv.y);
        float oz = eluf(a.z + bv.z);
        float ow = eluf(a.w + bv.w);
        ushort4 h4;
        h4.x = f2bf(ox); h4.y = f2bf(oy); h4.z = f2bf(oz); h4.w = f2bf(ow);
        *(ushort4*)(outhi + (size_t)n * DHID + cidx) = h4;
        if (writeLo){
            ushort4 l4;
            l4.x = f2bf(ox - bf2f(h4.x));
            l4.y = f2bf(oy - bf2f(h4.y));
            l4.z = f2bf(oz - bf2f(h4.z));
            l4.w = f2bf(ow - bf2f(h4.w));
            *(ushort4*)(outlo + (size_t)n * DHID + cidx) = l4;
        }
    }
}

// ---------------- two-stage per-graph mean/max pooling (bf16 input) ----------------
__global__ __launch_bounds__(256) void k_pool_init(float* __restrict__ gsum, float* __restrict__ gmax, int L){
    int i = blockIdx.x * blockDim.x + threadIdx.x;
    if (i < L){ gsum[i] = 0.f; gmax[i] = -FLT_BIG; }
}

__global__ __launch_bounds__(256) void k_pool_partial(const u16* __restrict__ hf,
                                                      const int* __restrict__ batch,
                                                      float* __restrict__ gsum, float* __restrict__ gmax,
                                                      int N){
    int c = blockIdx.y * 256 + threadIdx.x;
    int i0 = blockIdx.x * PCHUNK;
    int i1 = i0 + PCHUNK; if (i1 > N) i1 = N;
    int curg = batch[i0];
    float s = 0.f, m = -FLT_BIG;
    for (int i = i0; i < i1; ++i){
        int g = batch[i];
        if (g != curg){
            atomicAdd(&gsum[(size_t)curg * DHID + c], s);
            atomicMaxF(&gmax[(size_t)curg * DHID + c], m);
            s = 0.f; m = -FLT_BIG; curg = g;
        }
        float v = bf2f(hf[(size_t)i * DHID + c]);
        s += v;
        m = fmaxf(m, v);
    }
    atomicAdd(&gsum[(size_t)curg * DHID + c], s);
    atomicMaxF(&gmax[(size_t)curg * DHID + c], m);
}

__global__ __launch_bounds__(256) void k_pool_final(const float* __restrict__ gsum,
                                                    const float* __restrict__ gmax,
                                                    const int* __restrict__ lo, const int* __restrict__ hi,
                                                    float* __restrict__ gfeat){
    int g = blockIdx.x;
    int c = threadIdx.x * 4;
    int l = lo[g], h2 = hi[g];
    int cnt = (h2 > l) ? (h2 - l) : 0;
    float invc = 1.f / (float)((cnt > 1) ? cnt : 1);
    float4 s = *(const float4*)(gsum + (size_t)g * DHID + c);
    float4 m = *(const float4*)(gmax + (size_t)g * DHID + c);
    float4 mean = make_float4(s.x * invc, s.y * invc, s.z * invc, s.w * invc);
    if (cnt == 0) m = make_float4(0.f, 0.f, 0.f, 0.f);
    *(float4*)(gfeat + (size_t)g * 2048 + c)        = mean;
    *(float4*)(gfeat + (size_t)g * 2048 + 1024 + c) = m;
}

// ---------------- small FC — latency-optimized ----------------
// Old version: grid (Nc/256, G) with one serial K-loop per thread = 254 cyc/iter pure
// L2 latency (217 us for Wc1, VALUBusy 1.7%, 20 VGPR). New: grid (Nc/64, G); 4 waves
// split K into quarters; 8 accumulators/thread keep 8 coalesced loads in flight; tiny
// LDS cross-wave reduce. fp32 sum-order change only (~1e-6 rel, tolerance 7.8e-3).
__global__ __launch_bounds__(256) void k_fc(const float* __restrict__ X, const float* __restrict__ W,
                                            const float* __restrict__ b, float* __restrict__ Y,
                                            int K, int Nc, int relu){
    __shared__ float xs[2048];
    __shared__ float part[4][64];
    int r = blockIdx.y;
    int c0 = blockIdx.x * 64;
    int tid = threadIdx.x;
    int w = tid >> 6, lane = tid & 63;

    for (int i = tid; i < K; i += 256) xs[i] = X[(size_t)r * K + i];
    __syncthreads();

    int c = c0 + lane;
    int kq = K >> 2;                 // K in {2048,512,256} — divisible by 4
    int kbeg = w * kq;
    float acc = 0.f;
    if (c < Nc){
        float a0=0.f,a1=0.f,a2=0.f,a3=0.f,a4=0.f,a5=0.f,a6=0.f,a7=0.f;
        int k = kbeg;
        int kend8 = kbeg + (kq & ~7);
        for (; k < kend8; k += 8){
            a0 = fmaf(xs[k  ], W[(size_t)(k  ) * Nc + c], a0);
            a1 = fmaf(xs[k+1], W[(size_t)(k+1) * Nc + c], a1);
            a2 = fmaf(xs[k+2], W[(size_t)(k+2) * Nc + c], a2);
            a3 = fmaf(xs[k+3], W[(size_t)(k+3) * Nc + c], a3);
            a4 = fmaf(xs[k+4], W[(size_t)(k+4) * Nc + c], a4);
            a5 = fmaf(xs[k+5], W[(size_t)(k+5) * Nc + c], a5);
            a6 = fmaf(xs[k+6], W[(size_t)(k+6) * Nc + c], a6);
            a7 = fmaf(xs[k+7], W[(size_t)(k+7) * Nc + c], a7);
        }
        for (; k < kbeg + kq; ++k) a0 = fmaf(xs[k], W[(size_t)k * Nc + c], a0);
        acc = ((a0 + a1) + (a2 + a3)) + ((a4 + a5) + (a6 + a7));
    }
    if (w) part[w][lane] = acc;
    __syncthreads();
    if (w == 0 && c < Nc){
        acc += part[1][lane] + part[2][lane] + part[3][lane];
        acc += b[c];
        if (relu) acc = fmaxf(acc, 0.f);
        Y[(size_t)r * Nc + c] = acc;
    }
}

// ---------------- launch ----------------
extern "C" void kernel_launch(void* const* d_in, const int* in_sizes, int n_in,
                              void* d_out, int out_size, void* d_ws, size_t ws_size,
                              hipStream_t stream) {
    const float* x      = (const float*)d_in[0];
    const int*   ei     = (const int*)  d_in[1];
    const int*   batch  = (const int*)  d_in[2];
    const float* W1     = (const float*)d_in[3];
    const float* asrc1  = (const float*)d_in[4];
    const float* adst1  = (const float*)d_in[5];
    const float* b1     = (const float*)d_in[6];
    const float* W2     = (const float*)d_in[7];
    const float* asrc2  = (const float*)d_in[8];
    const float* adst2  = (const float*)d_in[9];
    const float* b2     = (const float*)d_in[10];
    const float* Wc1    = (const float*)d_in[11];
    const float* bc1    = (const float*)d_in[12];
    const float* Wc2    = (const float*)d_in[13];
    const float* bc2    = (const float*)d_in[14];
    const float* Wc3    = (const float*)d_in[15];
    const float* bc3    = (const float*)d_in[16];

    const int N = in_sizes[2];
    const int E = in_sizes[1] / 2;
    const int G = out_size / 5;
    const int DIN = in_sizes[0] / N;

    const int* srcI = ei;
    const int* dstI = ei + E;

    char* p = (char*)d_ws;
    auto alloc = [&](size_t bytes) -> void* {
        void* q = (void*)p;
        p += (bytes + 255) & ~(size_t)255;
        return q;
    };
    u16*   R1     = (u16*)alloc((size_t)N * DHID * 2 * 2);   // activations hi+lo
    u16*   R2     = (u16*)alloc((size_t)N * DHID * 2);       // bf16 h plane
    float* es     = (float*)alloc((size_t)N * HEADS * 4);
    float* ed     = (float*)alloc((size_t)N * HEADS * 4);
    float* gfeat  = (float*)alloc((size_t)G * 2048 * 4);
    float* gsum   = (float*)alloc((size_t)G * DHID * 4);
    float* gmax   = (float*)alloc((size_t)G * DHID * 4);
    float* z1     = (float*)alloc((size_t)G * 512 * 4);
    float* z2     = (float*)alloc((size_t)G * 256 * 4);
    int*   cnt    = (int*)  alloc((size_t)N * 4);
    int*   fill   = (int*)  alloc((size_t)N * 4);
    int*   rowptr = (int*)  alloc((size_t)(N + 1) * 4);
    int*   col    = (int*)  alloc((size_t)E * 4);
    int*   lo     = (int*)  alloc((size_t)G * 4);
    int*   hi     = (int*)  alloc((size_t)G * 4);
    u16*   w1th   = (u16*)  alloc((size_t)DIN * DHID * 2);
    u16*   w1tl   = (u16*)  alloc((size_t)DIN * DHID * 2);
    u16*   w2th   = (u16*)  alloc((size_t)DHID * DHID * 2);
    u16*   w2tl   = (u16*)  alloc((size_t)DHID * DHID * 2);
    float* logits = (float*)d_out;

    int nb = (N + 255) / 256;
    int ebp = (E + 255) / 256;
    int aggb = (N + 3) / 4;

    // CSR + pooling bounds
    k_init   <<<nb,  256, 0, stream>>>(cnt, fill, lo, hi, N, G);
    k_count  <<<ebp, 256, 0, stream>>>(dstI, cnt, E);
    k_scan   <<<1,  1024, 0, stream>>>(cnt, rowptr, N, E);
    k_scatter<<<ebp, 256, 0, stream>>>(srcI, dstI, rowptr, fill, col, E);
    k_bounds <<<nb,  256, 0, stream>>>(batch, lo, hi, N);

    // weight splits (with LDS-tiled transpose)
    k_splitT<<<dim3((DHID + 31) / 32, (DIN + 31) / 32),  256, 0, stream>>>(W1, w1th, w1tl, DIN, DHID);
    k_splitT<<<dim3((DHID + 31) / 32, (DHID + 31) / 32), 256, 0, stream>>>(W2, w2th, w2tl, DHID, DHID);

    // GEMM launched as two half-M dispatches (instrumentation + identical total work)
    int R = (N + 127) / 128;
    int Rh = (R + 1) / 2;         // first-half row-tiles
    int Rl = R - Rh;              // second-half row-tiles
    int Rchunk_h = (Rh + 7) / 8;
    int Rchunk_l = (Rl + 7) / 8;
    dim3 grdH(8, 8 * Rchunk_h);
    dim3 grdL(8, 8 * Rchunk_l);

    // ---- GAT layer 1 ----
    u16* a1h = R1;
    u16* a1l = R1 + (size_t)N * DIN;
    long L41 = (long)N * DIN / 4;
    k_split<<<(unsigned)((L41 + 255) / 256), 256, 0, stream>>>(x, a1h, a1l, L41);
    u16* h1 = R2;
    k_gemm_mfma<<<grdH, 256, 0, stream>>>(a1h, a1l, w1th, w1tl, h1, N, DIN, DHID, Rchunk_h, 0,  Rh);
    k_gemm_mfma<<<grdL, 256, 0, stream>>>(a1h, a1l, w1th, w1tl, h1, N, DIN, DHID, Rchunk_l, Rh, Rl);
    k_esd<<<N, 256, 0, stream>>>(h1, asrc1, adst1, es, ed);
    u16* o1h = R1;
    u16* o1l = R1 + (size_t)N * DHID;
    k_agg<<<aggb, 256, 0, stream>>>(h1, es, ed, rowptr, col, b1, o1h, o1l, 1, N);

    // ---- GAT layer 2 ----
    u16* h2 = R2;
    k_gemm_mfma<<<grdH, 256, 0, stream>>>(o1h, o1l, w2th, w2tl, h2, N, DHID, DHID, Rchunk_h, 0,  Rh);
    k_gemm_mfma<<<grdL, 256, 0, stream>>>(o1h, o1l, w2th, w2tl, h2, N, DHID, DHID, Rchunk_l, Rh, Rl);
    k_esd<<<N, 256, 0, stream>>>(h2, asrc2, adst2, es, ed);
    u16* o2h = R1;
    k_agg<<<aggb, 256, 0, stream>>>(h2, es, ed, rowptr, col, b2, o2h, (u16*)0, 0, N);

    // ---- pooling + classifier ----
    k_pool_init<<<(G * DHID + 255) / 256, 256, 0, stream>>>(gsum, gmax, G * DHID);
    dim3 poolGrd((N + PCHUNK - 1) / PCHUNK, DHID / 256);
    k_pool_partial<<<poolGrd, 256, 0, stream>>>(o2h, batch, gsum, gmax, N);
    k_pool_final<<<G, 256, 0, stream>>>(gsum, gmax, lo, hi, gfeat);

    k_fc<<<dim3((512 + 63) / 64, G), 256, 0, stream>>>(gfeat, Wc1, bc1, z1, 2048, 512, 1);
    k_fc<<<dim3((256 + 63) / 64, G), 256, 0, stream>>>(z1,    Wc2, bc2, z2, 512,  256, 1);
    k_fc<<<dim3(1, G),                256, 0, stream>>>(z2,    Wc3, bc3, logits, 256, 5, 0);
}

// Round 11
// 1303.412 us; speedup vs baseline: 1.4869x; 1.0645x over previous
//
#include <hip/hip_runtime.h>
#include <math.h>

#define HEADS 4
#define CPH 256
#define DHID 1024
#define NEG_SLOPE 0.2f
#define FLT_BIG 3.402823466e38f
#define PCHUNK 128

typedef unsigned short u16;
typedef __bf16 bf16x8 __attribute__((ext_vector_type(8)));
typedef float f32x4 __attribute__((ext_vector_type(4)));

__device__ __forceinline__ float lrelu(float x){ return x > 0.f ? x : NEG_SLOPE * x; }
__device__ __forceinline__ float eluf(float x){ return x > 0.f ? x : expf(x) - 1.f; }

__device__ __forceinline__ u16 f2bf(float f){
    unsigned u = __float_as_uint(f);
    u += 0x7fffu + ((u >> 16) & 1u);
    return (u16)(u >> 16);
}
__device__ __forceinline__ float bf2f(u16 h){ return __uint_as_float(((unsigned)h) << 16); }
__device__ __forceinline__ float4 bf4_to_f4(ushort4 u){
    return make_float4(bf2f(u.x), bf2f(u.y), bf2f(u.z), bf2f(u.w));
}

__device__ __forceinline__ void gload_lds16(const void* g, void* l){
    __builtin_amdgcn_global_load_lds((const __attribute__((address_space(1))) unsigned int*)g,
                                     (__attribute__((address_space(3))) unsigned int*)l, 16, 0, 0);
}

__device__ __forceinline__ void atomicMaxF(float* addr, float v){
    if (v >= 0.f) atomicMax((int*)addr, __float_as_int(v));
    else          atomicMin((unsigned int*)addr, __float_as_uint(v));
}

// ---------------- CSR build + pooling bounds ----------------
__global__ void k_init(int* cnt, int* fill, int* lo, int* hi, int N, int G){
    int i = blockIdx.x * blockDim.x + threadIdx.x;
    if (i < N){ cnt[i] = 0; fill[i] = 0; }
    if (i < G){ lo[i] = 0x7fffffff; hi[i] = 0; }
}

__global__ void k_count(const int* __restrict__ dst, int* __restrict__ cnt, int E){
    int e = blockIdx.x * blockDim.x + threadIdx.x;
    if (e < E) atomicAdd(&cnt[dst[e]], 1);
}

__global__ __launch_bounds__(1024) void k_scan(const int* __restrict__ cnt, int* __restrict__ rowptr,
                                               int N, int E){
    __shared__ int tot[1024];
    int tid = threadIdx.x;
    int items = (N + 1023) >> 10;
    int base = tid * items;
    int sum = 0;
    for (int i = 0; i < items; ++i){ int idx = base + i; if (idx < N) sum += cnt[idx]; }
    tot[tid] = sum;
    __syncthreads();
    for (int off = 1; off < 1024; off <<= 1){
        int t = (tid >= off) ? tot[tid - off] : 0;
        __syncthreads();
        tot[tid] += t;
        __syncthreads();
    }
    int run = tot[tid] - sum;
    for (int i = 0; i < items; ++i){
        int idx = base + i;
        if (idx < N){ rowptr[idx] = run; run += cnt[idx]; }
    }
    if (tid == 0) rowptr[N] = E;
}

__global__ void k_scatter(const int* __restrict__ src, const int* __restrict__ dst,
                          const int* __restrict__ rowptr, int* __restrict__ fill,
                          int* __restrict__ col, int E){
    int e = blockIdx.x * blockDim.x + threadIdx.x;
    if (e < E){
        int d = dst[e];
        int pos = rowptr[d] + atomicAdd(&fill[d], 1);
        col[pos] = src[e];
    }
}

// batch is SORTED — per-graph [lo,hi) = run boundaries, zero atomics (was 288 us of
// 64-way same-address atomic serialization; now ~5 us).
__global__ void k_bounds(const int* __restrict__ batch, int* lo, int* hi, int N){
    int i = blockIdx.x * blockDim.x + threadIdx.x;
    if (i < N){
        int b = batch[i];
        if (i == 0     || batch[i - 1] != b) lo[b] = i;
        if (i == N - 1 || batch[i + 1] != b) hi[b] = i + 1;
    }
}

// ---------------- split kernels ----------------
__global__ void k_split(const float* __restrict__ X, u16* __restrict__ hi, u16* __restrict__ lo, long L4){
    long i = (long)blockIdx.x * blockDim.x + threadIdx.x;
    if (i < L4){
        float4 v = ((const float4*)X)[i];
        ushort4 h, l;
        h.x = f2bf(v.x); l.x = f2bf(v.x - bf2f(h.x));
        h.y = f2bf(v.y); l.y = f2bf(v.y - bf2f(h.y));
        h.z = f2bf(v.z); l.z = f2bf(v.z - bf2f(h.z));
        h.w = f2bf(v.w); l.w = f2bf(v.w - bf2f(h.w));
        ((ushort4*)hi)[i] = h;
        ((ushort4*)lo)[i] = l;
    }
}

// LDS-tiled transpose split: W (K x Nn, row-major) -> hiT/loT (Nn x K, row-major).
__global__ __launch_bounds__(256) void k_splitT(const float* __restrict__ W, u16* __restrict__ hiT,
                                                u16* __restrict__ loT, int K, int Nn){
    __shared__ float t[32][33];
    int n0 = blockIdx.x * 32;
    int k0 = blockIdx.y * 32;
    int tx = threadIdx.x & 31, ty = threadIdx.x >> 5;   // 8 rows per pass
    for (int r = ty; r < 32; r += 8){
        int k = k0 + r, n = n0 + tx;
        t[r][tx] = (k < K && n < Nn) ? W[(size_t)k * Nn + n] : 0.f;
    }
    __syncthreads();
    for (int r = ty; r < 32; r += 8){
        int n = n0 + r, k = k0 + tx;
        if (n < Nn && k < K){
            float v = t[tx][r];
            u16 h = f2bf(v);
            hiT[(size_t)n * K + k] = h;
            loT[(size_t)n * K + k] = f2bf(v - bf2f(h));
        }
    }
}

// ---------------- split-bf16 MFMA GEMM (16x16x32), 128x128 tile — round-0 verified best ----------------
// Recombined into ONE dispatch per layer (round-10 half-M split cost ~90 us/iter in tails
// + lost overlap; its instrumentation job is done). Structure is at the m97-type ceiling
// (~1000 TF effective on the 3-pass stream); scheduled 256^2 variants all measured slower.
__global__ __launch_bounds__(256) void k_gemm_mfma(
    const u16* __restrict__ Ahi, const u16* __restrict__ Alo,
    const u16* __restrict__ BThi, const u16* __restrict__ BTlo,
    u16* __restrict__ Cbf, int M, int K, int Nn, int Rchunk)
{
    __shared__ __align__(16) u16 As[2][128][32];
    __shared__ __align__(16) u16 Bs[2][128][32];
    int tid = threadIdx.x;
    int w = tid >> 6, lane = tid & 63;

    int R = (M + 127) >> 7;
    int by = blockIdx.x * Rchunk + (blockIdx.y >> 3);   // gridDim.x==8 (XCD swizzle)
    int bx = blockIdx.y & 7;
    if (by >= R) return;
    int row0 = by * 128, col0 = bx * 128;

    int srow = tid >> 2;
    int skoff = (tid & 3) * 8;

    int wm = (w >> 1) * 64, wn = (w & 1) * 64;
    int fr = lane & 15;
    int fq = lane >> 4;

    f32x4 acc[4][4];
#pragma unroll
    for (int i = 0; i < 4; ++i)
#pragma unroll
        for (int j = 0; j < 4; ++j){ acc[i][j].x = 0.f; acc[i][j].y = 0.f; acc[i][j].z = 0.f; acc[i][j].w = 0.f; }

    int ra0 = row0 + srow;      if (ra0 >= M) ra0 = M - 1;
    int ra1 = row0 + srow + 64; if (ra1 >= M) ra1 = M - 1;
    int rb0 = col0 + srow;
    int rb1 = col0 + srow + 64;

    for (int k0 = 0; k0 < K; k0 += 32){
        size_t ga0 = (size_t)ra0 * K + k0 + skoff;
        size_t ga1 = (size_t)ra1 * K + k0 + skoff;
        size_t gb0 = (size_t)rb0 * K + k0 + skoff;
        size_t gb1 = (size_t)rb1 * K + k0 + skoff;
        gload_lds16(Ahi  + ga0, &As[0][srow     ][skoff]);
        gload_lds16(Ahi  + ga1, &As[0][srow + 64][skoff]);
        gload_lds16(Alo  + ga0, &As[1][srow     ][skoff]);
        gload_lds16(Alo  + ga1, &As[1][srow + 64][skoff]);
        gload_lds16(BThi + gb0, &Bs[0][srow     ][skoff]);
        gload_lds16(BThi + gb1, &Bs[0][srow + 64][skoff]);
        gload_lds16(BTlo + gb0, &Bs[1][srow     ][skoff]);
        gload_lds16(BTlo + gb1, &Bs[1][srow + 64][skoff]);
        __syncthreads();

        bf16x8 ah[4], al[4], bh[4], bl[4];
#pragma unroll
        for (int i = 0; i < 4; ++i){
            ah[i] = *(const bf16x8*)&As[0][wm + i * 16 + fr][fq * 8];
            al[i] = *(const bf16x8*)&As[1][wm + i * 16 + fr][fq * 8];
            bh[i] = *(const bf16x8*)&Bs[0][wn + i * 16 + fr][fq * 8];
            bl[i] = *(const bf16x8*)&Bs[1][wn + i * 16 + fr][fq * 8];
        }
#pragma unroll
        for (int i = 0; i < 4; ++i)
#pragma unroll
            for (int j = 0; j < 4; ++j){
                acc[i][j] = __builtin_amdgcn_mfma_f32_16x16x32_bf16(ah[i], bh[j], acc[i][j], 0, 0, 0);
                acc[i][j] = __builtin_amdgcn_mfma_f32_16x16x32_bf16(ah[i], bl[j], acc[i][j], 0, 0, 0);
                acc[i][j] = __builtin_amdgcn_mfma_f32_16x16x32_bf16(al[i], bh[j], acc[i][j], 0, 0, 0);
            }
        __syncthreads();
    }

#pragma unroll
    for (int i = 0; i < 4; ++i){
#pragma unroll
        for (int j = 0; j < 4; ++j){
            int colc = col0 + wn + j * 16 + fr;
#pragma unroll
            for (int r = 0; r < 4; ++r){
                int row = row0 + wm + i * 16 + fq * 4 + r;
                if (row < M) Cbf[(size_t)row * Nn + colc] = f2bf(acc[i][j][r]);
            }
        }
    }
}

// ---------------- per-node attention score dots (bf16 h) ----------------
__global__ __launch_bounds__(256) void k_esd(const u16* __restrict__ h, const float* __restrict__ asrc,
                                             const float* __restrict__ adst,
                                             float* __restrict__ es, float* __restrict__ ed){
    int n = blockIdx.x;
    int tid = threadIdx.x;
    int w = tid >> 6, lane = tid & 63;
    float4 hv = bf4_to_f4(*(const ushort4*)(h + (size_t)n * DHID + w * CPH + lane * 4));
    float4 av = *(const float4*)(asrc + w * CPH + lane * 4);
    float4 dv = *(const float4*)(adst + w * CPH + lane * 4);
    float s = hv.x * av.x + hv.y * av.y + hv.z * av.z + hv.w * av.w;
    float d = hv.x * dv.x + hv.y * dv.y + hv.z * dv.z + hv.w * dv.w;
    for (int off = 32; off > 0; off >>= 1){
        s += __shfl_down(s, off);
        d += __shfl_down(d, off);
    }
    if (lane == 0){ es[n * HEADS + w] = s; ed[n * HEADS + w] = d; }
}

// ---------------- wave-per-node segment softmax + aggregation + bias + elu + split write ----------------
__global__ __launch_bounds__(256) void k_agg(const u16* __restrict__ hsrc, const float* __restrict__ es,
                                             const float* __restrict__ ed, const int* __restrict__ rowptr,
                                             const int* __restrict__ col, const float* __restrict__ bias,
                                             u16* __restrict__ outhi, u16* __restrict__ outlo,
                                             int writeLo, int N){
    int n = blockIdx.x * 4 + (threadIdx.x >> 6);
    if (n >= N) return;
    int lane = threadIdx.x & 63;
    int rp0 = rowptr[n];
    int deg = rowptr[n + 1] - rp0;
    int total = deg + 1;                         // + implicit self-loop
    float4 edv = *(const float4*)(ed + (size_t)n * HEADS);

    float4 a0 = make_float4(0.f,0.f,0.f,0.f), a1 = a0, a2 = a0, a3 = a0;
    int c4 = lane * 4;

    if (total <= 64){
        // per-lane edge score (lane i owns edge i)
        int sl = (lane < deg) ? col[rp0 + lane] : n;
        float4 ev = *(const float4*)(es + (size_t)sl * HEADS);
        bool valid = (lane < total);
        float ex = valid ? lrelu(ev.x + edv.x) : -FLT_BIG;
        float ey = valid ? lrelu(ev.y + edv.y) : -FLT_BIG;
        float ez = valid ? lrelu(ev.z + edv.z) : -FLT_BIG;
        float ew = valid ? lrelu(ev.w + edv.w) : -FLT_BIG;
        float mxx = ex, mxy = ey, mxz = ez, mxw = ew;
#pragma unroll
        for (int off = 1; off < 64; off <<= 1){
            mxx = fmaxf(mxx, __shfl_xor(mxx, off));
            mxy = fmaxf(mxy, __shfl_xor(mxy, off));
            mxz = fmaxf(mxz, __shfl_xor(mxz, off));
            mxw = fmaxf(mxw, __shfl_xor(mxw, off));
        }
        float px = valid ? expf(ex - mxx) : 0.f;
        float py = valid ? expf(ey - mxy) : 0.f;
        float pz = valid ? expf(ez - mxz) : 0.f;
        float pw = valid ? expf(ew - mxw) : 0.f;
        float sx = px, sy = py, sz = pz, sw = pw;
#pragma unroll
        for (int off = 1; off < 64; off <<= 1){
            sx += __shfl_xor(sx, off);
            sy += __shfl_xor(sy, off);
            sz += __shfl_xor(sz, off);
            sw += __shfl_xor(sw, off);
        }
        float alx_l = px / (sx + 1e-16f);
        float aly_l = py / (sy + 1e-16f);
        float alz_l = pz / (sz + 1e-16f);
        float alw_l = pw / (sw + 1e-16f);

        for (int i = 0; i < total; ++i){
            int s = __shfl(sl, i);                      // lane i holds col[rp0+i] (or n)
            float alx = __shfl(alx_l, i);
            float aly = __shfl(aly_l, i);
            float alz = __shfl(alz_l, i);
            float alw = __shfl(alw_l, i);
            const u16* rowp = hsrc + (size_t)s * DHID;
            ushort4 r0 = *(const ushort4*)(rowp + 0 * CPH + c4);
            ushort4 r1 = *(const ushort4*)(rowp + 1 * CPH + c4);
            ushort4 r2 = *(const ushort4*)(rowp + 2 * CPH + c4);
            ushort4 r3 = *(const ushort4*)(rowp + 3 * CPH + c4);
            float4 f0 = bf4_to_f4(r0), f1 = bf4_to_f4(r1), f2 = bf4_to_f4(r2), f3 = bf4_to_f4(r3);
            a0.x = fmaf(alx, f0.x, a0.x); a0.y = fmaf(alx, f0.y, a0.y);
            a0.z = fmaf(alx, f0.z, a0.z); a0.w = fmaf(alx, f0.w, a0.w);
            a1.x = fmaf(aly, f1.x, a1.x); a1.y = fmaf(aly, f1.y, a1.y);
            a1.z = fmaf(aly, f1.z, a1.z); a1.w = fmaf(aly, f1.w, a1.w);
            a2.x = fmaf(alz, f2.x, a2.x); a2.y = fmaf(alz, f2.y, a2.y);
            a2.z = fmaf(alz, f2.z, a2.z); a2.w = fmaf(alz, f2.w, a2.w);
            a3.x = fmaf(alw, f3.x, a3.x); a3.y = fmaf(alw, f3.y, a3.y);
            a3.z = fmaf(alw, f3.z, a3.z); a3.w = fmaf(alw, f3.w, a3.w);
        }
    } else {
        // fallback: original 3-pass
        float4 mx = make_float4(-FLT_BIG, -FLT_BIG, -FLT_BIG, -FLT_BIG);
        for (int i = lane; i < total; i += 64){
            int s = (i < deg) ? col[rp0 + i] : n;
            float4 ev = *(const float4*)(es + (size_t)s * HEADS);
            mx.x = fmaxf(mx.x, lrelu(ev.x + edv.x));
            mx.y = fmaxf(mx.y, lrelu(ev.y + edv.y));
            mx.z = fmaxf(mx.z, lrelu(ev.z + edv.z));
            mx.w = fmaxf(mx.w, lrelu(ev.w + edv.w));
        }
#pragma unroll
        for (int off = 1; off < 64; off <<= 1){
            mx.x = fmaxf(mx.x, __shfl_xor(mx.x, off));
            mx.y = fmaxf(mx.y, __shfl_xor(mx.y, off));
            mx.z = fmaxf(mx.z, __shfl_xor(mx.z, off));
            mx.w = fmaxf(mx.w, __shfl_xor(mx.w, off));
        }
        float4 sm = make_float4(0.f, 0.f, 0.f, 0.f);
        for (int i = lane; i < total; i += 64){
            int s = (i < deg) ? col[rp0 + i] : n;
            float4 ev = *(const float4*)(es + (size_t)s * HEADS);
            sm.x += expf(lrelu(ev.x + edv.x) - mx.x);
            sm.y += expf(lrelu(ev.y + edv.y) - mx.y);
            sm.z += expf(lrelu(ev.z + edv.z) - mx.z);
            sm.w += expf(lrelu(ev.w + edv.w) - mx.w);
        }
#pragma unroll
        for (int off = 1; off < 64; off <<= 1){
            sm.x += __shfl_xor(sm.x, off);
            sm.y += __shfl_xor(sm.y, off);
            sm.z += __shfl_xor(sm.z, off);
            sm.w += __shfl_xor(sm.w, off);
        }
        float4 inv = make_float4(1.f / (sm.x + 1e-16f), 1.f / (sm.y + 1e-16f),
                                 1.f / (sm.z + 1e-16f), 1.f / (sm.w + 1e-16f));
        for (int i = 0; i < total; ++i){
            int s = (i < deg) ? col[rp0 + i] : n;
            float4 ev = *(const float4*)(es + (size_t)s * HEADS);
            const u16* rowp = hsrc + (size_t)s * DHID;
            ushort4 r0 = *(const ushort4*)(rowp + 0 * CPH + c4);
            ushort4 r1 = *(const ushort4*)(rowp + 1 * CPH + c4);
            ushort4 r2 = *(const ushort4*)(rowp + 2 * CPH + c4);
            ushort4 r3 = *(const ushort4*)(rowp + 3 * CPH + c4);
            float alx = expf(lrelu(ev.x + edv.x) - mx.x) * inv.x;
            float aly = expf(lrelu(ev.y + edv.y) - mx.y) * inv.y;
            float alz = expf(lrelu(ev.z + edv.z) - mx.z) * inv.z;
            float alw = expf(lrelu(ev.w + edv.w) - mx.w) * inv.w;
            float4 f0 = bf4_to_f4(r0), f1 = bf4_to_f4(r1), f2 = bf4_to_f4(r2), f3 = bf4_to_f4(r3);
            a0.x = fmaf(alx, f0.x, a0.x); a0.y = fmaf(alx, f0.y, a0.y);
            a0.z = fmaf(alx, f0.z, a0.z); a0.w = fmaf(alx, f0.w, a0.w);
            a1.x = fmaf(aly, f1.x, a1.x); a1.y = fmaf(aly, f1.y, a1.y);
            a1.z = fmaf(aly, f1.z, a1.z); a1.w = fmaf(aly, f1.w, a1.w);
            a2.x = fmaf(alz, f2.x, a2.x); a2.y = fmaf(alz, f2.y, a2.y);
            a2.z = fmaf(alz, f2.z, a2.z); a2.w = fmaf(alz, f2.w, a2.w);
            a3.x = fmaf(alw, f3.x, a3.x); a3.y = fmaf(alw, f3.y, a3.y);
            a3.z = fmaf(alw, f3.z, a3.z); a3.w = fmaf(alw, f3.w, a3.w);
        }
    }

    // epilogue: +bias, elu, bf16 hi(/lo) store per head
#pragma unroll
    for (int h = 0; h < 4; ++h){
        float4 a = (h == 0) ? a0 : (h == 1) ? a1 : (h == 2) ? a2 : a3;
        int cidx = h * CPH + c4;
        float4 bv = *(const float4*)(bias + cidx);
        float ox = eluf(a.x + bv.x);
        float oy = eluf(a.y + bv.y);
        float oz = eluf(a.z + bv.z);
        float ow = eluf(a.w + bv.w);
        ushort4 h4;
        h4.x = f2bf(ox); h4.y = f2bf(oy); h4.z = f2bf(oz); h4.w = f2bf(ow);
        *(ushort4*)(outhi + (size_t)n * DHID + cidx) = h4;
        if (writeLo){
            ushort4 l4;
            l4.x = f2bf(ox - bf2f(h4.x));
            l4.y = f2bf(oy - bf2f(h4.y));
            l4.z = f2bf(oz - bf2f(h4.z));
            l4.w = f2bf(ow - bf2f(h4.w));
            *(ushort4*)(outlo + (size_t)n * DHID + cidx) = l4;
        }
    }
}

// ---------------- two-stage per-graph mean/max pooling (bf16 input) ----------------
__global__ __launch_bounds__(256) void k_pool_init(float* __restrict__ gsum, float* __restrict__ gmax, int L){
    int i = blockIdx.x * blockDim.x + threadIdx.x;
    if (i < L){ gsum[i] = 0.f; gmax[i] = -FLT_BIG; }
}

__global__ __launch_bounds__(256) void k_pool_partial(const u16* __restrict__ hf,
                                                      const int* __restrict__ batch,
                                                      float* __restrict__ gsum, float* __restrict__ gmax,
                                                      int N){
    int c = blockIdx.y * 256 + threadIdx.x;
    int i0 = blockIdx.x * PCHUNK;
    int i1 = i0 + PCHUNK; if (i1 > N) i1 = N;
    int curg = batch[i0];
    float s = 0.f, m = -FLT_BIG;
    for (int i = i0; i < i1; ++i){
        int g = batch[i];
        if (g != curg){
            atomicAdd(&gsum[(size_t)curg * DHID + c], s);
            atomicMaxF(&gmax[(size_t)curg * DHID + c], m);
            s = 0.f; m = -FLT_BIG; curg = g;
        }
        float v = bf2f(hf[(size_t)i * DHID + c]);
        s += v;
        m = fmaxf(m, v);
    }
    atomicAdd(&gsum[(size_t)curg * DHID + c], s);
    atomicMaxF(&gmax[(size_t)curg * DHID + c], m);
}

__global__ __launch_bounds__(256) void k_pool_final(const float* __restrict__ gsum,
                                                    const float* __restrict__ gmax,
                                                    const int* __restrict__ lo, const int* __restrict__ hi,
                                                    float* __restrict__ gfeat){
    int g = blockIdx.x;
    int c = threadIdx.x * 4;
    int l = lo[g], h2 = hi[g];
    int cnt = (h2 > l) ? (h2 - l) : 0;
    float invc = 1.f / (float)((cnt > 1) ? cnt : 1);
    float4 s = *(const float4*)(gsum + (size_t)g * DHID + c);
    float4 m = *(const float4*)(gmax + (size_t)g * DHID + c);
    float4 mean = make_float4(s.x * invc, s.y * invc, s.z * invc, s.w * invc);
    if (cnt == 0) m = make_float4(0.f, 0.f, 0.f, 0.f);
    *(float4*)(gfeat + (size_t)g * 2048 + c)        = mean;
    *(float4*)(gfeat + (size_t)g * 2048 + 1024 + c) = m;
}

// ---------------- small FC — latency-optimized ----------------
__global__ __launch_bounds__(256) void k_fc(const float* __restrict__ X, const float* __restrict__ W,
                                            const float* __restrict__ b, float* __restrict__ Y,
                                            int K, int Nc, int relu){
    __shared__ float xs[2048];
    __shared__ float part[4][64];
    int r = blockIdx.y;
    int c0 = blockIdx.x * 64;
    int tid = threadIdx.x;
    int w = tid >> 6, lane = tid & 63;

    for (int i = tid; i < K; i += 256) xs[i] = X[(size_t)r * K + i];
    __syncthreads();

    int c = c0 + lane;
    int kq = K >> 2;                 // K in {2048,512,256} — divisible by 4
    int kbeg = w * kq;
    float acc = 0.f;
    if (c < Nc){
        float a0=0.f,a1=0.f,a2=0.f,a3=0.f,a4=0.f,a5=0.f,a6=0.f,a7=0.f;
        int k = kbeg;
        int kend8 = kbeg + (kq & ~7);
        for (; k < kend8; k += 8){
            a0 = fmaf(xs[k  ], W[(size_t)(k  ) * Nc + c], a0);
            a1 = fmaf(xs[k+1], W[(size_t)(k+1) * Nc + c], a1);
            a2 = fmaf(xs[k+2], W[(size_t)(k+2) * Nc + c], a2);
            a3 = fmaf(xs[k+3], W[(size_t)(k+3) * Nc + c], a3);
            a4 = fmaf(xs[k+4], W[(size_t)(k+4) * Nc + c], a4);
            a5 = fmaf(xs[k+5], W[(size_t)(k+5) * Nc + c], a5);
            a6 = fmaf(xs[k+6], W[(size_t)(k+6) * Nc + c], a6);
            a7 = fmaf(xs[k+7], W[(size_t)(k+7) * Nc + c], a7);
        }
        for (; k < kbeg + kq; ++k) a0 = fmaf(xs[k], W[(size_t)k * Nc + c], a0);
        acc = ((a0 + a1) + (a2 + a3)) + ((a4 + a5) + (a6 + a7));
    }
    if (w) part[w][lane] = acc;
    __syncthreads();
    if (w == 0 && c < Nc){
        acc += part[1][lane] + part[2][lane] + part[3][lane];
        acc += b[c];
        if (relu) acc = fmaxf(acc, 0.f);
        Y[(size_t)r * Nc + c] = acc;
    }
}

// ---------------- launch ----------------
extern "C" void kernel_launch(void* const* d_in, const int* in_sizes, int n_in,
                              void* d_out, int out_size, void* d_ws, size_t ws_size,
                              hipStream_t stream) {
    const float* x      = (const float*)d_in[0];
    const int*   ei     = (const int*)  d_in[1];
    const int*   batch  = (const int*)  d_in[2];
    const float* W1     = (const float*)d_in[3];
    const float* asrc1  = (const float*)d_in[4];
    const float* adst1  = (const float*)d_in[5];
    const float* b1     = (const float*)d_in[6];
    const float* W2     = (const float*)d_in[7];
    const float* asrc2  = (const float*)d_in[8];
    const float* adst2  = (const float*)d_in[9];
    const float* b2     = (const float*)d_in[10];
    const float* Wc1    = (const float*)d_in[11];
    const float* bc1    = (const float*)d_in[12];
    const float* Wc2    = (const float*)d_in[13];
    const float* bc2    = (const float*)d_in[14];
    const float* Wc3    = (const float*)d_in[15];
    const float* bc3    = (const float*)d_in[16];

    const int N = in_sizes[2];
    const int E = in_sizes[1] / 2;
    const int G = out_size / 5;
    const int DIN = in_sizes[0] / N;

    const int* srcI = ei;
    const int* dstI = ei + E;

    char* p = (char*)d_ws;
    auto alloc = [&](size_t bytes) -> void* {
        void* q = (void*)p;
        p += (bytes + 255) & ~(size_t)255;
        return q;
    };
    u16*   R1     = (u16*)alloc((size_t)N * DHID * 2 * 2);   // activations hi+lo
    u16*   R2     = (u16*)alloc((size_t)N * DHID * 2);       // bf16 h plane
    float* es     = (float*)alloc((size_t)N * HEADS * 4);
    float* ed     = (float*)alloc((size_t)N * HEADS * 4);
    float* gfeat  = (float*)alloc((size_t)G * 2048 * 4);
    float* gsum   = (float*)alloc((size_t)G * DHID * 4);
    float* gmax   = (float*)alloc((size_t)G * DHID * 4);
    float* z1     = (float*)alloc((size_t)G * 512 * 4);
    float* z2     = (float*)alloc((size_t)G * 256 * 4);
    int*   cnt    = (int*)  alloc((size_t)N * 4);
    int*   fill   = (int*)  alloc((size_t)N * 4);
    int*   rowptr = (int*)  alloc((size_t)(N + 1) * 4);
    int*   col    = (int*)  alloc((size_t)E * 4);
    int*   lo     = (int*)  alloc((size_t)G * 4);
    int*   hi     = (int*)  alloc((size_t)G * 4);
    u16*   w1th   = (u16*)  alloc((size_t)DIN * DHID * 2);
    u16*   w1tl   = (u16*)  alloc((size_t)DIN * DHID * 2);
    u16*   w2th   = (u16*)  alloc((size_t)DHID * DHID * 2);
    u16*   w2tl   = (u16*)  alloc((size_t)DHID * DHID * 2);
    float* logits = (float*)d_out;

    int nb = (N + 255) / 256;
    int ebp = (E + 255) / 256;
    int aggb = (N + 3) / 4;

    // CSR + pooling bounds
    k_init   <<<nb,  256, 0, stream>>>(cnt, fill, lo, hi, N, G);
    k_count  <<<ebp, 256, 0, stream>>>(dstI, cnt, E);
    k_scan   <<<1,  1024, 0, stream>>>(cnt, rowptr, N, E);
    k_scatter<<<ebp, 256, 0, stream>>>(srcI, dstI, rowptr, fill, col, E);
    k_bounds <<<nb,  256, 0, stream>>>(batch, lo, hi, N);

    // weight splits (with LDS-tiled transpose)
    k_splitT<<<dim3((DHID + 31) / 32, (DIN + 31) / 32),  256, 0, stream>>>(W1, w1th, w1tl, DIN, DHID);
    k_splitT<<<dim3((DHID + 31) / 32, (DHID + 31) / 32), 256, 0, stream>>>(W2, w2th, w2tl, DHID, DHID);

    int R = (N + 127) / 128;
    int Rchunk = (R + 7) / 8;
    dim3 gemmGrd(8, 8 * Rchunk);   // XCD swizzle: x = row-chunk, y = (local row, col-block)

    // ---- GAT layer 1 ----
    u16* a1h = R1;
    u16* a1l = R1 + (size_t)N * DIN;
    long L41 = (long)N * DIN / 4;
    k_split<<<(unsigned)((L41 + 255) / 256), 256, 0, stream>>>(x, a1h, a1l, L41);
    u16* h1 = R2;
    k_gemm_mfma<<<gemmGrd, 256, 0, stream>>>(a1h, a1l, w1th, w1tl, h1, N, DIN, DHID, Rchunk);
    k_esd<<<N, 256, 0, stream>>>(h1, asrc1, adst1, es, ed);
    u16* o1h = R1;
    u16* o1l = R1 + (size_t)N * DHID;
    k_agg<<<aggb, 256, 0, stream>>>(h1, es, ed, rowptr, col, b1, o1h, o1l, 1, N);

    // ---- GAT layer 2 ----
    u16* h2 = R2;
    k_gemm_mfma<<<gemmGrd, 256, 0, stream>>>(o1h, o1l, w2th, w2tl, h2, N, DHID, DHID, Rchunk);
    k_esd<<<N, 256, 0, stream>>>(h2, asrc2, adst2, es, ed);
    u16* o2h = R1;
    k_agg<<<aggb, 256, 0, stream>>>(h2, es, ed, rowptr, col, b2, o2h, (u16*)0, 0, N);

    // ---- pooling + classifier ----
    k_pool_init<<<(G * DHID + 255) / 256, 256, 0, stream>>>(gsum, gmax, G * DHID);
    dim3 poolGrd((N + PCHUNK - 1) / PCHUNK, DHID / 256);
    k_pool_partial<<<poolGrd, 256, 0, stream>>>(o2h, batch, gsum, gmax, N);
    k_pool_final<<<G, 256, 0, stream>>>(gsum, gmax, lo, hi, gfeat);

    k_fc<<<dim3((512 + 63) / 64, G), 256, 0, stream>>>(gfeat, Wc1, bc1, z1, 2048, 512, 1);
    k_fc<<<dim3((256 + 63) / 64, G), 256, 0, stream>>>(z1,    Wc2, bc2, z2, 512,  256, 1);
    k_fc<<<dim3(1, G),                256, 0, stream>>>(z2,    Wc3, bc3, logits, 256, 5, 0);
}

// Round 12
// 1211.896 us; speedup vs baseline: 1.5992x; 1.0755x over previous
//
#include <hip/hip_runtime.h>
#include <math.h>

#define HEADS 4
#define CPH 256
#define DHID 1024
#define NEG_SLOPE 0.2f
#define FLT_BIG 3.402823466e38f
#define PCHUNK 128

typedef unsigned short u16;
typedef _Float16 f16x8 __attribute__((ext_vector_type(8)));
typedef float f32x4 __attribute__((ext_vector_type(4)));

__device__ __forceinline__ float lrelu(float x){ return x > 0.f ? x : NEG_SLOPE * x; }
__device__ __forceinline__ float eluf(float x){ return x > 0.f ? x : expf(x) - 1.f; }

__device__ __forceinline__ u16 f2bf(float f){
    unsigned u = __float_as_uint(f);
    u += 0x7fffu + ((u >> 16) & 1u);
    return (u16)(u >> 16);
}
__device__ __forceinline__ float bf2f(u16 h){ return __uint_as_float(((unsigned)h) << 16); }
__device__ __forceinline__ float4 bf4_to_f4(ushort4 u){
    return make_float4(bf2f(u.x), bf2f(u.y), bf2f(u.z), bf2f(u.w));
}
__device__ __forceinline__ u16 f2h_bits(float f){
    _Float16 h = (_Float16)f;
    return *(u16*)&h;
}
__device__ __forceinline__ float h2f_bits(u16 b){
    _Float16 h = *(_Float16*)&b;
    return (float)h;
}

__device__ __forceinline__ void gload_lds16(const void* g, void* l){
    __builtin_amdgcn_global_load_lds((const __attribute__((address_space(1))) unsigned int*)g,
                                     (__attribute__((address_space(3))) unsigned int*)l, 16, 0, 0);
}

__device__ __forceinline__ void atomicMaxF(float* addr, float v){
    if (v >= 0.f) atomicMax((int*)addr, __float_as_int(v));
    else          atomicMin((unsigned int*)addr, __float_as_uint(v));
}

// ---------------- CSR build + pooling bounds ----------------
__global__ void k_init(int* cnt, int* fill, int* lo, int* hi, int N, int G){
    int i = blockIdx.x * blockDim.x + threadIdx.x;
    if (i < N){ cnt[i] = 0; fill[i] = 0; }
    if (i < G){ lo[i] = 0x7fffffff; hi[i] = 0; }
}

__global__ void k_count(const int* __restrict__ dst, int* __restrict__ cnt, int E){
    int e = blockIdx.x * blockDim.x + threadIdx.x;
    if (e < E) atomicAdd(&cnt[dst[e]], 1);
}

__global__ __launch_bounds__(1024) void k_scan(const int* __restrict__ cnt, int* __restrict__ rowptr,
                                               int N, int E){
    __shared__ int tot[1024];
    int tid = threadIdx.x;
    int items = (N + 1023) >> 10;
    int base = tid * items;
    int sum = 0;
    for (int i = 0; i < items; ++i){ int idx = base + i; if (idx < N) sum += cnt[idx]; }
    tot[tid] = sum;
    __syncthreads();
    for (int off = 1; off < 1024; off <<= 1){
        int t = (tid >= off) ? tot[tid - off] : 0;
        __syncthreads();
        tot[tid] += t;
        __syncthreads();
    }
    int run = tot[tid] - sum;
    for (int i = 0; i < items; ++i){
        int idx = base + i;
        if (idx < N){ rowptr[idx] = run; run += cnt[idx]; }
    }
    if (tid == 0) rowptr[N] = E;
}

__global__ void k_scatter(const int* __restrict__ src, const int* __restrict__ dst,
                          const int* __restrict__ rowptr, int* __restrict__ fill,
                          int* __restrict__ col, int E){
    int e = blockIdx.x * blockDim.x + threadIdx.x;
    if (e < E){
        int d = dst[e];
        int pos = rowptr[d] + atomicAdd(&fill[d], 1);
        col[pos] = src[e];
    }
}

// batch is SORTED — per-graph [lo,hi) = run boundaries, zero atomics.
__global__ void k_bounds(const int* __restrict__ batch, int* lo, int* hi, int N){
    int i = blockIdx.x * blockDim.x + threadIdx.x;
    if (i < N){
        int b = batch[i];
        if (i == 0     || batch[i - 1] != b) lo[b] = i;
        if (i == N - 1 || batch[i + 1] != b) hi[b] = i + 1;
    }
}

// ---------------- split kernels (f16 hi/lo) ----------------
__global__ void k_split(const float* __restrict__ X, u16* __restrict__ hi, u16* __restrict__ lo, long L4){
    long i = (long)blockIdx.x * blockDim.x + threadIdx.x;
    if (i < L4){
        float4 v = ((const float4*)X)[i];
        ushort4 h, l;
        h.x = f2h_bits(v.x); l.x = f2h_bits(v.x - h2f_bits(h.x));
        h.y = f2h_bits(v.y); l.y = f2h_bits(v.y - h2f_bits(h.y));
        h.z = f2h_bits(v.z); l.z = f2h_bits(v.z - h2f_bits(h.z));
        h.w = f2h_bits(v.w); l.w = f2h_bits(v.w - h2f_bits(h.w));
        ((ushort4*)hi)[i] = h;
        ((ushort4*)lo)[i] = l;
    }
}

// LDS-tiled transpose: W (K x Nn, row-major) -> hiT (Nn x K, f16 only — 2-pass GEMM
// never consumes a weight-lo plane).
__global__ __launch_bounds__(256) void k_splitT(const float* __restrict__ W, u16* __restrict__ hiT,
                                                int K, int Nn){
    __shared__ float t[32][33];
    int n0 = blockIdx.x * 32;
    int k0 = blockIdx.y * 32;
    int tx = threadIdx.x & 31, ty = threadIdx.x >> 5;   // 8 rows per pass
    for (int r = ty; r < 32; r += 8){
        int k = k0 + r, n = n0 + tx;
        t[r][tx] = (k < K && n < Nn) ? W[(size_t)k * Nn + n] : 0.f;
    }
    __syncthreads();
    for (int r = ty; r < 32; r += 8){
        int n = n0 + r, k = k0 + tx;
        if (n < Nn && k < K) hiT[(size_t)n * K + k] = f2h_bits(t[tx][r]);
    }
}

// ---------------- split-f16 MFMA GEMM (16x16x32), 128x128 tile, 2-pass ----------------
// D = Ah*Bh + Al*Bh = (exact A) x (f16-quantized B); per-term error 2^-12*|b| -> dot error
// ~3e-4 over K=1024, an order below the bf16-storage error (2^-7) that sets absmax.
// vs bf16 3-pass: MFMA -33%, staging 8->6, LDS reads 16->12, LDS 32->24KB. Structure is the
// round-0 verified 128^2 2-barrier kernel (every scheduled 256^2 variant measured slower).
__global__ __launch_bounds__(256) void k_gemm_mfma(
    const u16* __restrict__ Ahi, const u16* __restrict__ Alo,
    const u16* __restrict__ BTh,
    u16* __restrict__ Cbf, int M, int K, int Nn, int Rchunk)
{
    __shared__ __align__(16) u16 As[2][128][32];
    __shared__ __align__(16) u16 Bs[128][32];
    int tid = threadIdx.x;
    int w = tid >> 6, lane = tid & 63;

    int R = (M + 127) >> 7;
    int by = blockIdx.x * Rchunk + (blockIdx.y >> 3);   // gridDim.x==8 (XCD swizzle)
    int bx = blockIdx.y & 7;
    if (by >= R) return;
    int row0 = by * 128, col0 = bx * 128;

    int srow = tid >> 2;
    int skoff = (tid & 3) * 8;

    int wm = (w >> 1) * 64, wn = (w & 1) * 64;
    int fr = lane & 15;
    int fq = lane >> 4;

    f32x4 acc[4][4];
#pragma unroll
    for (int i = 0; i < 4; ++i)
#pragma unroll
        for (int j = 0; j < 4; ++j){ acc[i][j].x = 0.f; acc[i][j].y = 0.f; acc[i][j].z = 0.f; acc[i][j].w = 0.f; }

    int ra0 = row0 + srow;      if (ra0 >= M) ra0 = M - 1;
    int ra1 = row0 + srow + 64; if (ra1 >= M) ra1 = M - 1;
    int rb0 = col0 + srow;
    int rb1 = col0 + srow + 64;

    for (int k0 = 0; k0 < K; k0 += 32){
        size_t ga0 = (size_t)ra0 * K + k0 + skoff;
        size_t ga1 = (size_t)ra1 * K + k0 + skoff;
        size_t gb0 = (size_t)rb0 * K + k0 + skoff;
        size_t gb1 = (size_t)rb1 * K + k0 + skoff;
        gload_lds16(Ahi + ga0, &As[0][srow     ][skoff]);
        gload_lds16(Ahi + ga1, &As[0][srow + 64][skoff]);
        gload_lds16(Alo + ga0, &As[1][srow     ][skoff]);
        gload_lds16(Alo + ga1, &As[1][srow + 64][skoff]);
        gload_lds16(BTh + gb0, &Bs[srow     ][skoff]);
        gload_lds16(BTh + gb1, &Bs[srow + 64][skoff]);
        __syncthreads();

        f16x8 ah[4], al[4], bh[4];
#pragma unroll
        for (int i = 0; i < 4; ++i){
            ah[i] = *(const f16x8*)&As[0][wm + i * 16 + fr][fq * 8];
            al[i] = *(const f16x8*)&As[1][wm + i * 16 + fr][fq * 8];
            bh[i] = *(const f16x8*)&Bs[wn + i * 16 + fr][fq * 8];
        }
#pragma unroll
        for (int i = 0; i < 4; ++i)
#pragma unroll
            for (int j = 0; j < 4; ++j){
                acc[i][j] = __builtin_amdgcn_mfma_f32_16x16x32_f16(ah[i], bh[j], acc[i][j], 0, 0, 0);
                acc[i][j] = __builtin_amdgcn_mfma_f32_16x16x32_f16(al[i], bh[j], acc[i][j], 0, 0, 0);
            }
        __syncthreads();
    }

#pragma unroll
    for (int i = 0; i < 4; ++i){
#pragma unroll
        for (int j = 0; j < 4; ++j){
            int colc = col0 + wn + j * 16 + fr;
#pragma unroll
            for (int r = 0; r < 4; ++r){
                int row = row0 + wm + i * 16 + fq * 4 + r;
                if (row < M) Cbf[(size_t)row * Nn + colc] = f2bf(acc[i][j][r]);
            }
        }
    }
}

// ---------------- per-node attention score dots (bf16 h) ----------------
__global__ __launch_bounds__(256) void k_esd(const u16* __restrict__ h, const float* __restrict__ asrc,
                                             const float* __restrict__ adst,
                                             float* __restrict__ es, float* __restrict__ ed){
    int n = blockIdx.x;
    int tid = threadIdx.x;
    int w = tid >> 6, lane = tid & 63;
    float4 hv = bf4_to_f4(*(const ushort4*)(h + (size_t)n * DHID + w * CPH + lane * 4));
    float4 av = *(const float4*)(asrc + w * CPH + lane * 4);
    float4 dv = *(const float4*)(adst + w * CPH + lane * 4);
    float s = hv.x * av.x + hv.y * av.y + hv.z * av.z + hv.w * av.w;
    float d = hv.x * dv.x + hv.y * dv.y + hv.z * dv.z + hv.w * dv.w;
    for (int off = 32; off > 0; off >>= 1){
        s += __shfl_down(s, off);
        d += __shfl_down(d, off);
    }
    if (lane == 0){ es[n * HEADS + w] = s; ed[n * HEADS + w] = d; }
}

// ---------------- wave-per-node segment softmax + aggregation + bias + elu ----------------
// writeLo=1: outputs f16 hi/lo (consumed only by the next split-f16 GEMM).
// writeLo=0: outputs bf16 hi only (consumed by pooling).
__global__ __launch_bounds__(256) void k_agg(const u16* __restrict__ hsrc, const float* __restrict__ es,
                                             const float* __restrict__ ed, const int* __restrict__ rowptr,
                                             const int* __restrict__ col, const float* __restrict__ bias,
                                             u16* __restrict__ outhi, u16* __restrict__ outlo,
                                             int writeLo, int N){
    int n = blockIdx.x * 4 + (threadIdx.x >> 6);
    if (n >= N) return;
    int lane = threadIdx.x & 63;
    int rp0 = rowptr[n];
    int deg = rowptr[n + 1] - rp0;
    int total = deg + 1;                         // + implicit self-loop
    float4 edv = *(const float4*)(ed + (size_t)n * HEADS);

    float4 a0 = make_float4(0.f,0.f,0.f,0.f), a1 = a0, a2 = a0, a3 = a0;
    int c4 = lane * 4;

    if (total <= 64){
        int sl = (lane < deg) ? col[rp0 + lane] : n;
        float4 ev = *(const float4*)(es + (size_t)sl * HEADS);
        bool valid = (lane < total);
        float ex = valid ? lrelu(ev.x + edv.x) : -FLT_BIG;
        float ey = valid ? lrelu(ev.y + edv.y) : -FLT_BIG;
        float ez = valid ? lrelu(ev.z + edv.z) : -FLT_BIG;
        float ew = valid ? lrelu(ev.w + edv.w) : -FLT_BIG;
        float mxx = ex, mxy = ey, mxz = ez, mxw = ew;
#pragma unroll
        for (int off = 1; off < 64; off <<= 1){
            mxx = fmaxf(mxx, __shfl_xor(mxx, off));
            mxy = fmaxf(mxy, __shfl_xor(mxy, off));
            mxz = fmaxf(mxz, __shfl_xor(mxz, off));
            mxw = fmaxf(mxw, __shfl_xor(mxw, off));
        }
        float px = valid ? expf(ex - mxx) : 0.f;
        float py = valid ? expf(ey - mxy) : 0.f;
        float pz = valid ? expf(ez - mxz) : 0.f;
        float pw = valid ? expf(ew - mxw) : 0.f;
        float sx = px, sy = py, sz = pz, sw = pw;
#pragma unroll
        for (int off = 1; off < 64; off <<= 1){
            sx += __shfl_xor(sx, off);
            sy += __shfl_xor(sy, off);
            sz += __shfl_xor(sz, off);
            sw += __shfl_xor(sw, off);
        }
        float alx_l = px / (sx + 1e-16f);
        float aly_l = py / (sy + 1e-16f);
        float alz_l = pz / (sz + 1e-16f);
        float alw_l = pw / (sw + 1e-16f);

        for (int i = 0; i < total; ++i){
            int s = __shfl(sl, i);                      // lane i holds col[rp0+i] (or n)
            float alx = __shfl(alx_l, i);
            float aly = __shfl(aly_l, i);
            float alz = __shfl(alz_l, i);
            float alw = __shfl(alw_l, i);
            const u16* rowp = hsrc + (size_t)s * DHID;
            ushort4 r0 = *(const ushort4*)(rowp + 0 * CPH + c4);
            ushort4 r1 = *(const ushort4*)(rowp + 1 * CPH + c4);
            ushort4 r2 = *(const ushort4*)(rowp + 2 * CPH + c4);
            ushort4 r3 = *(const ushort4*)(rowp + 3 * CPH + c4);
            float4 f0 = bf4_to_f4(r0), f1 = bf4_to_f4(r1), f2 = bf4_to_f4(r2), f3 = bf4_to_f4(r3);
            a0.x = fmaf(alx, f0.x, a0.x); a0.y = fmaf(alx, f0.y, a0.y);
            a0.z = fmaf(alx, f0.z, a0.z); a0.w = fmaf(alx, f0.w, a0.w);
            a1.x = fmaf(aly, f1.x, a1.x); a1.y = fmaf(aly, f1.y, a1.y);
            a1.z = fmaf(aly, f1.z, a1.z); a1.w = fmaf(aly, f1.w, a1.w);
            a2.x = fmaf(alz, f2.x, a2.x); a2.y = fmaf(alz, f2.y, a2.y);
            a2.z = fmaf(alz, f2.z, a2.z); a2.w = fmaf(alz, f2.w, a2.w);
            a3.x = fmaf(alw, f3.x, a3.x); a3.y = fmaf(alw, f3.y, a3.y);
            a3.z = fmaf(alw, f3.z, a3.z); a3.w = fmaf(alw, f3.w, a3.w);
        }
    } else {
        float4 mx = make_float4(-FLT_BIG, -FLT_BIG, -FLT_BIG, -FLT_BIG);
        for (int i = lane; i < total; i += 64){
            int s = (i < deg) ? col[rp0 + i] : n;
            float4 ev = *(const float4*)(es + (size_t)s * HEADS);
            mx.x = fmaxf(mx.x, lrelu(ev.x + edv.x));
            mx.y = fmaxf(mx.y, lrelu(ev.y + edv.y));
            mx.z = fmaxf(mx.z, lrelu(ev.z + edv.z));
            mx.w = fmaxf(mx.w, lrelu(ev.w + edv.w));
        }
#pragma unroll
        for (int off = 1; off < 64; off <<= 1){
            mx.x = fmaxf(mx.x, __shfl_xor(mx.x, off));
            mx.y = fmaxf(mx.y, __shfl_xor(mx.y, off));
            mx.z = fmaxf(mx.z, __shfl_xor(mx.z, off));
            mx.w = fmaxf(mx.w, __shfl_xor(mx.w, off));
        }
        float4 sm = make_float4(0.f, 0.f, 0.f, 0.f);
        for (int i = lane; i < total; i += 64){
            int s = (i < deg) ? col[rp0 + i] : n;
            float4 ev = *(const float4*)(es + (size_t)s * HEADS);
            sm.x += expf(lrelu(ev.x + edv.x) - mx.x);
            sm.y += expf(lrelu(ev.y + edv.y) - mx.y);
            sm.z += expf(lrelu(ev.z + edv.z) - mx.z);
            sm.w += expf(lrelu(ev.w + edv.w) - mx.w);
        }
#pragma unroll
        for (int off = 1; off < 64; off <<= 1){
            sm.x += __shfl_xor(sm.x, off);
            sm.y += __shfl_xor(sm.y, off);
            sm.z += __shfl_xor(sm.z, off);
            sm.w += __shfl_xor(sm.w, off);
        }
        float4 inv = make_float4(1.f / (sm.x + 1e-16f), 1.f / (sm.y + 1e-16f),
                                 1.f / (sm.z + 1e-16f), 1.f / (sm.w + 1e-16f));
        for (int i = 0; i < total; ++i){
            int s = (i < deg) ? col[rp0 + i] : n;
            float4 ev = *(const float4*)(es + (size_t)s * HEADS);
            const u16* rowp = hsrc + (size_t)s * DHID;
            ushort4 r0 = *(const ushort4*)(rowp + 0 * CPH + c4);
            ushort4 r1 = *(const ushort4*)(rowp + 1 * CPH + c4);
            ushort4 r2 = *(const ushort4*)(rowp + 2 * CPH + c4);
            ushort4 r3 = *(const ushort4*)(rowp + 3 * CPH + c4);
            float alx = expf(lrelu(ev.x + edv.x) - mx.x) * inv.x;
            float aly = expf(lrelu(ev.y + edv.y) - mx.y) * inv.y;
            float alz = expf(lrelu(ev.z + edv.z) - mx.z) * inv.z;
            float alw = expf(lrelu(ev.w + edv.w) - mx.w) * inv.w;
            float4 f0 = bf4_to_f4(r0), f1 = bf4_to_f4(r1), f2 = bf4_to_f4(r2), f3 = bf4_to_f4(r3);
            a0.x = fmaf(alx, f0.x, a0.x); a0.y = fmaf(alx, f0.y, a0.y);
            a0.z = fmaf(alx, f0.z, a0.z); a0.w = fmaf(alx, f0.w, a0.w);
            a1.x = fmaf(aly, f1.x, a1.x); a1.y = fmaf(aly, f1.y, a1.y);
            a1.z = fmaf(aly, f1.z, a1.z); a1.w = fmaf(aly, f1.w, a1.w);
            a2.x = fmaf(alz, f2.x, a2.x); a2.y = fmaf(alz, f2.y, a2.y);
            a2.z = fmaf(alz, f2.z, a2.z); a2.w = fmaf(alz, f2.w, a2.w);
            a3.x = fmaf(alw, f3.x, a3.x); a3.y = fmaf(alw, f3.y, a3.y);
            a3.z = fmaf(alw, f3.z, a3.z); a3.w = fmaf(alw, f3.w, a3.w);
        }
    }

    // epilogue: +bias, elu, store
#pragma unroll
    for (int h = 0; h < 4; ++h){
        float4 a = (h == 0) ? a0 : (h == 1) ? a1 : (h == 2) ? a2 : a3;
        int cidx = h * CPH + c4;
        float4 bv = *(const float4*)(bias + cidx);
        float ox = eluf(a.x + bv.x);
        float oy = eluf(a.y + bv.y);
        float oz = eluf(a.z + bv.z);
        float ow = eluf(a.w + bv.w);
        ushort4 h4, l4;
        if (writeLo){
            h4.x = f2h_bits(ox); l4.x = f2h_bits(ox - h2f_bits(h4.x));
            h4.y = f2h_bits(oy); l4.y = f2h_bits(oy - h2f_bits(h4.y));
            h4.z = f2h_bits(oz); l4.z = f2h_bits(oz - h2f_bits(h4.z));
            h4.w = f2h_bits(ow); l4.w = f2h_bits(ow - h2f_bits(h4.w));
            *(ushort4*)(outhi + (size_t)n * DHID + cidx) = h4;
            *(ushort4*)(outlo + (size_t)n * DHID + cidx) = l4;
        } else {
            h4.x = f2bf(ox); h4.y = f2bf(oy); h4.z = f2bf(oz); h4.w = f2bf(ow);
            *(ushort4*)(outhi + (size_t)n * DHID + cidx) = h4;
        }
    }
}

// ---------------- two-stage per-graph mean/max pooling (bf16 input) ----------------
__global__ __launch_bounds__(256) void k_pool_init(float* __restrict__ gsum, float* __restrict__ gmax, int L){
    int i = blockIdx.x * blockDim.x + threadIdx.x;
    if (i < L){ gsum[i] = 0.f; gmax[i] = -FLT_BIG; }
}

__global__ __launch_bounds__(256) void k_pool_partial(const u16* __restrict__ hf,
                                                      const int* __restrict__ batch,
                                                      float* __restrict__ gsum, float* __restrict__ gmax,
                                                      int N){
    int c = blockIdx.y * 256 + threadIdx.x;
    int i0 = blockIdx.x * PCHUNK;
    int i1 = i0 + PCHUNK; if (i1 > N) i1 = N;
    int curg = batch[i0];
    float s = 0.f, m = -FLT_BIG;
    for (int i = i0; i < i1; ++i){
        int g = batch[i];
        if (g != curg){
            atomicAdd(&gsum[(size_t)curg * DHID + c], s);
            atomicMaxF(&gmax[(size_t)curg * DHID + c], m);
            s = 0.f; m = -FLT_BIG; curg = g;
        }
        float v = bf2f(hf[(size_t)i * DHID + c]);
        s += v;
        m = fmaxf(m, v);
    }
    atomicAdd(&gsum[(size_t)curg * DHID + c], s);
    atomicMaxF(&gmax[(size_t)curg * DHID + c], m);
}

__global__ __launch_bounds__(256) void k_pool_final(const float* __restrict__ gsum,
                                                    const float* __restrict__ gmax,
                                                    const int* __restrict__ lo, const int* __restrict__ hi,
                                                    float* __restrict__ gfeat){
    int g = blockIdx.x;
    int c = threadIdx.x * 4;
    int l = lo[g], h2 = hi[g];
    int cnt = (h2 > l) ? (h2 - l) : 0;
    float invc = 1.f / (float)((cnt > 1) ? cnt : 1);
    float4 s = *(const float4*)(gsum + (size_t)g * DHID + c);
    float4 m = *(const float4*)(gmax + (size_t)g * DHID + c);
    float4 mean = make_float4(s.x * invc, s.y * invc, s.z * invc, s.w * invc);
    if (cnt == 0) m = make_float4(0.f, 0.f, 0.f, 0.f);
    *(float4*)(gfeat + (size_t)g * 2048 + c)        = mean;
    *(float4*)(gfeat + (size_t)g * 2048 + 1024 + c) = m;
}

// ---------------- small FC — latency-optimized ----------------
__global__ __launch_bounds__(256) void k_fc(const float* __restrict__ X, const float* __restrict__ W,
                                            const float* __restrict__ b, float* __restrict__ Y,
                                            int K, int Nc, int relu){
    __shared__ float xs[2048];
    __shared__ float part[4][64];
    int r = blockIdx.y;
    int c0 = blockIdx.x * 64;
    int tid = threadIdx.x;
    int w = tid >> 6, lane = tid & 63;

    for (int i = tid; i < K; i += 256) xs[i] = X[(size_t)r * K + i];
    __syncthreads();

    int c = c0 + lane;
    int kq = K >> 2;                 // K in {2048,512,256} — divisible by 4
    int kbeg = w * kq;
    float acc = 0.f;
    if (c < Nc){
        float a0=0.f,a1=0.f,a2=0.f,a3=0.f,a4=0.f,a5=0.f,a6=0.f,a7=0.f;
        int k = kbeg;
        int kend8 = kbeg + (kq & ~7);
        for (; k < kend8; k += 8){
            a0 = fmaf(xs[k  ], W[(size_t)(k  ) * Nc + c], a0);
            a1 = fmaf(xs[k+1], W[(size_t)(k+1) * Nc + c], a1);
            a2 = fmaf(xs[k+2], W[(size_t)(k+2) * Nc + c], a2);
            a3 = fmaf(xs[k+3], W[(size_t)(k+3) * Nc + c], a3);
            a4 = fmaf(xs[k+4], W[(size_t)(k+4) * Nc + c], a4);
            a5 = fmaf(xs[k+5], W[(size_t)(k+5) * Nc + c], a5);
            a6 = fmaf(xs[k+6], W[(size_t)(k+6) * Nc + c], a6);
            a7 = fmaf(xs[k+7], W[(size_t)(k+7) * Nc + c], a7);
        }
        for (; k < kbeg + kq; ++k) a0 = fmaf(xs[k], W[(size_t)k * Nc + c], a0);
        acc = ((a0 + a1) + (a2 + a3)) + ((a4 + a5) + (a6 + a7));
    }
    if (w) part[w][lane] = acc;
    __syncthreads();
    if (w == 0 && c < Nc){
        acc += part[1][lane] + part[2][lane] + part[3][lane];
        acc += b[c];
        if (relu) acc = fmaxf(acc, 0.f);
        Y[(size_t)r * Nc + c] = acc;
    }
}

// ---------------- launch ----------------
extern "C" void kernel_launch(void* const* d_in, const int* in_sizes, int n_in,
                              void* d_out, int out_size, void* d_ws, size_t ws_size,
                              hipStream_t stream) {
    const float* x      = (const float*)d_in[0];
    const int*   ei     = (const int*)  d_in[1];
    const int*   batch  = (const int*)  d_in[2];
    const float* W1     = (const float*)d_in[3];
    const float* asrc1  = (const float*)d_in[4];
    const float* adst1  = (const float*)d_in[5];
    const float* b1     = (const float*)d_in[6];
    const float* W2     = (const float*)d_in[7];
    const float* asrc2  = (const float*)d_in[8];
    const float* adst2  = (const float*)d_in[9];
    const float* b2     = (const float*)d_in[10];
    const float* Wc1    = (const float*)d_in[11];
    const float* bc1    = (const float*)d_in[12];
    const float* Wc2    = (const float*)d_in[13];
    const float* bc2    = (const float*)d_in[14];
    const float* Wc3    = (const float*)d_in[15];
    const float* bc3    = (const float*)d_in[16];

    const int N = in_sizes[2];
    const int E = in_sizes[1] / 2;
    const int G = out_size / 5;
    const int DIN = in_sizes[0] / N;

    const int* srcI = ei;
    const int* dstI = ei + E;

    char* p = (char*)d_ws;
    auto alloc = [&](size_t bytes) -> void* {
        void* q = (void*)p;
        p += (bytes + 255) & ~(size_t)255;
        return q;
    };
    u16*   R1     = (u16*)alloc((size_t)N * DHID * 2 * 2);   // activations hi+lo
    u16*   R2     = (u16*)alloc((size_t)N * DHID * 2);       // bf16 h plane
    float* es     = (float*)alloc((size_t)N * HEADS * 4);
    float* ed     = (float*)alloc((size_t)N * HEADS * 4);
    float* gfeat  = (float*)alloc((size_t)G * 2048 * 4);
    float* gsum   = (float*)alloc((size_t)G * DHID * 4);
    float* gmax   = (float*)alloc((size_t)G * DHID * 4);
    float* z1     = (float*)alloc((size_t)G * 512 * 4);
    float* z2     = (float*)alloc((size_t)G * 256 * 4);
    int*   cnt    = (int*)  alloc((size_t)N * 4);
    int*   fill   = (int*)  alloc((size_t)N * 4);
    int*   rowptr = (int*)  alloc((size_t)(N + 1) * 4);
    int*   col    = (int*)  alloc((size_t)E * 4);
    int*   lo     = (int*)  alloc((size_t)G * 4);
    int*   hi     = (int*)  alloc((size_t)G * 4);
    u16*   w1th   = (u16*)  alloc((size_t)DIN * DHID * 2);
    u16*   w2th   = (u16*)  alloc((size_t)DHID * DHID * 2);
    float* logits = (float*)d_out;

    int nb = (N + 255) / 256;
    int ebp = (E + 255) / 256;
    int aggb = (N + 3) / 4;

    // CSR + pooling bounds
    k_init   <<<nb,  256, 0, stream>>>(cnt, fill, lo, hi, N, G);
    k_count  <<<ebp, 256, 0, stream>>>(dstI, cnt, E);
    k_scan   <<<1,  1024, 0, stream>>>(cnt, rowptr, N, E);
    k_scatter<<<ebp, 256, 0, stream>>>(srcI, dstI, rowptr, fill, col, E);
    k_bounds <<<nb,  256, 0, stream>>>(batch, lo, hi, N);

    // weight transpose + f16 quantize (hi plane only — 2-pass GEMM)
    k_splitT<<<dim3((DHID + 31) / 32, (DIN + 31) / 32),  256, 0, stream>>>(W1, w1th, DIN, DHID);
    k_splitT<<<dim3((DHID + 31) / 32, (DHID + 31) / 32), 256, 0, stream>>>(W2, w2th, DHID, DHID);

    int R = (N + 127) / 128;
    int Rchunk = (R + 7) / 8;
    dim3 gemmGrd(8, 8 * Rchunk);   // XCD swizzle: x = row-chunk, y = (local row, col-block)

    // ---- GAT layer 1 ----
    u16* a1h = R1;
    u16* a1l = R1 + (size_t)N * DIN;
    long L41 = (long)N * DIN / 4;
    k_split<<<(unsigned)((L41 + 255) / 256), 256, 0, stream>>>(x, a1h, a1l, L41);
    u16* h1 = R2;
    k_gemm_mfma<<<gemmGrd, 256, 0, stream>>>(a1h, a1l, w1th, h1, N, DIN, DHID, Rchunk);
    k_esd<<<N, 256, 0, stream>>>(h1, asrc1, adst1, es, ed);
    u16* o1h = R1;
    u16* o1l = R1 + (size_t)N * DHID;
    k_agg<<<aggb, 256, 0, stream>>>(h1, es, ed, rowptr, col, b1, o1h, o1l, 1, N);

    // ---- GAT layer 2 ----
    u16* h2 = R2;
    k_gemm_mfma<<<gemmGrd, 256, 0, stream>>>(o1h, o1l, w2th, h2, N, DHID, DHID, Rchunk);
    k_esd<<<N, 256, 0, stream>>>(h2, asrc2, adst2, es, ed);
    u16* o2h = R1;
    k_agg<<<aggb, 256, 0, stream>>>(h2, es, ed, rowptr, col, b2, o2h, (u16*)0, 0, N);

    // ---- pooling + classifier ----
    k_pool_init<<<(G * DHID + 255) / 256, 256, 0, stream>>>(gsum, gmax, G * DHID);
    dim3 poolGrd((N + PCHUNK - 1) / PCHUNK, DHID / 256);
    k_pool_partial<<<poolGrd, 256, 0, stream>>>(o2h, batch, gsum, gmax, N);
    k_pool_final<<<G, 256, 0, stream>>>(gsum, gmax, lo, hi, gfeat);

    k_fc<<<dim3((512 + 63) / 64, G), 256, 0, stream>>>(gfeat, Wc1, bc1, z1, 2048, 512, 1);
    k_fc<<<dim3((256 + 63) / 64, G), 256, 0, stream>>>(z1,    Wc2, bc2, z2, 512,  256, 1);
    k_fc<<<dim3(1, G),                256, 0, stream>>>(z2,    Wc3, bc3, logits, 256, 5, 0);
}

// Round 13
// 1016.505 us; speedup vs baseline: 1.9066x; 1.1922x over previous
//
#include <hip/hip_runtime.h>
#include <math.h>

#define HEADS 4
#define CPH 256
#define DHID 1024
#define NEG_SLOPE 0.2f
#define FLT_BIG 3.402823466e38f
#define PCHUNK 128

typedef unsigned short u16;
typedef _Float16 f16x8 __attribute__((ext_vector_type(8)));
typedef float f32x4 __attribute__((ext_vector_type(4)));

__device__ __forceinline__ float lrelu(float x){ return x > 0.f ? x : NEG_SLOPE * x; }
__device__ __forceinline__ float eluf(float x){ return x > 0.f ? x : expf(x) - 1.f; }

__device__ __forceinline__ u16 f2bf(float f){
    unsigned u = __float_as_uint(f);
    u += 0x7fffu + ((u >> 16) & 1u);
    return (u16)(u >> 16);
}
__device__ __forceinline__ float bf2f(u16 h){ return __uint_as_float(((unsigned)h) << 16); }
__device__ __forceinline__ float4 bf4_to_f4(ushort4 u){
    return make_float4(bf2f(u.x), bf2f(u.y), bf2f(u.z), bf2f(u.w));
}
__device__ __forceinline__ u16 f2h_bits(float f){
    _Float16 h = (_Float16)f;
    return *(u16*)&h;
}

__device__ __forceinline__ void gload_lds16(const void* g, void* l){
    __builtin_amdgcn_global_load_lds((const __attribute__((address_space(1))) unsigned int*)g,
                                     (__attribute__((address_space(3))) unsigned int*)l, 16, 0, 0);
}

__device__ __forceinline__ void atomicMaxF(float* addr, float v){
    if (v >= 0.f) atomicMax((int*)addr, __float_as_int(v));
    else          atomicMin((unsigned int*)addr, __float_as_uint(v));
}

// ---------------- CSR build + pooling bounds ----------------
__global__ void k_init(int* cnt, int* fill, int* lo, int* hi, int N, int G){
    int i = blockIdx.x * blockDim.x + threadIdx.x;
    if (i < N){ cnt[i] = 0; fill[i] = 0; }
    if (i < G){ lo[i] = 0x7fffffff; hi[i] = 0; }
}

__global__ void k_count(const int* __restrict__ dst, int* __restrict__ cnt, int E){
    int e = blockIdx.x * blockDim.x + threadIdx.x;
    if (e < E) atomicAdd(&cnt[dst[e]], 1);
}

__global__ __launch_bounds__(1024) void k_scan(const int* __restrict__ cnt, int* __restrict__ rowptr,
                                               int N, int E){
    __shared__ int tot[1024];
    int tid = threadIdx.x;
    int items = (N + 1023) >> 10;
    int base = tid * items;
    int sum = 0;
    for (int i = 0; i < items; ++i){ int idx = base + i; if (idx < N) sum += cnt[idx]; }
    tot[tid] = sum;
    __syncthreads();
    for (int off = 1; off < 1024; off <<= 1){
        int t = (tid >= off) ? tot[tid - off] : 0;
        __syncthreads();
        tot[tid] += t;
        __syncthreads();
    }
    int run = tot[tid] - sum;
    for (int i = 0; i < items; ++i){
        int idx = base + i;
        if (idx < N){ rowptr[idx] = run; run += cnt[idx]; }
    }
    if (tid == 0) rowptr[N] = E;
}

__global__ void k_scatter(const int* __restrict__ src, const int* __restrict__ dst,
                          const int* __restrict__ rowptr, int* __restrict__ fill,
                          int* __restrict__ col, int E){
    int e = blockIdx.x * blockDim.x + threadIdx.x;
    if (e < E){
        int d = dst[e];
        int pos = rowptr[d] + atomicAdd(&fill[d], 1);
        col[pos] = src[e];
    }
}

// batch is SORTED — per-graph [lo,hi) = run boundaries, zero atomics.
__global__ void k_bounds(const int* __restrict__ batch, int* lo, int* hi, int N){
    int i = blockIdx.x * blockDim.x + threadIdx.x;
    if (i < N){
        int b = batch[i];
        if (i == 0     || batch[i - 1] != b) lo[b] = i;
        if (i == N - 1 || batch[i + 1] != b) hi[b] = i + 1;
    }
}

// ---------------- f16 quantize (single plane — single-pass GEMM) ----------------
__global__ void k_split(const float* __restrict__ X, u16* __restrict__ hi, long L4){
    long i = (long)blockIdx.x * blockDim.x + threadIdx.x;
    if (i < L4){
        float4 v = ((const float4*)X)[i];
        ushort4 h;
        h.x = f2h_bits(v.x);
        h.y = f2h_bits(v.y);
        h.z = f2h_bits(v.z);
        h.w = f2h_bits(v.w);
        ((ushort4*)hi)[i] = h;
    }
}

// LDS-tiled transpose: W (K x Nn, row-major) -> hiT (Nn x K, f16).
__global__ __launch_bounds__(256) void k_splitT(const float* __restrict__ W, u16* __restrict__ hiT,
                                                int K, int Nn){
    __shared__ float t[32][33];
    int n0 = blockIdx.x * 32;
    int k0 = blockIdx.y * 32;
    int tx = threadIdx.x & 31, ty = threadIdx.x >> 5;   // 8 rows per pass
    for (int r = ty; r < 32; r += 8){
        int k = k0 + r, n = n0 + tx;
        t[r][tx] = (k < K && n < Nn) ? W[(size_t)k * Nn + n] : 0.f;
    }
    __syncthreads();
    for (int r = ty; r < 32; r += 8){
        int n = n0 + r, k = k0 + tx;
        if (n < Nn && k < K) hiT[(size_t)n * K + k] = f2h_bits(t[tx][r]);
    }
}

// ---------------- single-pass f16 MFMA GEMM (16x16x32), 128x128 tile ----------------
// D = f16(A) x f16(B); dot error ~sqrt(2K)*2^-12*rms(a)*rms(b) ~ 3.4e-4 @K=1024 — an order
// below the bf16 h-storage error (2^-8*|h| ~ 4e-3) that sets absmax (validated: bf16-3pass ->
// f16-2pass left absmax bit-identical). Per-k-step shape == m97 (16 MFMA, 8 ds_read_b128,
// 4 global_load_lds) which measured 874-912 TF. Fallback if absmax moves: round-12 2-pass.
__global__ __launch_bounds__(256) void k_gemm_mfma(
    const u16* __restrict__ Ah, const u16* __restrict__ BTh,
    u16* __restrict__ Cbf, int M, int K, int Nn, int Rchunk)
{
    __shared__ __align__(16) u16 As[128][32];
    __shared__ __align__(16) u16 Bs[128][32];
    int tid = threadIdx.x;
    int w = tid >> 6, lane = tid & 63;

    int R = (M + 127) >> 7;
    int by = blockIdx.x * Rchunk + (blockIdx.y >> 3);   // gridDim.x==8 (XCD swizzle)
    int bx = blockIdx.y & 7;
    if (by >= R) return;
    int row0 = by * 128, col0 = bx * 128;

    int srow = tid >> 2;
    int skoff = (tid & 3) * 8;

    int wm = (w >> 1) * 64, wn = (w & 1) * 64;
    int fr = lane & 15;
    int fq = lane >> 4;

    f32x4 acc[4][4];
#pragma unroll
    for (int i = 0; i < 4; ++i)
#pragma unroll
        for (int j = 0; j < 4; ++j){ acc[i][j].x = 0.f; acc[i][j].y = 0.f; acc[i][j].z = 0.f; acc[i][j].w = 0.f; }

    int ra0 = row0 + srow;      if (ra0 >= M) ra0 = M - 1;
    int ra1 = row0 + srow + 64; if (ra1 >= M) ra1 = M - 1;
    int rb0 = col0 + srow;
    int rb1 = col0 + srow + 64;

    for (int k0 = 0; k0 < K; k0 += 32){
        size_t ga0 = (size_t)ra0 * K + k0 + skoff;
        size_t ga1 = (size_t)ra1 * K + k0 + skoff;
        size_t gb0 = (size_t)rb0 * K + k0 + skoff;
        size_t gb1 = (size_t)rb1 * K + k0 + skoff;
        gload_lds16(Ah  + ga0, &As[srow     ][skoff]);
        gload_lds16(Ah  + ga1, &As[srow + 64][skoff]);
        gload_lds16(BTh + gb0, &Bs[srow     ][skoff]);
        gload_lds16(BTh + gb1, &Bs[srow + 64][skoff]);
        __syncthreads();

        f16x8 a[4], b[4];
#pragma unroll
        for (int i = 0; i < 4; ++i){
            a[i] = *(const f16x8*)&As[wm + i * 16 + fr][fq * 8];
            b[i] = *(const f16x8*)&Bs[wn + i * 16 + fr][fq * 8];
        }
#pragma unroll
        for (int i = 0; i < 4; ++i)
#pragma unroll
            for (int j = 0; j < 4; ++j)
                acc[i][j] = __builtin_amdgcn_mfma_f32_16x16x32_f16(a[i], b[j], acc[i][j], 0, 0, 0);
        __syncthreads();
    }

#pragma unroll
    for (int i = 0; i < 4; ++i){
#pragma unroll
        for (int j = 0; j < 4; ++j){
            int colc = col0 + wn + j * 16 + fr;
#pragma unroll
            for (int r = 0; r < 4; ++r){
                int row = row0 + wm + i * 16 + fq * 4 + r;
                if (row < M) Cbf[(size_t)row * Nn + colc] = f2bf(acc[i][j][r]);
            }
        }
    }
}

// ---------------- per-node attention score dots (bf16 h) ----------------
__global__ __launch_bounds__(256) void k_esd(const u16* __restrict__ h, const float* __restrict__ asrc,
                                             const float* __restrict__ adst,
                                             float* __restrict__ es, float* __restrict__ ed){
    int n = blockIdx.x;
    int tid = threadIdx.x;
    int w = tid >> 6, lane = tid & 63;
    float4 hv = bf4_to_f4(*(const ushort4*)(h + (size_t)n * DHID + w * CPH + lane * 4));
    float4 av = *(const float4*)(asrc + w * CPH + lane * 4);
    float4 dv = *(const float4*)(adst + w * CPH + lane * 4);
    float s = hv.x * av.x + hv.y * av.y + hv.z * av.z + hv.w * av.w;
    float d = hv.x * dv.x + hv.y * dv.y + hv.z * dv.z + hv.w * dv.w;
    for (int off = 32; off > 0; off >>= 1){
        s += __shfl_down(s, off);
        d += __shfl_down(d, off);
    }
    if (lane == 0){ es[n * HEADS + w] = s; ed[n * HEADS + w] = d; }
}

// ---------------- wave-per-node segment softmax + aggregation + bias + elu ----------------
// f16out=1: output f16 (consumed only by the next single-pass f16 GEMM).
// f16out=0: output bf16 (consumed by pooling).
__global__ __launch_bounds__(256) void k_agg(const u16* __restrict__ hsrc, const float* __restrict__ es,
                                             const float* __restrict__ ed, const int* __restrict__ rowptr,
                                             const int* __restrict__ col, const float* __restrict__ bias,
                                             u16* __restrict__ outhi, int f16out, int N){
    int n = blockIdx.x * 4 + (threadIdx.x >> 6);
    if (n >= N) return;
    int lane = threadIdx.x & 63;
    int rp0 = rowptr[n];
    int deg = rowptr[n + 1] - rp0;
    int total = deg + 1;                         // + implicit self-loop
    float4 edv = *(const float4*)(ed + (size_t)n * HEADS);

    float4 a0 = make_float4(0.f,0.f,0.f,0.f), a1 = a0, a2 = a0, a3 = a0;
    int c4 = lane * 4;

    if (total <= 64){
        int sl = (lane < deg) ? col[rp0 + lane] : n;
        float4 ev = *(const float4*)(es + (size_t)sl * HEADS);
        bool valid = (lane < total);
        float ex = valid ? lrelu(ev.x + edv.x) : -FLT_BIG;
        float ey = valid ? lrelu(ev.y + edv.y) : -FLT_BIG;
        float ez = valid ? lrelu(ev.z + edv.z) : -FLT_BIG;
        float ew = valid ? lrelu(ev.w + edv.w) : -FLT_BIG;
        float mxx = ex, mxy = ey, mxz = ez, mxw = ew;
#pragma unroll
        for (int off = 1; off < 64; off <<= 1){
            mxx = fmaxf(mxx, __shfl_xor(mxx, off));
            mxy = fmaxf(mxy, __shfl_xor(mxy, off));
            mxz = fmaxf(mxz, __shfl_xor(mxz, off));
            mxw = fmaxf(mxw, __shfl_xor(mxw, off));
        }
        float px = valid ? expf(ex - mxx) : 0.f;
        float py = valid ? expf(ey - mxy) : 0.f;
        float pz = valid ? expf(ez - mxz) : 0.f;
        float pw = valid ? expf(ew - mxw) : 0.f;
        float sx = px, sy = py, sz = pz, sw = pw;
#pragma unroll
        for (int off = 1; off < 64; off <<= 1){
            sx += __shfl_xor(sx, off);
            sy += __shfl_xor(sy, off);
            sz += __shfl_xor(sz, off);
            sw += __shfl_xor(sw, off);
        }
        float alx_l = px / (sx + 1e-16f);
        float aly_l = py / (sy + 1e-16f);
        float alz_l = pz / (sz + 1e-16f);
        float alw_l = pw / (sw + 1e-16f);

        for (int i = 0; i < total; ++i){
            int s = __shfl(sl, i);                      // lane i holds col[rp0+i] (or n)
            float alx = __shfl(alx_l, i);
            float aly = __shfl(aly_l, i);
            float alz = __shfl(alz_l, i);
            float alw = __shfl(alw_l, i);
            const u16* rowp = hsrc + (size_t)s * DHID;
            ushort4 r0 = *(const ushort4*)(rowp + 0 * CPH + c4);
            ushort4 r1 = *(const ushort4*)(rowp + 1 * CPH + c4);
            ushort4 r2 = *(const ushort4*)(rowp + 2 * CPH + c4);
            ushort4 r3 = *(const ushort4*)(rowp + 3 * CPH + c4);
            float4 f0 = bf4_to_f4(r0), f1 = bf4_to_f4(r1), f2 = bf4_to_f4(r2), f3 = bf4_to_f4(r3);
            a0.x = fmaf(alx, f0.x, a0.x); a0.y = fmaf(alx, f0.y, a0.y);
            a0.z = fmaf(alx, f0.z, a0.z); a0.w = fmaf(alx, f0.w, a0.w);
            a1.x = fmaf(aly, f1.x, a1.x); a1.y = fmaf(aly, f1.y, a1.y);
            a1.z = fmaf(aly, f1.z, a1.z); a1.w = fmaf(aly, f1.w, a1.w);
            a2.x = fmaf(alz, f2.x, a2.x); a2.y = fmaf(alz, f2.y, a2.y);
            a2.z = fmaf(alz, f2.z, a2.z); a2.w = fmaf(alz, f2.w, a2.w);
            a3.x = fmaf(alw, f3.x, a3.x); a3.y = fmaf(alw, f3.y, a3.y);
            a3.z = fmaf(alw, f3.z, a3.z); a3.w = fmaf(alw, f3.w, a3.w);
        }
    } else {
        float4 mx = make_float4(-FLT_BIG, -FLT_BIG, -FLT_BIG, -FLT_BIG);
        for (int i = lane; i < total; i += 64){
            int s = (i < deg) ? col[rp0 + i] : n;
            float4 ev = *(const float4*)(es + (size_t)s * HEADS);
            mx.x = fmaxf(mx.x, lrelu(ev.x + edv.x));
            mx.y = fmaxf(mx.y, lrelu(ev.y + edv.y));
            mx.z = fmaxf(mx.z, lrelu(ev.z + edv.z));
            mx.w = fmaxf(mx.w, lrelu(ev.w + edv.w));
        }
#pragma unroll
        for (int off = 1; off < 64; off <<= 1){
            mx.x = fmaxf(mx.x, __shfl_xor(mx.x, off));
            mx.y = fmaxf(mx.y, __shfl_xor(mx.y, off));
            mx.z = fmaxf(mx.z, __shfl_xor(mx.z, off));
            mx.w = fmaxf(mx.w, __shfl_xor(mx.w, off));
        }
        float4 sm = make_float4(0.f, 0.f, 0.f, 0.f);
        for (int i = lane; i < total; i += 64){
            int s = (i < deg) ? col[rp0 + i] : n;
            float4 ev = *(const float4*)(es + (size_t)s * HEADS);
            sm.x += expf(lrelu(ev.x + edv.x) - mx.x);
            sm.y += expf(lrelu(ev.y + edv.y) - mx.y);
            sm.z += expf(lrelu(ev.z + edv.z) - mx.z);
            sm.w += expf(lrelu(ev.w + edv.w) - mx.w);
        }
#pragma unroll
        for (int off = 1; off < 64; off <<= 1){
            sm.x += __shfl_xor(sm.x, off);
            sm.y += __shfl_xor(sm.y, off);
            sm.z += __shfl_xor(sm.z, off);
            sm.w += __shfl_xor(sm.w, off);
        }
        float4 inv = make_float4(1.f / (sm.x + 1e-16f), 1.f / (sm.y + 1e-16f),
                                 1.f / (sm.z + 1e-16f), 1.f / (sm.w + 1e-16f));
        for (int i = 0; i < total; ++i){
            int s = (i < deg) ? col[rp0 + i] : n;
            float4 ev = *(const float4*)(es + (size_t)s * HEADS);
            const u16* rowp = hsrc + (size_t)s * DHID;
            ushort4 r0 = *(const ushort4*)(rowp + 0 * CPH + c4);
            ushort4 r1 = *(const ushort4*)(rowp + 1 * CPH + c4);
            ushort4 r2 = *(const ushort4*)(rowp + 2 * CPH + c4);
            ushort4 r3 = *(const ushort4*)(rowp + 3 * CPH + c4);
            float alx = expf(lrelu(ev.x + edv.x) - mx.x) * inv.x;
            float aly = expf(lrelu(ev.y + edv.y) - mx.y) * inv.y;
            float alz = expf(lrelu(ev.z + edv.z) - mx.z) * inv.z;
            float alw = expf(lrelu(ev.w + edv.w) - mx.w) * inv.w;
            float4 f0 = bf4_to_f4(r0), f1 = bf4_to_f4(r1), f2 = bf4_to_f4(r2), f3 = bf4_to_f4(r3);
            a0.x = fmaf(alx, f0.x, a0.x); a0.y = fmaf(alx, f0.y, a0.y);
            a0.z = fmaf(alx, f0.z, a0.z); a0.w = fmaf(alx, f0.w, a0.w);
            a1.x = fmaf(aly, f1.x, a1.x); a1.y = fmaf(aly, f1.y, a1.y);
            a1.z = fmaf(aly, f1.z, a1.z); a1.w = fmaf(aly, f1.w, a1.w);
            a2.x = fmaf(alz, f2.x, a2.x); a2.y = fmaf(alz, f2.y, a2.y);
            a2.z = fmaf(alz, f2.z, a2.z); a2.w = fmaf(alz, f2.w, a2.w);
            a3.x = fmaf(alw, f3.x, a3.x); a3.y = fmaf(alw, f3.y, a3.y);
            a3.z = fmaf(alw, f3.z, a3.z); a3.w = fmaf(alw, f3.w, a3.w);
        }
    }

    // epilogue: +bias, elu, store
#pragma unroll
    for (int h = 0; h < 4; ++h){
        float4 a = (h == 0) ? a0 : (h == 1) ? a1 : (h == 2) ? a2 : a3;
        int cidx = h * CPH + c4;
        float4 bv = *(const float4*)(bias + cidx);
        float ox = eluf(a.x + bv.x);
        float oy = eluf(a.y + bv.y);
        float oz = eluf(a.z + bv.z);
        float ow = eluf(a.w + bv.w);
        ushort4 h4;
        if (f16out){
            h4.x = f2h_bits(ox); h4.y = f2h_bits(oy); h4.z = f2h_bits(oz); h4.w = f2h_bits(ow);
        } else {
            h4.x = f2bf(ox); h4.y = f2bf(oy); h4.z = f2bf(oz); h4.w = f2bf(ow);
        }
        *(ushort4*)(outhi + (size_t)n * DHID + cidx) = h4;
    }
}

// ---------------- two-stage per-graph mean/max pooling (bf16 input) ----------------
__global__ __launch_bounds__(256) void k_pool_init(float* __restrict__ gsum, float* __restrict__ gmax, int L){
    int i = blockIdx.x * blockDim.x + threadIdx.x;
    if (i < L){ gsum[i] = 0.f; gmax[i] = -FLT_BIG; }
}

__global__ __launch_bounds__(256) void k_pool_partial(const u16* __restrict__ hf,
                                                      const int* __restrict__ batch,
                                                      float* __restrict__ gsum, float* __restrict__ gmax,
                                                      int N){
    int c = blockIdx.y * 256 + threadIdx.x;
    int i0 = blockIdx.x * PCHUNK;
    int i1 = i0 + PCHUNK; if (i1 > N) i1 = N;
    int curg = batch[i0];
    float s = 0.f, m = -FLT_BIG;
    for (int i = i0; i < i1; ++i){
        int g = batch[i];
        if (g != curg){
            atomicAdd(&gsum[(size_t)curg * DHID + c], s);
            atomicMaxF(&gmax[(size_t)curg * DHID + c], m);
            s = 0.f; m = -FLT_BIG; curg = g;
        }
        float v = bf2f(hf[(size_t)i * DHID + c]);
        s += v;
        m = fmaxf(m, v);
    }
    atomicAdd(&gsum[(size_t)curg * DHID + c], s);
    atomicMaxF(&gmax[(size_t)curg * DHID + c], m);
}

__global__ __launch_bounds__(256) void k_pool_final(const float* __restrict__ gsum,
                                                    const float* __restrict__ gmax,
                                                    const int* __restrict__ lo, const int* __restrict__ hi,
                                                    float* __restrict__ gfeat){
    int g = blockIdx.x;
    int c = threadIdx.x * 4;
    int l = lo[g], h2 = hi[g];
    int cnt = (h2 > l) ? (h2 - l) : 0;
    float invc = 1.f / (float)((cnt > 1) ? cnt : 1);
    float4 s = *(const float4*)(gsum + (size_t)g * DHID + c);
    float4 m = *(const float4*)(gmax + (size_t)g * DHID + c);
    float4 mean = make_float4(s.x * invc, s.y * invc, s.z * invc, s.w * invc);
    if (cnt == 0) m = make_float4(0.f, 0.f, 0.f, 0.f);
    *(float4*)(gfeat + (size_t)g * 2048 + c)        = mean;
    *(float4*)(gfeat + (size_t)g * 2048 + 1024 + c) = m;
}

// ---------------- small FC — latency-optimized ----------------
__global__ __launch_bounds__(256) void k_fc(const float* __restrict__ X, const float* __restrict__ W,
                                            const float* __restrict__ b, float* __restrict__ Y,
                                            int K, int Nc, int relu){
    __shared__ float xs[2048];
    __shared__ float part[4][64];
    int r = blockIdx.y;
    int c0 = blockIdx.x * 64;
    int tid = threadIdx.x;
    int w = tid >> 6, lane = tid & 63;

    for (int i = tid; i < K; i += 256) xs[i] = X[(size_t)r * K + i];
    __syncthreads();

    int c = c0 + lane;
    int kq = K >> 2;                 // K in {2048,512,256} — divisible by 4
    int kbeg = w * kq;
    float acc = 0.f;
    if (c < Nc){
        float a0=0.f,a1=0.f,a2=0.f,a3=0.f,a4=0.f,a5=0.f,a6=0.f,a7=0.f;
        int k = kbeg;
        int kend8 = kbeg + (kq & ~7);
        for (; k < kend8; k += 8){
            a0 = fmaf(xs[k  ], W[(size_t)(k  ) * Nc + c], a0);
            a1 = fmaf(xs[k+1], W[(size_t)(k+1) * Nc + c], a1);
            a2 = fmaf(xs[k+2], W[(size_t)(k+2) * Nc + c], a2);
            a3 = fmaf(xs[k+3], W[(size_t)(k+3) * Nc + c], a3);
            a4 = fmaf(xs[k+4], W[(size_t)(k+4) * Nc + c], a4);
            a5 = fmaf(xs[k+5], W[(size_t)(k+5) * Nc + c], a5);
            a6 = fmaf(xs[k+6], W[(size_t)(k+6) * Nc + c], a6);
            a7 = fmaf(xs[k+7], W[(size_t)(k+7) * Nc + c], a7);
        }
        for (; k < kbeg + kq; ++k) a0 = fmaf(xs[k], W[(size_t)k * Nc + c], a0);
        acc = ((a0 + a1) + (a2 + a3)) + ((a4 + a5) + (a6 + a7));
    }
    if (w) part[w][lane] = acc;
    __syncthreads();
    if (w == 0 && c < Nc){
        acc += part[1][lane] + part[2][lane] + part[3][lane];
        acc += b[c];
        if (relu) acc = fmaxf(acc, 0.f);
        Y[(size_t)r * Nc + c] = acc;
    }
}

// ---------------- launch ----------------
extern "C" void kernel_launch(void* const* d_in, const int* in_sizes, int n_in,
                              void* d_out, int out_size, void* d_ws, size_t ws_size,
                              hipStream_t stream) {
    const float* x      = (const float*)d_in[0];
    const int*   ei     = (const int*)  d_in[1];
    const int*   batch  = (const int*)  d_in[2];
    const float* W1     = (const float*)d_in[3];
    const float* asrc1  = (const float*)d_in[4];
    const float* adst1  = (const float*)d_in[5];
    const float* b1     = (const float*)d_in[6];
    const float* W2     = (const float*)d_in[7];
    const float* asrc2  = (const float*)d_in[8];
    const float* adst2  = (const float*)d_in[9];
    const float* b2     = (const float*)d_in[10];
    const float* Wc1    = (const float*)d_in[11];
    const float* bc1    = (const float*)d_in[12];
    const float* Wc2    = (const float*)d_in[13];
    const float* bc2    = (const float*)d_in[14];
    const float* Wc3    = (const float*)d_in[15];
    const float* bc3    = (const float*)d_in[16];

    const int N = in_sizes[2];
    const int E = in_sizes[1] / 2;
    const int G = out_size / 5;
    const int DIN = in_sizes[0] / N;

    const int* srcI = ei;
    const int* dstI = ei + E;

    char* p = (char*)d_ws;
    auto alloc = [&](size_t bytes) -> void* {
        void* q = (void*)p;
        p += (bytes + 255) & ~(size_t)255;
        return q;
    };
    u16*   R1     = (u16*)alloc((size_t)N * DHID * 2 * 2);   // activations
    u16*   R2     = (u16*)alloc((size_t)N * DHID * 2);       // h plane
    float* es     = (float*)alloc((size_t)N * HEADS * 4);
    float* ed     = (float*)alloc((size_t)N * HEADS * 4);
    float* gfeat  = (float*)alloc((size_t)G * 2048 * 4);
    float* gsum   = (float*)alloc((size_t)G * DHID * 4);
    float* gmax   = (float*)alloc((size_t)G * DHID * 4);
    float* z1     = (float*)alloc((size_t)G * 512 * 4);
    float* z2     = (float*)alloc((size_t)G * 256 * 4);
    int*   cnt    = (int*)  alloc((size_t)N * 4);
    int*   fill   = (int*)  alloc((size_t)N * 4);
    int*   rowptr = (int*)  alloc((size_t)(N + 1) * 4);
    int*   col    = (int*)  alloc((size_t)E * 4);
    int*   lo     = (int*)  alloc((size_t)G * 4);
    int*   hi     = (int*)  alloc((size_t)G * 4);
    u16*   w1th   = (u16*)  alloc((size_t)DIN * DHID * 2);
    u16*   w2th   = (u16*)  alloc((size_t)DHID * DHID * 2);
    float* logits = (float*)d_out;

    int nb = (N + 255) / 256;
    int ebp = (E + 255) / 256;
    int aggb = (N + 3) / 4;

    // CSR + pooling bounds
    k_init   <<<nb,  256, 0, stream>>>(cnt, fill, lo, hi, N, G);
    k_count  <<<ebp, 256, 0, stream>>>(dstI, cnt, E);
    k_scan   <<<1,  1024, 0, stream>>>(cnt, rowptr, N, E);
    k_scatter<<<ebp, 256, 0, stream>>>(srcI, dstI, rowptr, fill, col, E);
    k_bounds <<<nb,  256, 0, stream>>>(batch, lo, hi, N);

    // weight transpose + f16 quantize
    k_splitT<<<dim3((DHID + 31) / 32, (DIN + 31) / 32),  256, 0, stream>>>(W1, w1th, DIN, DHID);
    k_splitT<<<dim3((DHID + 31) / 32, (DHID + 31) / 32), 256, 0, stream>>>(W2, w2th, DHID, DHID);

    int R = (N + 127) / 128;
    int Rchunk = (R + 7) / 8;
    dim3 gemmGrd(8, 8 * Rchunk);   // XCD swizzle: x = row-chunk, y = (local row, col-block)

    // ---- GAT layer 1 ----
    u16* a1h = R1;
    long L41 = (long)N * DIN / 4;
    k_split<<<(unsigned)((L41 + 255) / 256), 256, 0, stream>>>(x, a1h, L41);
    u16* h1 = R2;
    k_gemm_mfma<<<gemmGrd, 256, 0, stream>>>(a1h, w1th, h1, N, DIN, DHID, Rchunk);
    k_esd<<<N, 256, 0, stream>>>(h1, asrc1, adst1, es, ed);
    u16* o1h = R1;
    k_agg<<<aggb, 256, 0, stream>>>(h1, es, ed, rowptr, col, b1, o1h, 1, N);

    // ---- GAT layer 2 ----
    u16* h2 = R2;
    k_gemm_mfma<<<gemmGrd, 256, 0, stream>>>(o1h, w2th, h2, N, DHID, DHID, Rchunk);
    k_esd<<<N, 256, 0, stream>>>(h2, asrc2, adst2, es, ed);
    u16* o2h = R1;
    k_agg<<<aggb, 256, 0, stream>>>(h2, es, ed, rowptr, col, b2, o2h, 0, N);

    // ---- pooling + classifier ----
    k_pool_init<<<(G * DHID + 255) / 256, 256, 0, stream>>>(gsum, gmax, G * DHID);
    dim3 poolGrd((N + PCHUNK - 1) / PCHUNK, DHID / 256);
    k_pool_partial<<<poolGrd, 256, 0, stream>>>(o2h, batch, gsum, gmax, N);
    k_pool_final<<<G, 256, 0, stream>>>(gsum, gmax, lo, hi, gfeat);

    k_fc<<<dim3((512 + 63) / 64, G), 256, 0, stream>>>(gfeat, Wc1, bc1, z1, 2048, 512, 1);
    k_fc<<<dim3((256 + 63) / 64, G), 256, 0, stream>>>(z1,    Wc2, bc2, z2, 512,  256, 1);
    k_fc<<<dim3(1, G),                256, 0, stream>>>(z2,    Wc3, bc3, logits, 256, 5, 0);
}